// Round 2
// baseline (1490.042 us; speedup 1.0000x reference)
//
#include <hip/hip_runtime.h>
#include <hip/hip_bf16.h>
#include <math.h>

// ---------------------------------------------------------------------------
// FederatedPPOAgent: 3x GCNConv (N=100k, E=3.2M, D=128) + actor/critic MLPs.
//
//   CSR build : LDS-privatized counting sort. 8 node-ranges x 32 edge-chunks;
//               block (r,c) histograms chunk c for range r in LDS (50KB),
//               global scan -> rowptr, hist -> per-(r,c) cursors, fill with
//               LDS atomics only. Zero global atomics (round-1 fill_csr_k had
//               194MB line-thrash writes + 3.2M device atomics -> 287us).
//   per layer : hprime = (X @ W) * dinv[row]    (fp32 tile GEMM, x-tile in LDS)
//               h_out  = act((sum_{e->d} hprime[src] + hprime[d]) * dinv[d] + b)
//                        (wave-per-node gather-sum, no atomics)
//   heads     : per-64-node tile, whole actor+critic chain in LDS, softmax,
//               coalesced [N,9] store.
// ---------------------------------------------------------------------------

#define WS_ALIGN(x) (((x) + 255) & ~(size_t)255)

constexpr int RNG = 8;        // node ranges (XCD-affine via blockIdx%8)
constexpr int CHK = 32;       // edge chunks
constexpr int NR_CAP = 12544; // LDS histogram capacity (>= ceil(100000/8))

// ---------------- CSR build (LDS counting sort) ----------------

__global__ __launch_bounds__(256) void hist_count_k(
    const int* __restrict__ dst, int* __restrict__ hist,
    int E, int EC, int NRg) {
    __shared__ int h[NR_CAP];
    int b = blockIdx.x;
    int r = b & (RNG - 1), c = b >> 3;
    for (int i = threadIdx.x; i < NRg; i += 256) h[i] = 0;
    __syncthreads();
    int base = r * NRg;
    int e0 = c * EC, e1 = min(E, e0 + EC);
    for (int e = e0 + threadIdx.x; e < e1; e += 256) {
        int d = dst[e] - base;
        if ((unsigned)d < (unsigned)NRg) atomicAdd(&h[d], 1);
    }
    __syncthreads();
    int* out = hist + ((size_t)r * CHK + c) * NRg;
    for (int i = threadIdx.x; i < NRg; i += 256) out[i] = h[i];
}

__global__ void sum_hist_k(const int* __restrict__ hist, int* __restrict__ cnt,
                           int N, int NRg) {
    int i = blockIdx.x * 256 + threadIdx.x;
    if (i >= N) return;
    int r = i / NRg, li = i - r * NRg;
    const int* hp = hist + ((size_t)r * CHK) * NRg + li;
    int s = 0;
#pragma unroll
    for (int c = 0; c < CHK; c++) s += hp[(size_t)c * NRg];
    cnt[i] = s;
}

__global__ void dinv_k(const int* __restrict__ cnt, float* __restrict__ dinv, int n) {
    int i = blockIdx.x * 256 + threadIdx.x;
    if (i < n) dinv[i] = rsqrtf((float)cnt[i] + 1.0f);   // +1: self loop
}

__global__ void chunk_sum_k(const int* __restrict__ cnt, int* __restrict__ bsum, int n) {
    __shared__ int sd[256];
    int t = threadIdx.x;
    int i = blockIdx.x * 256 + t;
    sd[t] = (i < n) ? cnt[i] : 0;
    __syncthreads();
    for (int d = 128; d > 0; d >>= 1) {
        if (t < d) sd[t] += sd[t + d];
        __syncthreads();
    }
    if (t == 0) bsum[blockIdx.x] = sd[0];
}

// single block, 512 threads; nb <= 512
__global__ void scan_mid_k(const int* __restrict__ bsum, int* __restrict__ boff,
                           int nb, int* __restrict__ rowptr, int N) {
    __shared__ int s[512];
    int t = threadIdx.x;
    s[t] = (t < nb) ? bsum[t] : 0;
    __syncthreads();
    if (t == 0) {
        int run = 0;
        for (int i = 0; i < nb; i++) { int v = s[i]; s[i] = run; run += v; }
        rowptr[N] = run;  // total edges
    }
    __syncthreads();
    if (t < nb) boff[t] = s[t];
}

__global__ void scan_final_k(const int* __restrict__ cnt, const int* __restrict__ boff,
                             int* __restrict__ rowptr, int n) {
    __shared__ int s[256];
    int t = threadIdx.x;
    int i = blockIdx.x * 256 + t;
    int v = (i < n) ? cnt[i] : 0;
    s[t] = v;
    __syncthreads();
    // Hillis-Steele inclusive scan
    for (int d = 1; d < 256; d <<= 1) {
        int x = (t >= d) ? s[t - d] : 0;
        __syncthreads();
        s[t] += x;
        __syncthreads();
    }
    if (i < n) rowptr[i] = s[t] - v + boff[blockIdx.x];  // exclusive
}

// hist[r][c][i] -> exclusive running cursor = rowptr + prefix over chunks
__global__ void offsets_k(int* __restrict__ hist, const int* __restrict__ rowptr,
                          int N, int NRg) {
    int i = blockIdx.x * 256 + threadIdx.x;
    if (i >= N) return;
    int r = i / NRg, li = i - r * NRg;
    int* hp = hist + ((size_t)r * CHK) * NRg + li;
    int run = rowptr[i];
#pragma unroll
    for (int c = 0; c < CHK; c++) {
        int v = hp[(size_t)c * NRg];
        hp[(size_t)c * NRg] = run;
        run += v;
    }
}

__global__ __launch_bounds__(256) void fill_k(
    const int* __restrict__ src, const int* __restrict__ dst,
    const int* __restrict__ hist, int* __restrict__ col,
    int E, int EC, int NRg) {
    __shared__ int cur[NR_CAP];
    int b = blockIdx.x;
    int r = b & (RNG - 1), c = b >> 3;
    const int* hp = hist + ((size_t)r * CHK + c) * NRg;
    for (int i = threadIdx.x; i < NRg; i += 256) cur[i] = hp[i];
    __syncthreads();
    int base = r * NRg;
    int e0 = c * EC, e1 = min(E, e0 + EC);
    for (int e = e0 + threadIdx.x; e < e1; e += 256) {
        int d = dst[e] - base;
        if ((unsigned)d < (unsigned)NRg) {
            int slot = atomicAdd(&cur[d], 1);   // LDS atomic
            col[slot] = src[e];                 // confined to range r's 1.6MB
        }
    }
}

// ---------------- GEMM: Y[r,:] = (X[r,:] @ W) * dinv[r] ----------------
// X:[N,128], W:[128,OUT], OUT in {128,64}. 64-row tile per 256-thread block.

template <int OUT>
__global__ __launch_bounds__(256) void gemm_scaled_k(
    const float* __restrict__ X, const float* __restrict__ W,
    const float* __restrict__ dinv, float* __restrict__ Y, int N) {
    constexpr int TR = 64;
    __shared__ __align__(16) float xs[TR][132];   // pad: 132 % 32 banks -> free 2-way
    int t = threadIdx.x;
    int rowBase = blockIdx.x * TR;

    // stage x tile (64 x 128) with float4 loads
    for (int i = t; i < TR * 32; i += 256) {
        int r = i >> 5, q = i & 31;
        int gr = rowBase + r;
        float4 v = make_float4(0.f, 0.f, 0.f, 0.f);
        if (gr < N) v = ((const float4*)(X + (size_t)gr * 128))[q];
        *(float4*)&xs[r][q * 4] = v;
    }
    __syncthreads();

    constexpr int CG = OUT / 8;             // col groups of 8
    constexpr int RPT = (TR * CG) / 256;    // rows per thread: 4 (OUT=128), 2 (OUT=64)
    int c0 = (t % CG) * 8;
    int r0 = (t / CG) * RPT;

    float acc[RPT][8];
#pragma unroll
    for (int j = 0; j < RPT; j++)
#pragma unroll
        for (int c = 0; c < 8; c++) acc[j][c] = 0.f;

#pragma unroll 4
    for (int k = 0; k < 128; k++) {
        float4 w0 = *(const float4*)(W + k * OUT + c0);
        float4 w1 = *(const float4*)(W + k * OUT + c0 + 4);
#pragma unroll
        for (int j = 0; j < RPT; j++) {
            float xv = xs[r0 + j][k];
            acc[j][0] = fmaf(xv, w0.x, acc[j][0]);
            acc[j][1] = fmaf(xv, w0.y, acc[j][1]);
            acc[j][2] = fmaf(xv, w0.z, acc[j][2]);
            acc[j][3] = fmaf(xv, w0.w, acc[j][3]);
            acc[j][4] = fmaf(xv, w1.x, acc[j][4]);
            acc[j][5] = fmaf(xv, w1.y, acc[j][5]);
            acc[j][6] = fmaf(xv, w1.z, acc[j][6]);
            acc[j][7] = fmaf(xv, w1.w, acc[j][7]);
        }
    }

#pragma unroll
    for (int j = 0; j < RPT; j++) {
        int gr = rowBase + r0 + j;
        if (gr < N) {
            float s = dinv[gr];
            float4 o0 = make_float4(acc[j][0] * s, acc[j][1] * s, acc[j][2] * s, acc[j][3] * s);
            float4 o1 = make_float4(acc[j][4] * s, acc[j][5] * s, acc[j][6] * s, acc[j][7] * s);
            float* yp = Y + (size_t)gr * OUT + c0;
            *(float4*)yp = o0;
            *(float4*)(yp + 4) = o1;
        }
    }
}

// ---------------- aggregation: wave per node, register gather-sum ----------------

template <int D, bool RELU>
__global__ __launch_bounds__(256) void agg_k(
    const float* __restrict__ H,        // [N,D] = hprime (already * dinv[src])
    const int* __restrict__ rowptr,     // [N+1]
    const int* __restrict__ col,        // [E] src per slot
    const float* __restrict__ dinv,
    const float* __restrict__ bias,     // [D]
    float* __restrict__ Y, int N) {
    int tid = threadIdx.x;
    int node = blockIdx.x * 4 + (tid >> 6);
    if (node >= N) return;
    int lane = tid & 63;
    constexpr int VF = D / 64;           // 2 (D=128) or 1 (D=64)
    const size_t fo = (size_t)lane * VF;

    float acc0, acc1 = 0.f;
    {   // self loop contribution
        const float* r = H + (size_t)node * D + fo;
        if constexpr (VF == 2) { float2 v = *(const float2*)r; acc0 = v.x; acc1 = v.y; }
        else acc0 = r[0];
    }

    int e = rowptr[node], end = rowptr[node + 1];
    for (; e + 4 <= end; e += 4) {
        int s0 = col[e], s1 = col[e + 1], s2 = col[e + 2], s3 = col[e + 3];
        const float* p0 = H + (size_t)s0 * D + fo;
        const float* p1 = H + (size_t)s1 * D + fo;
        const float* p2 = H + (size_t)s2 * D + fo;
        const float* p3 = H + (size_t)s3 * D + fo;
        if constexpr (VF == 2) {
            float2 a = *(const float2*)p0, b = *(const float2*)p1;
            float2 c = *(const float2*)p2, d = *(const float2*)p3;
            acc0 += (a.x + b.x) + (c.x + d.x);
            acc1 += (a.y + b.y) + (c.y + d.y);
        } else {
            acc0 += (p0[0] + p1[0]) + (p2[0] + p3[0]);
        }
    }
    for (; e < end; e++) {
        const float* p = H + (size_t)col[e] * D + fo;
        if constexpr (VF == 2) { float2 a = *(const float2*)p; acc0 += a.x; acc1 += a.y; }
        else acc0 += p[0];
    }

    float dv = dinv[node];
    float o0 = acc0 * dv + bias[fo];
    if (RELU) o0 = fmaxf(o0, 0.f);
    if constexpr (VF == 2) {
        float o1 = acc1 * dv + bias[fo + 1];
        if (RELU) o1 = fmaxf(o1, 0.f);
        *(float2*)(Y + (size_t)node * D + fo) = make_float2(o0, o1);
    } else {
        Y[(size_t)node * D + fo] = o0;
    }
}

// ---------------- fused actor/critic heads ----------------
// 64-node tile per 256-thread block; all intermediates in LDS.

template <int K, int OUT, int LDI, int LDO>
__device__ __forceinline__ void tile_mlp(const float (*xin)[LDI], float (*yout)[LDO],
                                         const float* __restrict__ W,
                                         const float* __restrict__ bias, int t) {
    constexpr int CG = OUT / 8;
    constexpr int RPT = (64 * CG) / 256;
    int c0 = (t % CG) * 8;
    int r0 = (t / CG) * RPT;
    float acc[RPT][8];
#pragma unroll
    for (int j = 0; j < RPT; j++)
#pragma unroll
        for (int c = 0; c < 8; c++) acc[j][c] = 0.f;
#pragma unroll 4
    for (int k = 0; k < K; k++) {
        float4 w0 = *(const float4*)(W + k * OUT + c0);
        float4 w1 = *(const float4*)(W + k * OUT + c0 + 4);
#pragma unroll
        for (int j = 0; j < RPT; j++) {
            float xv = xin[r0 + j][k];
            acc[j][0] = fmaf(xv, w0.x, acc[j][0]);
            acc[j][1] = fmaf(xv, w0.y, acc[j][1]);
            acc[j][2] = fmaf(xv, w0.z, acc[j][2]);
            acc[j][3] = fmaf(xv, w0.w, acc[j][3]);
            acc[j][4] = fmaf(xv, w1.x, acc[j][4]);
            acc[j][5] = fmaf(xv, w1.y, acc[j][5]);
            acc[j][6] = fmaf(xv, w1.z, acc[j][6]);
            acc[j][7] = fmaf(xv, w1.w, acc[j][7]);
        }
    }
#pragma unroll
    for (int j = 0; j < RPT; j++)
#pragma unroll
        for (int c = 0; c < 8; c++) {
            float v = acc[j][c] + bias[c0 + c];
            yout[r0 + j][c0 + c] = fmaxf(v, 0.f);   // all 4 hidden layers are relu
        }
}

__global__ __launch_bounds__(256) void heads_k(
    const float* __restrict__ H3,  // [N,64]
    const float* __restrict__ Wa1, const float* __restrict__ ba1,
    const float* __restrict__ Wa2, const float* __restrict__ ba2,
    const float* __restrict__ Wa3, const float* __restrict__ ba3,
    const float* __restrict__ Wc1, const float* __restrict__ bc1,
    const float* __restrict__ Wc2, const float* __restrict__ bc2,
    const float* __restrict__ Wc3, const float* __restrict__ bc3,
    float* __restrict__ out, int N) {
    constexpr int TN = 64;
    __shared__ __align__(16) float hs[TN][68];    // h3 tile (64x64)
    __shared__ float t1[TN][129];                 // 128-dim intermediate
    __shared__ float t2[TN][65];                  // 64-dim intermediate
    __shared__ float lg[TN][12];                  // probs(8) + value(1)
    int t = threadIdx.x;
    int nodeBase = blockIdx.x * TN;

    for (int i = t; i < TN * 16; i += 256) {
        int r = i >> 4, q = i & 15;
        int gn = nodeBase + r;
        float4 v = make_float4(0.f, 0.f, 0.f, 0.f);
        if (gn < N) v = ((const float4*)(H3 + (size_t)gn * 64))[q];
        *(float4*)&hs[r][q * 4] = v;
    }
    __syncthreads();

    // critic chain
    tile_mlp<64, 128, 68, 129>(hs, t1, Wc1, bc1, t);
    __syncthreads();
    tile_mlp<128, 64, 129, 65>(t1, t2, Wc2, bc2, t);
    __syncthreads();
    if (t < TN) {                                  // value head (OUT=1)
        float s = bc3[0];
        for (int k = 0; k < 64; k++) s = fmaf(t2[t][k], Wc3[k], s);
        lg[t][8] = s;
    }
    // actor chain (a1 writes t1; safe: t1 readers done at prior barrier)
    tile_mlp<64, 128, 68, 129>(hs, t1, Wa1, ba1, t);
    __syncthreads();
    tile_mlp<128, 64, 129, 65>(t1, t2, Wa2, ba2, t);
    __syncthreads();
    if (t < TN) {                                  // logits + softmax
        float l[8];
#pragma unroll
        for (int c = 0; c < 8; c++) {
            float s = ba3[c];
            for (int k = 0; k < 64; k++) s = fmaf(t2[t][k], Wa3[k * 8 + c], s);
            l[c] = s;
        }
        float m = l[0];
#pragma unroll
        for (int c = 1; c < 8; c++) m = fmaxf(m, l[c]);
        float sum = 0.f;
#pragma unroll
        for (int c = 0; c < 8; c++) { l[c] = expf(l[c] - m); sum += l[c]; }
        float inv = 1.0f / sum;
#pragma unroll
        for (int c = 0; c < 8; c++) lg[t][c] = l[c] * inv;
    }
    __syncthreads();

    // coalesced store of [64 x 9]
    for (int i = t; i < TN * 9; i += 256) {
        int r = i / 9, c = i - r * 9;
        int gn = nodeBase + r;
        if (gn < N) out[(size_t)gn * 9 + c] = lg[r][c];
    }
}

// ---------------- launch ----------------

extern "C" void kernel_launch(void* const* d_in, const int* in_sizes, int n_in,
                              void* d_out, int out_size, void* d_ws, size_t ws_size,
                              hipStream_t stream) {
    const float* x   = (const float*)d_in[0];
    const int*   ei  = (const int*)d_in[1];
    const float* W1  = (const float*)d_in[2];  const float* b1  = (const float*)d_in[3];
    const float* W2  = (const float*)d_in[4];  const float* b2  = (const float*)d_in[5];
    const float* W3  = (const float*)d_in[6];  const float* b3  = (const float*)d_in[7];
    const float* Wa1 = (const float*)d_in[8];  const float* ba1 = (const float*)d_in[9];
    const float* Wa2 = (const float*)d_in[10]; const float* ba2 = (const float*)d_in[11];
    const float* Wa3 = (const float*)d_in[12]; const float* ba3 = (const float*)d_in[13];
    const float* Wc1 = (const float*)d_in[14]; const float* bc1 = (const float*)d_in[15];
    const float* Wc2 = (const float*)d_in[16]; const float* bc2 = (const float*)d_in[17];
    const float* Wc3 = (const float*)d_in[18]; const float* bc3 = (const float*)d_in[19];
    float* out = (float*)d_out;

    const int N = in_sizes[0] / 128;     // 100000
    const int E = in_sizes[1] / 2;       // 3200000
    const int* src = ei;
    const int* dst = ei + E;

    // workspace layout
    size_t off = 0;
    auto take = [&](size_t bytes) { size_t o = off; off = WS_ALIGN(off + bytes); return o; };
    char* ws = (char*)d_ws;
    float* bufA   = (float*)(ws + take((size_t)N * 128 * 4));
    float* bufB   = (float*)(ws + take((size_t)N * 128 * 4));
    float* dinv   = (float*)(ws + take((size_t)N * 4));
    int*   cnt    = (int*)  (ws + take((size_t)N * 4));
    int*   rowptr = (int*)  (ws + take((size_t)(N + 1) * 4));
    int*   col    = (int*)  (ws + take((size_t)E * 4));
    int*   bsum   = (int*)  (ws + take(512 * 4));
    int*   boff   = (int*)  (ws + take(512 * 4));
    // hist aliases bufA: dead before the first GEMM writes bufA.
    int*   hist   = (int*)bufA;          // RNG*CHK*NRg ints = 12.8MB < 51.2MB
    (void)ws_size; (void)n_in; (void)out_size;

    const int NRg = (N + RNG - 1) / RNG;     // 12500 (<= NR_CAP)
    const int EC  = (E + CHK - 1) / CHK;     // 100000 edges per chunk
    const int nb  = (N + 255) / 256;         // 391 scan blocks (<512)
    const int gN  = (N + 255) / 256;
    const int gT  = (N + 63) / 64;           // 64-row tiles
    const int gAg = (N + 3) / 4;             // 4 nodes per block

    // CSR build (no global atomics)
    hist_count_k<<<RNG * CHK, 256, 0, stream>>>(dst, hist, E, EC, NRg);
    sum_hist_k<<<gN, 256, 0, stream>>>(hist, cnt, N, NRg);
    dinv_k<<<gN, 256, 0, stream>>>(cnt, dinv, N);
    chunk_sum_k<<<nb, 256, 0, stream>>>(cnt, bsum, N);
    scan_mid_k<<<1, 512, 0, stream>>>(bsum, boff, nb, rowptr, N);
    scan_final_k<<<nb, 256, 0, stream>>>(cnt, boff, rowptr, N);
    offsets_k<<<gN, 256, 0, stream>>>(hist, rowptr, N, NRg);
    fill_k<<<RNG * CHK, 256, 0, stream>>>(src, dst, hist, col, E, EC, NRg);

    // layer 1: 128 -> 128, relu
    gemm_scaled_k<128><<<gT, 256, 0, stream>>>(x, W1, dinv, bufA, N);
    agg_k<128, true><<<gAg, 256, 0, stream>>>(bufA, rowptr, col, dinv, b1, bufB, N);
    // layer 2: 128 -> 128, relu
    gemm_scaled_k<128><<<gT, 256, 0, stream>>>(bufB, W2, dinv, bufA, N);
    agg_k<128, true><<<gAg, 256, 0, stream>>>(bufA, rowptr, col, dinv, b2, bufB, N);
    // layer 3: 128 -> 64, linear
    gemm_scaled_k<64><<<gT, 256, 0, stream>>>(bufB, W3, dinv, bufA, N);
    agg_k<64, false><<<gAg, 256, 0, stream>>>(bufA, rowptr, col, dinv, b3, bufB, N);

    // heads
    heads_k<<<gT, 256, 0, stream>>>(bufB, Wa1, ba1, Wa2, ba2, Wa3, ba3,
                                    Wc1, bc1, Wc2, bc2, Wc3, bc3, out, N);
}

// Round 3
// 1001.575 us; speedup vs baseline: 1.4877x; 1.4877x over previous
//
#include <hip/hip_runtime.h>
#include <hip/hip_bf16.h>
#include <math.h>

// ---------------------------------------------------------------------------
// FederatedPPOAgent: 3x GCNConv (N=100k, E=3.2M, D=128) + actor/critic MLPs.
//
// R3 changes vs R2:
//  - CSR build is a 3-phase bucket sort: 8-bin count -> scan -> coalesced
//    scatter into per-range u64 (dst_local,src) segments; hist/fill then read
//    only their own range's edges ONCE (R2 fill_k re-read all edges 8x:
//    FETCH 105MB, WRITE 105MB line-thrash, 250us).
//  - hprime stored bf16: agg gather row = 256B = 64 lanes x ushort2, halving
//    the dominant L3 gather traffic. Accumulation fp32 (absmax ~2e-4 << 2.5e-3).
// ---------------------------------------------------------------------------

#define WS_ALIGN(x) (((x) + 255) & ~(size_t)255)

constexpr int RNG    = 8;        // node ranges (XCD-affine via blockIdx&7)
constexpr int CHK    = 32;       // per-range fill chunks
constexpr int NRG_SZ = 12500;    // nodes per range (8*12500 = 100000 exactly)
constexpr int NB_A   = 256;      // bucket-phase blocks

__device__ __forceinline__ float b2f(unsigned short u) {
    return __uint_as_float(((unsigned int)u) << 16);
}

// ---------------- CSR build ----------------

__global__ __launch_bounds__(256) void bucket_count_k(
    const int* __restrict__ dst, int* __restrict__ bcnt, int E) {
    __shared__ int c8[RNG];
    int b = blockIdx.x, t = threadIdx.x;
    if (t < RNG) c8[t] = 0;
    __syncthreads();
    int ec = (E + NB_A - 1) / NB_A;
    int e0 = b * ec, e1 = min(E, e0 + ec);
    for (int e = e0 + t; e < e1; e += 256) {
        int d = __builtin_nontemporal_load(dst + e);
        atomicAdd(&c8[d / NRG_SZ], 1);
    }
    __syncthreads();
    if (t < RNG) bcnt[t * NB_A + b] = c8[t];
}

// 1 block, 1024 threads; scans RNG*NB_A = 2048 entries (r-major, b-minor)
__global__ void bucket_off_k(const int* __restrict__ bcnt, int* __restrict__ base,
                             int* __restrict__ bstart, int E) {
    __shared__ int s[RNG * NB_A];
    int t = threadIdx.x;
    s[t] = bcnt[t];
    s[t + 1024] = bcnt[t + 1024];
    __syncthreads();
    if (t == 0) {
        int run = 0;
        for (int i = 0; i < RNG * NB_A; i++) { int v = s[i]; s[i] = run; run += v; }
    }
    __syncthreads();
    base[t] = s[t];
    base[t + 1024] = s[t + 1024];
    if (t < RNG) bstart[t] = s[t * NB_A];
    if (t == 0) bstart[RNG] = E;
}

__global__ __launch_bounds__(256) void bucket_scatter_k(
    const int* __restrict__ src, const int* __restrict__ dst,
    const int* __restrict__ base, unsigned long long* __restrict__ bucket, int E) {
    __shared__ int cur[RNG];
    int b = blockIdx.x, t = threadIdx.x;
    if (t < RNG) cur[t] = base[t * NB_A + b];
    __syncthreads();
    int ec = (E + NB_A - 1) / NB_A;
    int e0 = b * ec, e1 = min(E, e0 + ec);
    for (int e = e0 + t; e < e1; e += 256) {
        int d = __builtin_nontemporal_load(dst + e);
        int sv = __builtin_nontemporal_load(src + e);
        int r = d / NRG_SZ;
        int pos = atomicAdd(&cur[r], 1);
        bucket[pos] = ((unsigned long long)(d - r * NRG_SZ) << 32) | (unsigned int)sv;
    }
}

__global__ __launch_bounds__(256) void hist_bucket_k(
    const unsigned long long* __restrict__ bucket, const int* __restrict__ bstart,
    int* __restrict__ hist) {
    __shared__ int h[NRG_SZ];
    int b = blockIdx.x, r = b & 7, c2 = b >> 3, t = threadIdx.x;
    for (int i = t; i < NRG_SZ; i += 256) h[i] = 0;
    int s0 = bstart[r], s1 = bstart[r + 1];
    int ec = (s1 - s0 + CHK - 1) / CHK;
    int e0 = s0 + c2 * ec, e1 = min(s1, e0 + ec);
    __syncthreads();
    for (int e = e0 + t; e < e1; e += 256) {
        unsigned long long v = __builtin_nontemporal_load(bucket + e);
        atomicAdd(&h[(int)(v >> 32)], 1);
    }
    __syncthreads();
    int* out = hist + ((size_t)r * CHK + c2) * NRG_SZ;
    for (int i = t; i < NRG_SZ; i += 256) out[i] = h[i];
}

__global__ void sum_hist_dinv_k(const int* __restrict__ hist, int* __restrict__ cnt,
                                float* __restrict__ dinv, int N) {
    int i = blockIdx.x * 256 + threadIdx.x;
    if (i >= N) return;
    int r = i / NRG_SZ, li = i - r * NRG_SZ;
    const int* hp = hist + ((size_t)r * CHK) * NRG_SZ + li;
    int s = 0;
#pragma unroll
    for (int c = 0; c < CHK; c++) s += hp[(size_t)c * NRG_SZ];
    cnt[i] = s;
    dinv[i] = rsqrtf((float)s + 1.0f);   // +1: self loop
}

__global__ void chunk_sum_k(const int* __restrict__ cnt, int* __restrict__ bsum, int n) {
    __shared__ int sd[256];
    int t = threadIdx.x;
    int i = blockIdx.x * 256 + t;
    sd[t] = (i < n) ? cnt[i] : 0;
    __syncthreads();
    for (int d = 128; d > 0; d >>= 1) {
        if (t < d) sd[t] += sd[t + d];
        __syncthreads();
    }
    if (t == 0) bsum[blockIdx.x] = sd[0];
}

// single block, 512 threads; nb <= 512
__global__ void scan_mid_k(const int* __restrict__ bsum, int* __restrict__ boff,
                           int nb, int* __restrict__ rowptr, int N) {
    __shared__ int s[512];
    int t = threadIdx.x;
    s[t] = (t < nb) ? bsum[t] : 0;
    __syncthreads();
    if (t == 0) {
        int run = 0;
        for (int i = 0; i < nb; i++) { int v = s[i]; s[i] = run; run += v; }
        rowptr[N] = run;
    }
    __syncthreads();
    if (t < nb) boff[t] = s[t];
}

__global__ void scan_final_k(const int* __restrict__ cnt, const int* __restrict__ boff,
                             int* __restrict__ rowptr, int n) {
    __shared__ int s[256];
    int t = threadIdx.x;
    int i = blockIdx.x * 256 + t;
    int v = (i < n) ? cnt[i] : 0;
    s[t] = v;
    __syncthreads();
    for (int d = 1; d < 256; d <<= 1) {
        int x = (t >= d) ? s[t - d] : 0;
        __syncthreads();
        s[t] += x;
        __syncthreads();
    }
    if (i < n) rowptr[i] = s[t] - v + boff[blockIdx.x];
}

// hist[r][c][li] -> exclusive running cursor = rowptr + prefix over chunks
__global__ void offsets_k(int* __restrict__ hist, const int* __restrict__ rowptr, int N) {
    int i = blockIdx.x * 256 + threadIdx.x;
    if (i >= N) return;
    int r = i / NRG_SZ, li = i - r * NRG_SZ;
    int* hp = hist + ((size_t)r * CHK) * NRG_SZ + li;
    int run = rowptr[i];
#pragma unroll
    for (int c = 0; c < CHK; c++) {
        int v = hp[(size_t)c * NRG_SZ];
        hp[(size_t)c * NRG_SZ] = run;
        run += v;
    }
}

__global__ __launch_bounds__(256) void fill2_k(
    const unsigned long long* __restrict__ bucket, const int* __restrict__ bstart,
    const int* __restrict__ hist, int* __restrict__ col) {
    __shared__ int cur[NRG_SZ];
    int b = blockIdx.x, r = b & 7, c2 = b >> 3, t = threadIdx.x;
    const int* hp = hist + ((size_t)r * CHK + c2) * NRG_SZ;
    for (int i = t; i < NRG_SZ; i += 256) cur[i] = hp[i];
    int s0 = bstart[r], s1 = bstart[r + 1];
    int ec = (s1 - s0 + CHK - 1) / CHK;
    int e0 = s0 + c2 * ec, e1 = min(s1, e0 + ec);
    __syncthreads();
    for (int e = e0 + t; e < e1; e += 256) {
        unsigned long long v = __builtin_nontemporal_load(bucket + e);
        int slot = atomicAdd(&cur[(int)(v >> 32)], 1);   // LDS atomic
        col[slot] = (int)(unsigned int)(v & 0xffffffffULL);
    }
}

// ---------------- GEMM: Y[r,:] = bf16((X[r,:] @ W) * dinv[r]) ----------------

template <int OUT>
__global__ __launch_bounds__(256) void gemm_scaled_k(
    const float* __restrict__ X, const float* __restrict__ W,
    const float* __restrict__ dinv, unsigned short* __restrict__ Y, int N) {
    constexpr int TR = 64;
    __shared__ __align__(16) float xs[TR][132];
    int t = threadIdx.x;
    int rowBase = blockIdx.x * TR;

    for (int i = t; i < TR * 32; i += 256) {
        int r = i >> 5, q = i & 31;
        int gr = rowBase + r;
        float4 v = make_float4(0.f, 0.f, 0.f, 0.f);
        if (gr < N) v = ((const float4*)(X + (size_t)gr * 128))[q];
        *(float4*)&xs[r][q * 4] = v;
    }
    __syncthreads();

    constexpr int CG = OUT / 8;
    constexpr int RPT = (TR * CG) / 256;
    int c0 = (t % CG) * 8;
    int r0 = (t / CG) * RPT;

    float acc[RPT][8];
#pragma unroll
    for (int j = 0; j < RPT; j++)
#pragma unroll
        for (int c = 0; c < 8; c++) acc[j][c] = 0.f;

#pragma unroll 4
    for (int k = 0; k < 128; k++) {
        float4 w0 = *(const float4*)(W + k * OUT + c0);
        float4 w1 = *(const float4*)(W + k * OUT + c0 + 4);
#pragma unroll
        for (int j = 0; j < RPT; j++) {
            float xv = xs[r0 + j][k];
            acc[j][0] = fmaf(xv, w0.x, acc[j][0]);
            acc[j][1] = fmaf(xv, w0.y, acc[j][1]);
            acc[j][2] = fmaf(xv, w0.z, acc[j][2]);
            acc[j][3] = fmaf(xv, w0.w, acc[j][3]);
            acc[j][4] = fmaf(xv, w1.x, acc[j][4]);
            acc[j][5] = fmaf(xv, w1.y, acc[j][5]);
            acc[j][6] = fmaf(xv, w1.z, acc[j][6]);
            acc[j][7] = fmaf(xv, w1.w, acc[j][7]);
        }
    }

#pragma unroll
    for (int j = 0; j < RPT; j++) {
        int gr = rowBase + r0 + j;
        if (gr < N) {
            float s = dinv[gr];
            unsigned short us[8];
#pragma unroll
            for (int c = 0; c < 8; c++) {
                __hip_bfloat16 hb = __float2bfloat16(acc[j][c] * s);
                us[c] = *(unsigned short*)&hb;
            }
            *(uint4*)(Y + (size_t)gr * OUT + c0) = *(uint4*)us;
        }
    }
}

// ---------------- aggregation: bf16 gather, fp32 accumulate ----------------

template <bool RELU>
__global__ __launch_bounds__(256) void agg128_k(
    const unsigned short* __restrict__ H,   // [N,128] bf16 hprime
    const int* __restrict__ rowptr, const int* __restrict__ col,
    const float* __restrict__ dinv, const float* __restrict__ bias,
    float* __restrict__ Y, int N) {
    int tid = threadIdx.x;
    int node = blockIdx.x * 4 + (tid >> 6);
    if (node >= N) return;
    int lane = tid & 63;
    int fo = lane * 2;

    float acc0, acc1;
    { ushort2 v = *(const ushort2*)(H + (size_t)node * 128 + fo);
      acc0 = b2f(v.x); acc1 = b2f(v.y); }

    int e = rowptr[node], end = rowptr[node + 1];
    for (; e + 4 <= end; e += 4) {
        int s0 = __builtin_nontemporal_load(col + e);
        int s1 = __builtin_nontemporal_load(col + e + 1);
        int s2 = __builtin_nontemporal_load(col + e + 2);
        int s3 = __builtin_nontemporal_load(col + e + 3);
        ushort2 a = *(const ushort2*)(H + (size_t)s0 * 128 + fo);
        ushort2 b = *(const ushort2*)(H + (size_t)s1 * 128 + fo);
        ushort2 c = *(const ushort2*)(H + (size_t)s2 * 128 + fo);
        ushort2 d = *(const ushort2*)(H + (size_t)s3 * 128 + fo);
        acc0 += (b2f(a.x) + b2f(b.x)) + (b2f(c.x) + b2f(d.x));
        acc1 += (b2f(a.y) + b2f(b.y)) + (b2f(c.y) + b2f(d.y));
    }
    for (; e < end; e++) {
        int s0 = __builtin_nontemporal_load(col + e);
        ushort2 a = *(const ushort2*)(H + (size_t)s0 * 128 + fo);
        acc0 += b2f(a.x); acc1 += b2f(a.y);
    }

    float dv = dinv[node];
    float2 bb = *(const float2*)(bias + fo);
    float o0 = acc0 * dv + bb.x;
    float o1 = acc1 * dv + bb.y;
    if (RELU) { o0 = fmaxf(o0, 0.f); o1 = fmaxf(o1, 0.f); }
    *(float2*)(Y + (size_t)node * 128 + fo) = make_float2(o0, o1);
}

// D=64, linear: half-wave (32 lanes) per node
__global__ __launch_bounds__(256) void agg64_k(
    const unsigned short* __restrict__ H,   // [N,64] bf16
    const int* __restrict__ rowptr, const int* __restrict__ col,
    const float* __restrict__ dinv, const float* __restrict__ bias,
    float* __restrict__ Y, int N) {
    int tid = threadIdx.x;
    int node = blockIdx.x * 8 + (tid >> 5);
    if (node >= N) return;
    int lane = tid & 31;
    int fo = lane * 2;

    float acc0, acc1;
    { ushort2 v = *(const ushort2*)(H + (size_t)node * 64 + fo);
      acc0 = b2f(v.x); acc1 = b2f(v.y); }

    int e = rowptr[node], end = rowptr[node + 1];
    for (; e + 4 <= end; e += 4) {
        int s0 = __builtin_nontemporal_load(col + e);
        int s1 = __builtin_nontemporal_load(col + e + 1);
        int s2 = __builtin_nontemporal_load(col + e + 2);
        int s3 = __builtin_nontemporal_load(col + e + 3);
        ushort2 a = *(const ushort2*)(H + (size_t)s0 * 64 + fo);
        ushort2 b = *(const ushort2*)(H + (size_t)s1 * 64 + fo);
        ushort2 c = *(const ushort2*)(H + (size_t)s2 * 64 + fo);
        ushort2 d = *(const ushort2*)(H + (size_t)s3 * 64 + fo);
        acc0 += (b2f(a.x) + b2f(b.x)) + (b2f(c.x) + b2f(d.x));
        acc1 += (b2f(a.y) + b2f(b.y)) + (b2f(c.y) + b2f(d.y));
    }
    for (; e < end; e++) {
        int s0 = __builtin_nontemporal_load(col + e);
        ushort2 a = *(const ushort2*)(H + (size_t)s0 * 64 + fo);
        acc0 += b2f(a.x); acc1 += b2f(a.y);
    }

    float dv = dinv[node];
    float2 bb = *(const float2*)(bias + fo);
    *(float2*)(Y + (size_t)node * 64 + fo) =
        make_float2(acc0 * dv + bb.x, acc1 * dv + bb.y);
}

// ---------------- fused actor/critic heads ----------------

template <int K, int OUT, int LDI, int LDO>
__device__ __forceinline__ void tile_mlp(const float (*xin)[LDI], float (*yout)[LDO],
                                         const float* __restrict__ W,
                                         const float* __restrict__ bias, int t) {
    constexpr int CG = OUT / 8;
    constexpr int RPT = (64 * CG) / 256;
    int c0 = (t % CG) * 8;
    int r0 = (t / CG) * RPT;
    float acc[RPT][8];
#pragma unroll
    for (int j = 0; j < RPT; j++)
#pragma unroll
        for (int c = 0; c < 8; c++) acc[j][c] = 0.f;
#pragma unroll 4
    for (int k = 0; k < K; k++) {
        float4 w0 = *(const float4*)(W + k * OUT + c0);
        float4 w1 = *(const float4*)(W + k * OUT + c0 + 4);
#pragma unroll
        for (int j = 0; j < RPT; j++) {
            float xv = xin[r0 + j][k];
            acc[j][0] = fmaf(xv, w0.x, acc[j][0]);
            acc[j][1] = fmaf(xv, w0.y, acc[j][1]);
            acc[j][2] = fmaf(xv, w0.z, acc[j][2]);
            acc[j][3] = fmaf(xv, w0.w, acc[j][3]);
            acc[j][4] = fmaf(xv, w1.x, acc[j][4]);
            acc[j][5] = fmaf(xv, w1.y, acc[j][5]);
            acc[j][6] = fmaf(xv, w1.z, acc[j][6]);
            acc[j][7] = fmaf(xv, w1.w, acc[j][7]);
        }
    }
#pragma unroll
    for (int j = 0; j < RPT; j++)
#pragma unroll
        for (int c = 0; c < 8; c++) {
            float v = acc[j][c] + bias[c0 + c];
            yout[r0 + j][c0 + c] = fmaxf(v, 0.f);
        }
}

__global__ __launch_bounds__(256) void heads_k(
    const float* __restrict__ H3,  // [N,64]
    const float* __restrict__ Wa1, const float* __restrict__ ba1,
    const float* __restrict__ Wa2, const float* __restrict__ ba2,
    const float* __restrict__ Wa3, const float* __restrict__ ba3,
    const float* __restrict__ Wc1, const float* __restrict__ bc1,
    const float* __restrict__ Wc2, const float* __restrict__ bc2,
    const float* __restrict__ Wc3, const float* __restrict__ bc3,
    float* __restrict__ out, int N) {
    constexpr int TN = 64;
    __shared__ __align__(16) float hs[TN][68];
    __shared__ float t1[TN][129];
    __shared__ float t2[TN][65];
    __shared__ float lg[TN][12];
    int t = threadIdx.x;
    int nodeBase = blockIdx.x * TN;

    for (int i = t; i < TN * 16; i += 256) {
        int r = i >> 4, q = i & 15;
        int gn = nodeBase + r;
        float4 v = make_float4(0.f, 0.f, 0.f, 0.f);
        if (gn < N) v = ((const float4*)(H3 + (size_t)gn * 64))[q];
        *(float4*)&hs[r][q * 4] = v;
    }
    __syncthreads();

    tile_mlp<64, 128, 68, 129>(hs, t1, Wc1, bc1, t);
    __syncthreads();
    tile_mlp<128, 64, 129, 65>(t1, t2, Wc2, bc2, t);
    __syncthreads();
    if (t < TN) {
        float s = bc3[0];
        for (int k = 0; k < 64; k++) s = fmaf(t2[t][k], Wc3[k], s);
        lg[t][8] = s;
    }
    tile_mlp<64, 128, 68, 129>(hs, t1, Wa1, ba1, t);
    __syncthreads();
    tile_mlp<128, 64, 129, 65>(t1, t2, Wa2, ba2, t);
    __syncthreads();
    if (t < TN) {
        float l[8];
#pragma unroll
        for (int c = 0; c < 8; c++) {
            float s = ba3[c];
            for (int k = 0; k < 64; k++) s = fmaf(t2[t][k], Wa3[k * 8 + c], s);
            l[c] = s;
        }
        float m = l[0];
#pragma unroll
        for (int c = 1; c < 8; c++) m = fmaxf(m, l[c]);
        float sum = 0.f;
#pragma unroll
        for (int c = 0; c < 8; c++) { l[c] = expf(l[c] - m); sum += l[c]; }
        float inv = 1.0f / sum;
#pragma unroll
        for (int c = 0; c < 8; c++) lg[t][c] = l[c] * inv;
    }
    __syncthreads();

    for (int i = t; i < TN * 9; i += 256) {
        int r = i / 9, c = i - r * 9;
        int gn = nodeBase + r;
        if (gn < N) out[(size_t)gn * 9 + c] = lg[r][c];
    }
}

// ---------------- launch ----------------

extern "C" void kernel_launch(void* const* d_in, const int* in_sizes, int n_in,
                              void* d_out, int out_size, void* d_ws, size_t ws_size,
                              hipStream_t stream) {
    const float* x   = (const float*)d_in[0];
    const int*   ei  = (const int*)d_in[1];
    const float* W1  = (const float*)d_in[2];  const float* b1  = (const float*)d_in[3];
    const float* W2  = (const float*)d_in[4];  const float* b2  = (const float*)d_in[5];
    const float* W3  = (const float*)d_in[6];  const float* b3  = (const float*)d_in[7];
    const float* Wa1 = (const float*)d_in[8];  const float* ba1 = (const float*)d_in[9];
    const float* Wa2 = (const float*)d_in[10]; const float* ba2 = (const float*)d_in[11];
    const float* Wa3 = (const float*)d_in[12]; const float* ba3 = (const float*)d_in[13];
    const float* Wc1 = (const float*)d_in[14]; const float* bc1 = (const float*)d_in[15];
    const float* Wc2 = (const float*)d_in[16]; const float* bc2 = (const float*)d_in[17];
    const float* Wc3 = (const float*)d_in[18]; const float* bc3 = (const float*)d_in[19];
    float* out = (float*)d_out;

    const int N = in_sizes[0] / 128;     // 100000
    const int E = in_sizes[1] / 2;       // 3200000
    const int* src = ei;
    const int* dst = ei + E;

    // workspace layout
    size_t off = 0;
    auto take = [&](size_t bytes) { size_t o = off; off = WS_ALIGN(off + bytes); return o; };
    char* ws = (char*)d_ws;
    float*          h      = (float*)(ws + take((size_t)N * 128 * 4));          // 51.2MB
    unsigned short* hprime = (unsigned short*)(ws + take((size_t)N * 128 * 2)); // 25.6MB
    float*          h3     = (float*)(ws + take((size_t)N * 64 * 4));           // 25.6MB
    int*            col    = (int*)(ws + take((size_t)E * 4));                  // 12.8MB
    float* dinv   = (float*)(ws + take((size_t)N * 4));
    int*   cnt    = (int*)  (ws + take((size_t)N * 4));
    int*   rowptr = (int*)  (ws + take((size_t)(N + 1) * 4));
    int*   bcnt   = (int*)  (ws + take(RNG * NB_A * 4));
    int*   base   = (int*)  (ws + take(RNG * NB_A * 4));
    int*   bstart = (int*)  (ws + take((RNG + 1) * 4));
    int*   bsum   = (int*)  (ws + take(512 * 4));
    int*   boff   = (int*)  (ws + take(512 * 4));
    // aliases into h (dead until agg L1): bucket 25.6MB + hist 12.8MB
    unsigned long long* bucket = (unsigned long long*)h;
    int* hist = (int*)((char*)h + (size_t)E * 8);
    (void)ws_size; (void)n_in; (void)out_size;

    const int nb  = (N + 255) / 256;     // 391 (<512)
    const int gN  = (N + 255) / 256;
    const int gT  = (N + 63) / 64;

    // CSR build: bucket sort (edges read 1x per phase, coalesced intermediate)
    bucket_count_k<<<NB_A, 256, 0, stream>>>(dst, bcnt, E);
    bucket_off_k<<<1, 1024, 0, stream>>>(bcnt, base, bstart, E);
    bucket_scatter_k<<<NB_A, 256, 0, stream>>>(src, dst, base, bucket, E);
    hist_bucket_k<<<RNG * CHK, 256, 0, stream>>>(bucket, bstart, hist);
    sum_hist_dinv_k<<<gN, 256, 0, stream>>>(hist, cnt, dinv, N);
    chunk_sum_k<<<nb, 256, 0, stream>>>(cnt, bsum, N);
    scan_mid_k<<<1, 512, 0, stream>>>(bsum, boff, nb, rowptr, N);
    scan_final_k<<<nb, 256, 0, stream>>>(cnt, boff, rowptr, N);
    offsets_k<<<gN, 256, 0, stream>>>(hist, rowptr, N);
    fill2_k<<<RNG * CHK, 256, 0, stream>>>(bucket, bstart, hist, col);

    // layer 1: 128 -> 128, relu
    gemm_scaled_k<128><<<gT, 256, 0, stream>>>(x, W1, dinv, hprime, N);
    agg128_k<true><<<(N + 3) / 4, 256, 0, stream>>>(hprime, rowptr, col, dinv, b1, h, N);
    // layer 2: 128 -> 128, relu
    gemm_scaled_k<128><<<gT, 256, 0, stream>>>(h, W2, dinv, hprime, N);
    agg128_k<true><<<(N + 3) / 4, 256, 0, stream>>>(hprime, rowptr, col, dinv, b2, h, N);
    // layer 3: 128 -> 64, linear
    gemm_scaled_k<64><<<gT, 256, 0, stream>>>(h, W3, dinv, hprime, N);
    agg64_k<<<(N + 7) / 8, 256, 0, stream>>>(hprime, rowptr, col, dinv, b3, h3, N);

    // heads
    heads_k<<<gT, 256, 0, stream>>>(h3, Wa1, ba1, Wa2, ba2, Wa3, ba3,
                                    Wc1, bc1, Wc2, bc2, Wc3, bc3, out, N);
}

// Round 4
// 970.089 us; speedup vs baseline: 1.5360x; 1.0325x over previous
//
#include <hip/hip_runtime.h>
#include <hip/hip_bf16.h>
#include <math.h>

// ---------------------------------------------------------------------------
// FederatedPPOAgent: 3x GCNConv (N=100k, E=3.2M, D=128) + actor/critic MLPs.
//
// R4 change vs R3: heads_k rewritten. R3 heads_k was latency-bound on global
// per-layer weight loads (VALUBusy 26.8%, 202us, W=32KB thrashing 32KB L1).
// Now: per-layer W staged into a reused LDS buffer with a bank-deswizzled
// layout (col-group g -> word (g>>1)*4 + (g&1)*ROW/2, making the 16-lane
// float4 weight reads 2-way/conflict-free), TN=32 node tile (LDS 67KB -> 2
// blocks/CU), and the logits/softmax tail parallelized over all 256 threads
// with shfl_xor softmax over the 8 action lanes.
// ---------------------------------------------------------------------------

#define WS_ALIGN(x) (((x) + 255) & ~(size_t)255)

constexpr int RNG    = 8;        // node ranges (XCD-affine via blockIdx&7)
constexpr int CHK    = 32;       // per-range fill chunks
constexpr int NRG_SZ = 12500;    // nodes per range (8*12500 = 100000 exactly)
constexpr int NB_A   = 256;      // bucket-phase blocks

__device__ __forceinline__ float b2f(unsigned short u) {
    return __uint_as_float(((unsigned int)u) << 16);
}

// ---------------- CSR build ----------------

__global__ __launch_bounds__(256) void bucket_count_k(
    const int* __restrict__ dst, int* __restrict__ bcnt, int E) {
    __shared__ int c8[RNG];
    int b = blockIdx.x, t = threadIdx.x;
    if (t < RNG) c8[t] = 0;
    __syncthreads();
    int ec = (E + NB_A - 1) / NB_A;
    int e0 = b * ec, e1 = min(E, e0 + ec);
    for (int e = e0 + t; e < e1; e += 256) {
        int d = __builtin_nontemporal_load(dst + e);
        atomicAdd(&c8[d / NRG_SZ], 1);
    }
    __syncthreads();
    if (t < RNG) bcnt[t * NB_A + b] = c8[t];
}

// 1 block, 1024 threads; scans RNG*NB_A = 2048 entries (r-major, b-minor)
__global__ void bucket_off_k(const int* __restrict__ bcnt, int* __restrict__ base,
                             int* __restrict__ bstart, int E) {
    __shared__ int s[RNG * NB_A];
    int t = threadIdx.x;
    s[t] = bcnt[t];
    s[t + 1024] = bcnt[t + 1024];
    __syncthreads();
    if (t == 0) {
        int run = 0;
        for (int i = 0; i < RNG * NB_A; i++) { int v = s[i]; s[i] = run; run += v; }
    }
    __syncthreads();
    base[t] = s[t];
    base[t + 1024] = s[t + 1024];
    if (t < RNG) bstart[t] = s[t * NB_A];
    if (t == 0) bstart[RNG] = E;
}

__global__ __launch_bounds__(256) void bucket_scatter_k(
    const int* __restrict__ src, const int* __restrict__ dst,
    const int* __restrict__ base, unsigned long long* __restrict__ bucket, int E) {
    __shared__ int cur[RNG];
    int b = blockIdx.x, t = threadIdx.x;
    if (t < RNG) cur[t] = base[t * NB_A + b];
    __syncthreads();
    int ec = (E + NB_A - 1) / NB_A;
    int e0 = b * ec, e1 = min(E, e0 + ec);
    for (int e = e0 + t; e < e1; e += 256) {
        int d = __builtin_nontemporal_load(dst + e);
        int sv = __builtin_nontemporal_load(src + e);
        int r = d / NRG_SZ;
        int pos = atomicAdd(&cur[r], 1);
        bucket[pos] = ((unsigned long long)(d - r * NRG_SZ) << 32) | (unsigned int)sv;
    }
}

__global__ __launch_bounds__(256) void hist_bucket_k(
    const unsigned long long* __restrict__ bucket, const int* __restrict__ bstart,
    int* __restrict__ hist) {
    __shared__ int h[NRG_SZ];
    int b = blockIdx.x, r = b & 7, c2 = b >> 3, t = threadIdx.x;
    for (int i = t; i < NRG_SZ; i += 256) h[i] = 0;
    int s0 = bstart[r], s1 = bstart[r + 1];
    int ec = (s1 - s0 + CHK - 1) / CHK;
    int e0 = s0 + c2 * ec, e1 = min(s1, e0 + ec);
    __syncthreads();
    for (int e = e0 + t; e < e1; e += 256) {
        unsigned long long v = __builtin_nontemporal_load(bucket + e);
        atomicAdd(&h[(int)(v >> 32)], 1);
    }
    __syncthreads();
    int* out = hist + ((size_t)r * CHK + c2) * NRG_SZ;
    for (int i = t; i < NRG_SZ; i += 256) out[i] = h[i];
}

__global__ void sum_hist_dinv_k(const int* __restrict__ hist, int* __restrict__ cnt,
                                float* __restrict__ dinv, int N) {
    int i = blockIdx.x * 256 + threadIdx.x;
    if (i >= N) return;
    int r = i / NRG_SZ, li = i - r * NRG_SZ;
    const int* hp = hist + ((size_t)r * CHK) * NRG_SZ + li;
    int s = 0;
#pragma unroll
    for (int c = 0; c < CHK; c++) s += hp[(size_t)c * NRG_SZ];
    cnt[i] = s;
    dinv[i] = rsqrtf((float)s + 1.0f);   // +1: self loop
}

__global__ void chunk_sum_k(const int* __restrict__ cnt, int* __restrict__ bsum, int n) {
    __shared__ int sd[256];
    int t = threadIdx.x;
    int i = blockIdx.x * 256 + t;
    sd[t] = (i < n) ? cnt[i] : 0;
    __syncthreads();
    for (int d = 128; d > 0; d >>= 1) {
        if (t < d) sd[t] += sd[t + d];
        __syncthreads();
    }
    if (t == 0) bsum[blockIdx.x] = sd[0];
}

// single block, 512 threads; nb <= 512
__global__ void scan_mid_k(const int* __restrict__ bsum, int* __restrict__ boff,
                           int nb, int* __restrict__ rowptr, int N) {
    __shared__ int s[512];
    int t = threadIdx.x;
    s[t] = (t < nb) ? bsum[t] : 0;
    __syncthreads();
    if (t == 0) {
        int run = 0;
        for (int i = 0; i < nb; i++) { int v = s[i]; s[i] = run; run += v; }
        rowptr[N] = run;
    }
    __syncthreads();
    if (t < nb) boff[t] = s[t];
}

__global__ void scan_final_k(const int* __restrict__ cnt, const int* __restrict__ boff,
                             int* __restrict__ rowptr, int n) {
    __shared__ int s[256];
    int t = threadIdx.x;
    int i = blockIdx.x * 256 + t;
    int v = (i < n) ? cnt[i] : 0;
    s[t] = v;
    __syncthreads();
    for (int d = 1; d < 256; d <<= 1) {
        int x = (t >= d) ? s[t - d] : 0;
        __syncthreads();
        s[t] += x;
        __syncthreads();
    }
    if (i < n) rowptr[i] = s[t] - v + boff[blockIdx.x];
}

// hist[r][c][li] -> exclusive running cursor = rowptr + prefix over chunks
__global__ void offsets_k(int* __restrict__ hist, const int* __restrict__ rowptr, int N) {
    int i = blockIdx.x * 256 + threadIdx.x;
    if (i >= N) return;
    int r = i / NRG_SZ, li = i - r * NRG_SZ;
    int* hp = hist + ((size_t)r * CHK) * NRG_SZ + li;
    int run = rowptr[i];
#pragma unroll
    for (int c = 0; c < CHK; c++) {
        int v = hp[(size_t)c * NRG_SZ];
        hp[(size_t)c * NRG_SZ] = run;
        run += v;
    }
}

__global__ __launch_bounds__(256) void fill2_k(
    const unsigned long long* __restrict__ bucket, const int* __restrict__ bstart,
    const int* __restrict__ hist, int* __restrict__ col) {
    __shared__ int cur[NRG_SZ];
    int b = blockIdx.x, r = b & 7, c2 = b >> 3, t = threadIdx.x;
    const int* hp = hist + ((size_t)r * CHK + c2) * NRG_SZ;
    for (int i = t; i < NRG_SZ; i += 256) cur[i] = hp[i];
    int s0 = bstart[r], s1 = bstart[r + 1];
    int ec = (s1 - s0 + CHK - 1) / CHK;
    int e0 = s0 + c2 * ec, e1 = min(s1, e0 + ec);
    __syncthreads();
    for (int e = e0 + t; e < e1; e += 256) {
        unsigned long long v = __builtin_nontemporal_load(bucket + e);
        int slot = atomicAdd(&cur[(int)(v >> 32)], 1);   // LDS atomic
        col[slot] = (int)(unsigned int)(v & 0xffffffffULL);
    }
}

// ---------------- GEMM: Y[r,:] = bf16((X[r,:] @ W) * dinv[r]) ----------------

template <int OUT>
__global__ __launch_bounds__(256) void gemm_scaled_k(
    const float* __restrict__ X, const float* __restrict__ W,
    const float* __restrict__ dinv, unsigned short* __restrict__ Y, int N) {
    constexpr int TR = 64;
    __shared__ __align__(16) float xs[TR][132];
    int t = threadIdx.x;
    int rowBase = blockIdx.x * TR;

    for (int i = t; i < TR * 32; i += 256) {
        int r = i >> 5, q = i & 31;
        int gr = rowBase + r;
        float4 v = make_float4(0.f, 0.f, 0.f, 0.f);
        if (gr < N) v = ((const float4*)(X + (size_t)gr * 128))[q];
        *(float4*)&xs[r][q * 4] = v;
    }
    __syncthreads();

    constexpr int CG = OUT / 8;
    constexpr int RPT = (TR * CG) / 256;
    int c0 = (t % CG) * 8;
    int r0 = (t / CG) * RPT;

    float acc[RPT][8];
#pragma unroll
    for (int j = 0; j < RPT; j++)
#pragma unroll
        for (int c = 0; c < 8; c++) acc[j][c] = 0.f;

#pragma unroll 4
    for (int k = 0; k < 128; k++) {
        float4 w0 = *(const float4*)(W + k * OUT + c0);
        float4 w1 = *(const float4*)(W + k * OUT + c0 + 4);
#pragma unroll
        for (int j = 0; j < RPT; j++) {
            float xv = xs[r0 + j][k];
            acc[j][0] = fmaf(xv, w0.x, acc[j][0]);
            acc[j][1] = fmaf(xv, w0.y, acc[j][1]);
            acc[j][2] = fmaf(xv, w0.z, acc[j][2]);
            acc[j][3] = fmaf(xv, w0.w, acc[j][3]);
            acc[j][4] = fmaf(xv, w1.x, acc[j][4]);
            acc[j][5] = fmaf(xv, w1.y, acc[j][5]);
            acc[j][6] = fmaf(xv, w1.z, acc[j][6]);
            acc[j][7] = fmaf(xv, w1.w, acc[j][7]);
        }
    }

#pragma unroll
    for (int j = 0; j < RPT; j++) {
        int gr = rowBase + r0 + j;
        if (gr < N) {
            float s = dinv[gr];
            unsigned short us[8];
#pragma unroll
            for (int c = 0; c < 8; c++) {
                __hip_bfloat16 hb = __float2bfloat16(acc[j][c] * s);
                us[c] = *(unsigned short*)&hb;
            }
            *(uint4*)(Y + (size_t)gr * OUT + c0) = *(uint4*)us;
        }
    }
}

// ---------------- aggregation: bf16 gather, fp32 accumulate ----------------

template <bool RELU>
__global__ __launch_bounds__(256) void agg128_k(
    const unsigned short* __restrict__ H,   // [N,128] bf16 hprime
    const int* __restrict__ rowptr, const int* __restrict__ col,
    const float* __restrict__ dinv, const float* __restrict__ bias,
    float* __restrict__ Y, int N) {
    int tid = threadIdx.x;
    int node = blockIdx.x * 4 + (tid >> 6);
    if (node >= N) return;
    int lane = tid & 63;
    int fo = lane * 2;

    float acc0, acc1;
    { ushort2 v = *(const ushort2*)(H + (size_t)node * 128 + fo);
      acc0 = b2f(v.x); acc1 = b2f(v.y); }

    int e = rowptr[node], end = rowptr[node + 1];
    for (; e + 4 <= end; e += 4) {
        int s0 = __builtin_nontemporal_load(col + e);
        int s1 = __builtin_nontemporal_load(col + e + 1);
        int s2 = __builtin_nontemporal_load(col + e + 2);
        int s3 = __builtin_nontemporal_load(col + e + 3);
        ushort2 a = *(const ushort2*)(H + (size_t)s0 * 128 + fo);
        ushort2 b = *(const ushort2*)(H + (size_t)s1 * 128 + fo);
        ushort2 c = *(const ushort2*)(H + (size_t)s2 * 128 + fo);
        ushort2 d = *(const ushort2*)(H + (size_t)s3 * 128 + fo);
        acc0 += (b2f(a.x) + b2f(b.x)) + (b2f(c.x) + b2f(d.x));
        acc1 += (b2f(a.y) + b2f(b.y)) + (b2f(c.y) + b2f(d.y));
    }
    for (; e < end; e++) {
        int s0 = __builtin_nontemporal_load(col + e);
        ushort2 a = *(const ushort2*)(H + (size_t)s0 * 128 + fo);
        acc0 += b2f(a.x); acc1 += b2f(a.y);
    }

    float dv = dinv[node];
    float2 bb = *(const float2*)(bias + fo);
    float o0 = acc0 * dv + bb.x;
    float o1 = acc1 * dv + bb.y;
    if (RELU) { o0 = fmaxf(o0, 0.f); o1 = fmaxf(o1, 0.f); }
    *(float2*)(Y + (size_t)node * 128 + fo) = make_float2(o0, o1);
}

// D=64, linear: half-wave (32 lanes) per node
__global__ __launch_bounds__(256) void agg64_k(
    const unsigned short* __restrict__ H,   // [N,64] bf16
    const int* __restrict__ rowptr, const int* __restrict__ col,
    const float* __restrict__ dinv, const float* __restrict__ bias,
    float* __restrict__ Y, int N) {
    int tid = threadIdx.x;
    int node = blockIdx.x * 8 + (tid >> 5);
    if (node >= N) return;
    int lane = tid & 31;
    int fo = lane * 2;

    float acc0, acc1;
    { ushort2 v = *(const ushort2*)(H + (size_t)node * 64 + fo);
      acc0 = b2f(v.x); acc1 = b2f(v.y); }

    int e = rowptr[node], end = rowptr[node + 1];
    for (; e + 4 <= end; e += 4) {
        int s0 = __builtin_nontemporal_load(col + e);
        int s1 = __builtin_nontemporal_load(col + e + 1);
        int s2 = __builtin_nontemporal_load(col + e + 2);
        int s3 = __builtin_nontemporal_load(col + e + 3);
        ushort2 a = *(const ushort2*)(H + (size_t)s0 * 64 + fo);
        ushort2 b = *(const ushort2*)(H + (size_t)s1 * 64 + fo);
        ushort2 c = *(const ushort2*)(H + (size_t)s2 * 64 + fo);
        ushort2 d = *(const ushort2*)(H + (size_t)s3 * 64 + fo);
        acc0 += (b2f(a.x) + b2f(b.x)) + (b2f(c.x) + b2f(d.x));
        acc1 += (b2f(a.y) + b2f(b.y)) + (b2f(c.y) + b2f(d.y));
    }
    for (; e < end; e++) {
        int s0 = __builtin_nontemporal_load(col + e);
        ushort2 a = *(const ushort2*)(H + (size_t)s0 * 64 + fo);
        acc0 += b2f(a.x); acc1 += b2f(a.y);
    }

    float dv = dinv[node];
    float2 bb = *(const float2*)(bias + fo);
    *(float2*)(Y + (size_t)node * 64 + fo) =
        make_float2(acc0 * dv + bb.x, acc1 * dv + bb.y);
}

// ---------------- fused actor/critic heads (R4) ----------------
// TN=32 nodes/block, 256 threads. Per-layer W staged into a reused LDS buffer
// with a bank-deswizzled layout.

constexpr int HTN = 32;

// W [64][128] -> wb, group g (=col/4) of row k stored at k*128 + (g&1)*64 + (g>>1)*4
__device__ __forceinline__ void stage_w128(float* wb, const float* __restrict__ W, int t) {
    for (int i = t; i < 2048; i += 256) {
        int k = i >> 5, g = i & 31;
        float4 v = *(const float4*)(W + i * 4);
        *(float4*)&wb[k * 128 + ((g & 1) << 6) + ((g >> 1) << 2)] = v;
    }
}
// W [128][64] -> wb, group g (=col/4) of row k at k*64 + (g&1)*32 + (g>>1)*4
__device__ __forceinline__ void stage_w64(float* wb, const float* __restrict__ W, int t) {
    for (int i = t; i < 2048; i += 256) {
        int k = i >> 4, g = i & 15;
        float4 v = *(const float4*)(W + i * 4);
        *(float4*)&wb[k * 64 + ((g & 1) << 5) + ((g >> 1) << 2)] = v;
    }
}

// K x 128 layer: xin[32][68], yout[32][132]. 16 col-groups x 2 rows/thread.
template <int K>
__device__ __forceinline__ void mlp128(const float (*xin)[68], float (*yout)[132],
                                       const float* __restrict__ wb,
                                       const float* __restrict__ bias, int t) {
    int c0 = (t & 15) * 8;
    int r0 = (t >> 4) * 2;
    int wo = c0 >> 1;                       // deswizzled read offset
    float acc[2][8];
#pragma unroll
    for (int j = 0; j < 2; j++)
#pragma unroll
        for (int c = 0; c < 8; c++) acc[j][c] = 0.f;
#pragma unroll 4
    for (int k = 0; k < K; k++) {
        float4 w0 = *(const float4*)&wb[k * 128 + wo];        // cols c0..c0+3
        float4 w1 = *(const float4*)&wb[k * 128 + wo + 64];   // cols c0+4..c0+7
        float x0 = xin[r0][k], x1 = xin[r0 + 1][k];
        acc[0][0] = fmaf(x0, w0.x, acc[0][0]); acc[0][1] = fmaf(x0, w0.y, acc[0][1]);
        acc[0][2] = fmaf(x0, w0.z, acc[0][2]); acc[0][3] = fmaf(x0, w0.w, acc[0][3]);
        acc[0][4] = fmaf(x0, w1.x, acc[0][4]); acc[0][5] = fmaf(x0, w1.y, acc[0][5]);
        acc[0][6] = fmaf(x0, w1.z, acc[0][6]); acc[0][7] = fmaf(x0, w1.w, acc[0][7]);
        acc[1][0] = fmaf(x1, w0.x, acc[1][0]); acc[1][1] = fmaf(x1, w0.y, acc[1][1]);
        acc[1][2] = fmaf(x1, w0.z, acc[1][2]); acc[1][3] = fmaf(x1, w0.w, acc[1][3]);
        acc[1][4] = fmaf(x1, w1.x, acc[1][4]); acc[1][5] = fmaf(x1, w1.y, acc[1][5]);
        acc[1][6] = fmaf(x1, w1.z, acc[1][6]); acc[1][7] = fmaf(x1, w1.w, acc[1][7]);
    }
    float4 b0 = *(const float4*)(bias + c0);
    float4 b1 = *(const float4*)(bias + c0 + 4);
#pragma unroll
    for (int j = 0; j < 2; j++) {
        float4 o0 = make_float4(fmaxf(acc[j][0] + b0.x, 0.f), fmaxf(acc[j][1] + b0.y, 0.f),
                                fmaxf(acc[j][2] + b0.z, 0.f), fmaxf(acc[j][3] + b0.w, 0.f));
        float4 o1 = make_float4(fmaxf(acc[j][4] + b1.x, 0.f), fmaxf(acc[j][5] + b1.y, 0.f),
                                fmaxf(acc[j][6] + b1.z, 0.f), fmaxf(acc[j][7] + b1.w, 0.f));
        *(float4*)&yout[r0 + j][c0] = o0;
        *(float4*)&yout[r0 + j][c0 + 4] = o1;
    }
}

// 128 x 64 layer: xin[32][132], yout[32][68]. 8 col-groups x 1 row/thread.
__device__ __forceinline__ void mlp64(const float (*xin)[132], float (*yout)[68],
                                      const float* __restrict__ wb,
                                      const float* __restrict__ bias, int t) {
    int c0 = (t & 7) * 8;
    int r0 = t >> 3;
    int wo = c0 >> 1;
    float acc[8];
#pragma unroll
    for (int c = 0; c < 8; c++) acc[c] = 0.f;
#pragma unroll 4
    for (int k = 0; k < 128; k++) {
        float4 w0 = *(const float4*)&wb[k * 64 + wo];
        float4 w1 = *(const float4*)&wb[k * 64 + wo + 32];
        float xv = xin[r0][k];
        acc[0] = fmaf(xv, w0.x, acc[0]); acc[1] = fmaf(xv, w0.y, acc[1]);
        acc[2] = fmaf(xv, w0.z, acc[2]); acc[3] = fmaf(xv, w0.w, acc[3]);
        acc[4] = fmaf(xv, w1.x, acc[4]); acc[5] = fmaf(xv, w1.y, acc[5]);
        acc[6] = fmaf(xv, w1.z, acc[6]); acc[7] = fmaf(xv, w1.w, acc[7]);
    }
    float4 b0 = *(const float4*)(bias + c0);
    float4 b1 = *(const float4*)(bias + c0 + 4);
    float4 o0 = make_float4(fmaxf(acc[0] + b0.x, 0.f), fmaxf(acc[1] + b0.y, 0.f),
                            fmaxf(acc[2] + b0.z, 0.f), fmaxf(acc[3] + b0.w, 0.f));
    float4 o1 = make_float4(fmaxf(acc[4] + b1.x, 0.f), fmaxf(acc[5] + b1.y, 0.f),
                            fmaxf(acc[6] + b1.z, 0.f), fmaxf(acc[7] + b1.w, 0.f));
    *(float4*)&yout[r0][c0] = o0;
    *(float4*)&yout[r0][c0 + 4] = o1;
}

__global__ __launch_bounds__(256) void heads_k(
    const float* __restrict__ H3,  // [N,64]
    const float* __restrict__ Wa1, const float* __restrict__ ba1,
    const float* __restrict__ Wa2, const float* __restrict__ ba2,
    const float* __restrict__ Wa3, const float* __restrict__ ba3,
    const float* __restrict__ Wc1, const float* __restrict__ bc1,
    const float* __restrict__ Wc2, const float* __restrict__ bc2,
    const float* __restrict__ Wc3, const float* __restrict__ bc3,
    float* __restrict__ out, int N) {
    __shared__ __align__(16) float hs[HTN][68];
    __shared__ __align__(16) float t1[HTN][132];
    __shared__ __align__(16) float t2[HTN][68];
    __shared__ __align__(16) float wb[8192];
    __shared__ float lg[HTN][12];
    int t = threadIdx.x;
    int nodeBase = blockIdx.x * HTN;

    // stage h3 tile (32 x 64): 512 float4
    for (int i = t; i < HTN * 16; i += 256) {
        int r = i >> 4, q = i & 15;
        int gn = nodeBase + r;
        float4 v = make_float4(0.f, 0.f, 0.f, 0.f);
        if (gn < N) v = ((const float4*)(H3 + (size_t)gn * 64))[q];
        *(float4*)&hs[r][q * 4] = v;
    }
    stage_w128(wb, Wc1, t);
    __syncthreads();
    mlp128<64>(hs, t1, wb, bc1, t);          // critic layer 1
    __syncthreads();                          // t1 ready, wb reads done
    stage_w64(wb, Wc2, t);
    __syncthreads();
    mlp64(t1, t2, wb, bc2, t);                // critic layer 2
    __syncthreads();                          // t2 ready, wb reads done
    if (t < HTN) {                            // value head (OUT=1)
        float s = bc3[0];
        for (int k = 0; k < 64; k++) s = fmaf(t2[t][k], Wc3[k], s);
        lg[t][8] = s;
    }
    stage_w128(wb, Wa1, t);
    __syncthreads();
    mlp128<64>(hs, t1, wb, ba1, t);           // actor layer 1
    __syncthreads();
    stage_w64(wb, Wa2, t);
    __syncthreads();
    mlp64(t1, t2, wb, ba2, t);                // actor layer 2
    __syncthreads();
    {   // logits: thread = node*8 + action; softmax over the 8 action lanes
        int node = t >> 3, c = t & 7;
        float s = ba3[c];
        for (int k = 0; k < 64; k++) s = fmaf(t2[node][k], Wa3[k * 8 + c], s);
        float m = s;
#pragma unroll
        for (int w = 1; w < 8; w <<= 1) m = fmaxf(m, __shfl_xor(m, w, 64));
        float e = expf(s - m);
        float sum = e;
#pragma unroll
        for (int w = 1; w < 8; w <<= 1) sum += __shfl_xor(sum, w, 64);
        lg[node][c] = e / sum;
    }
    __syncthreads();

    // coalesced store of [32 x 9]
    for (int i = t; i < HTN * 9; i += 256) {
        int r = i / 9, c = i - r * 9;
        int gn = nodeBase + r;
        if (gn < N) out[(size_t)gn * 9 + c] = lg[r][c];
    }
}

// ---------------- launch ----------------

extern "C" void kernel_launch(void* const* d_in, const int* in_sizes, int n_in,
                              void* d_out, int out_size, void* d_ws, size_t ws_size,
                              hipStream_t stream) {
    const float* x   = (const float*)d_in[0];
    const int*   ei  = (const int*)d_in[1];
    const float* W1  = (const float*)d_in[2];  const float* b1  = (const float*)d_in[3];
    const float* W2  = (const float*)d_in[4];  const float* b2  = (const float*)d_in[5];
    const float* W3  = (const float*)d_in[6];  const float* b3  = (const float*)d_in[7];
    const float* Wa1 = (const float*)d_in[8];  const float* ba1 = (const float*)d_in[9];
    const float* Wa2 = (const float*)d_in[10]; const float* ba2 = (const float*)d_in[11];
    const float* Wa3 = (const float*)d_in[12]; const float* ba3 = (const float*)d_in[13];
    const float* Wc1 = (const float*)d_in[14]; const float* bc1 = (const float*)d_in[15];
    const float* Wc2 = (const float*)d_in[16]; const float* bc2 = (const float*)d_in[17];
    const float* Wc3 = (const float*)d_in[18]; const float* bc3 = (const float*)d_in[19];
    float* out = (float*)d_out;

    const int N = in_sizes[0] / 128;     // 100000
    const int E = in_sizes[1] / 2;       // 3200000
    const int* src = ei;
    const int* dst = ei + E;

    // workspace layout
    size_t off = 0;
    auto take = [&](size_t bytes) { size_t o = off; off = WS_ALIGN(off + bytes); return o; };
    char* ws = (char*)d_ws;
    float*          h      = (float*)(ws + take((size_t)N * 128 * 4));          // 51.2MB
    unsigned short* hprime = (unsigned short*)(ws + take((size_t)N * 128 * 2)); // 25.6MB
    float*          h3     = (float*)(ws + take((size_t)N * 64 * 4));           // 25.6MB
    int*            col    = (int*)(ws + take((size_t)E * 4));                  // 12.8MB
    float* dinv   = (float*)(ws + take((size_t)N * 4));
    int*   cnt    = (int*)  (ws + take((size_t)N * 4));
    int*   rowptr = (int*)  (ws + take((size_t)(N + 1) * 4));
    int*   bcnt   = (int*)  (ws + take(RNG * NB_A * 4));
    int*   base   = (int*)  (ws + take(RNG * NB_A * 4));
    int*   bstart = (int*)  (ws + take((RNG + 1) * 4));
    int*   bsum   = (int*)  (ws + take(512 * 4));
    int*   boff   = (int*)  (ws + take(512 * 4));
    // aliases into h (dead until agg L1): bucket 25.6MB + hist 12.8MB
    unsigned long long* bucket = (unsigned long long*)h;
    int* hist = (int*)((char*)h + (size_t)E * 8);
    (void)ws_size; (void)n_in; (void)out_size;

    const int nb  = (N + 255) / 256;     // 391 (<512)
    const int gN  = (N + 255) / 256;
    const int gT  = (N + 63) / 64;

    // CSR build: bucket sort (edges read 1x per phase, coalesced intermediate)
    bucket_count_k<<<NB_A, 256, 0, stream>>>(dst, bcnt, E);
    bucket_off_k<<<1, 1024, 0, stream>>>(bcnt, base, bstart, E);
    bucket_scatter_k<<<NB_A, 256, 0, stream>>>(src, dst, base, bucket, E);
    hist_bucket_k<<<RNG * CHK, 256, 0, stream>>>(bucket, bstart, hist);
    sum_hist_dinv_k<<<gN, 256, 0, stream>>>(hist, cnt, dinv, N);
    chunk_sum_k<<<nb, 256, 0, stream>>>(cnt, bsum, N);
    scan_mid_k<<<1, 512, 0, stream>>>(bsum, boff, nb, rowptr, N);
    scan_final_k<<<nb, 256, 0, stream>>>(cnt, boff, rowptr, N);
    offsets_k<<<gN, 256, 0, stream>>>(hist, rowptr, N);
    fill2_k<<<RNG * CHK, 256, 0, stream>>>(bucket, bstart, hist, col);

    // layer 1: 128 -> 128, relu
    gemm_scaled_k<128><<<gT, 256, 0, stream>>>(x, W1, dinv, hprime, N);
    agg128_k<true><<<(N + 3) / 4, 256, 0, stream>>>(hprime, rowptr, col, dinv, b1, h, N);
    // layer 2: 128 -> 128, relu
    gemm_scaled_k<128><<<gT, 256, 0, stream>>>(h, W2, dinv, hprime, N);
    agg128_k<true><<<(N + 3) / 4, 256, 0, stream>>>(hprime, rowptr, col, dinv, b2, h, N);
    // layer 3: 128 -> 64, linear
    gemm_scaled_k<64><<<gT, 256, 0, stream>>>(h, W3, dinv, hprime, N);
    agg64_k<<<(N + 7) / 8, 256, 0, stream>>>(hprime, rowptr, col, dinv, b3, h3, N);

    // heads
    heads_k<<<(N + HTN - 1) / HTN, 256, 0, stream>>>(h3, Wa1, ba1, Wa2, ba2, Wa3, ba3,
                                                     Wc1, bc1, Wc2, bc2, Wc3, bc3, out, N);
}

// Round 5
// 758.199 us; speedup vs baseline: 1.9652x; 1.2795x over previous
//
#include <hip/hip_runtime.h>
#include <hip/hip_bf16.h>
#include <math.h>

// ---------------------------------------------------------------------------
// FederatedPPOAgent: 3x GCNConv (N=100k, E=3.2M, D=128) + actor/critic MLPs.
//
// R5 changes vs R4: all GEMM-shaped compute moved to MFMA bf16 (fp32 acc).
//  - prep_w_k: the 7 layer weights -> bf16 W^T[n][k] once per call.
//  - gemm_mfma_k<K,OUT,AF32,BIAS_RELU>: BM=64 rows/block, 4 waves x 16-row
//    strips, mfma_f32_16x16x32_bf16, A/B in LDS, epilogue = *dinv[row] (GCN)
//    or bias+relu (heads), bf16 output. Replaces gemm_scaled_k AND the fused
//    heads chain (R4 heads_k was LDS/latency-capped at VALUBusy 39%, 161us;
//    MFMA floor for the same FLOPs is ~3us/layer).
//  - h, h3, head intermediates stored bf16 (R3 showed bf16 storage costs no
//    measurable absmax; threshold 2.5e-3, measured 3.8e-6).
//  - logits_k: tiny tail (64x8 logits + softmax via shfl_xor + 64-dot value).
// CSR build (bucket sort, R3) and agg kernels unchanged except bf16 output.
// ---------------------------------------------------------------------------

#define WS_ALIGN(x) (((x) + 255) & ~(size_t)255)

constexpr int RNG    = 8;        // node ranges
constexpr int CHK    = 32;       // per-range fill chunks
constexpr int NRG_SZ = 12500;    // nodes per range (8*12500 = 100000 exactly)
constexpr int NB_A   = 256;      // bucket-phase blocks

using bf16x8 = __attribute__((ext_vector_type(8))) short;   // 8 bf16 (4 VGPRs)
using f32x4  = __attribute__((ext_vector_type(4))) float;   // mfma C/D

__device__ __forceinline__ float b2f(unsigned short u) {
    return __uint_as_float(((unsigned int)u) << 16);
}
__device__ __forceinline__ unsigned short f2b(float f) {
    __hip_bfloat16 hb = __float2bfloat16(f);
    return *(unsigned short*)&hb;
}

// ---------------- CSR build (unchanged from R3/R4) ----------------

__global__ __launch_bounds__(256) void bucket_count_k(
    const int* __restrict__ dst, int* __restrict__ bcnt, int E) {
    __shared__ int c8[RNG];
    int b = blockIdx.x, t = threadIdx.x;
    if (t < RNG) c8[t] = 0;
    __syncthreads();
    int ec = (E + NB_A - 1) / NB_A;
    int e0 = b * ec, e1 = min(E, e0 + ec);
    for (int e = e0 + t; e < e1; e += 256) {
        int d = __builtin_nontemporal_load(dst + e);
        atomicAdd(&c8[d / NRG_SZ], 1);
    }
    __syncthreads();
    if (t < RNG) bcnt[t * NB_A + b] = c8[t];
}

__global__ void bucket_off_k(const int* __restrict__ bcnt, int* __restrict__ base,
                             int* __restrict__ bstart, int E) {
    __shared__ int s[RNG * NB_A];
    int t = threadIdx.x;
    s[t] = bcnt[t];
    s[t + 1024] = bcnt[t + 1024];
    __syncthreads();
    if (t == 0) {
        int run = 0;
        for (int i = 0; i < RNG * NB_A; i++) { int v = s[i]; s[i] = run; run += v; }
    }
    __syncthreads();
    base[t] = s[t];
    base[t + 1024] = s[t + 1024];
    if (t < RNG) bstart[t] = s[t * NB_A];
    if (t == 0) bstart[RNG] = E;
}

__global__ __launch_bounds__(256) void bucket_scatter_k(
    const int* __restrict__ src, const int* __restrict__ dst,
    const int* __restrict__ base, unsigned long long* __restrict__ bucket, int E) {
    __shared__ int cur[RNG];
    int b = blockIdx.x, t = threadIdx.x;
    if (t < RNG) cur[t] = base[t * NB_A + b];
    __syncthreads();
    int ec = (E + NB_A - 1) / NB_A;
    int e0 = b * ec, e1 = min(E, e0 + ec);
    for (int e = e0 + t; e < e1; e += 256) {
        int d = __builtin_nontemporal_load(dst + e);
        int sv = __builtin_nontemporal_load(src + e);
        int r = d / NRG_SZ;
        int pos = atomicAdd(&cur[r], 1);
        bucket[pos] = ((unsigned long long)(d - r * NRG_SZ) << 32) | (unsigned int)sv;
    }
}

__global__ __launch_bounds__(256) void hist_bucket_k(
    const unsigned long long* __restrict__ bucket, const int* __restrict__ bstart,
    int* __restrict__ hist) {
    __shared__ int h[NRG_SZ];
    int b = blockIdx.x, r = b & 7, c2 = b >> 3, t = threadIdx.x;
    for (int i = t; i < NRG_SZ; i += 256) h[i] = 0;
    int s0 = bstart[r], s1 = bstart[r + 1];
    int ec = (s1 - s0 + CHK - 1) / CHK;
    int e0 = s0 + c2 * ec, e1 = min(s1, e0 + ec);
    __syncthreads();
    for (int e = e0 + t; e < e1; e += 256) {
        unsigned long long v = __builtin_nontemporal_load(bucket + e);
        atomicAdd(&h[(int)(v >> 32)], 1);
    }
    __syncthreads();
    int* out = hist + ((size_t)r * CHK + c2) * NRG_SZ;
    for (int i = t; i < NRG_SZ; i += 256) out[i] = h[i];
}

__global__ void sum_hist_dinv_k(const int* __restrict__ hist, int* __restrict__ cnt,
                                float* __restrict__ dinv, int N) {
    int i = blockIdx.x * 256 + threadIdx.x;
    if (i >= N) return;
    int r = i / NRG_SZ, li = i - r * NRG_SZ;
    const int* hp = hist + ((size_t)r * CHK) * NRG_SZ + li;
    int s = 0;
#pragma unroll
    for (int c = 0; c < CHK; c++) s += hp[(size_t)c * NRG_SZ];
    cnt[i] = s;
    dinv[i] = rsqrtf((float)s + 1.0f);   // +1: self loop
}

__global__ void chunk_sum_k(const int* __restrict__ cnt, int* __restrict__ bsum, int n) {
    __shared__ int sd[256];
    int t = threadIdx.x;
    int i = blockIdx.x * 256 + t;
    sd[t] = (i < n) ? cnt[i] : 0;
    __syncthreads();
    for (int d = 128; d > 0; d >>= 1) {
        if (t < d) sd[t] += sd[t + d];
        __syncthreads();
    }
    if (t == 0) bsum[blockIdx.x] = sd[0];
}

__global__ void scan_mid_k(const int* __restrict__ bsum, int* __restrict__ boff,
                           int nb, int* __restrict__ rowptr, int N) {
    __shared__ int s[512];
    int t = threadIdx.x;
    s[t] = (t < nb) ? bsum[t] : 0;
    __syncthreads();
    if (t == 0) {
        int run = 0;
        for (int i = 0; i < nb; i++) { int v = s[i]; s[i] = run; run += v; }
        rowptr[N] = run;
    }
    __syncthreads();
    if (t < nb) boff[t] = s[t];
}

__global__ void scan_final_k(const int* __restrict__ cnt, const int* __restrict__ boff,
                             int* __restrict__ rowptr, int n) {
    __shared__ int s[256];
    int t = threadIdx.x;
    int i = blockIdx.x * 256 + t;
    int v = (i < n) ? cnt[i] : 0;
    s[t] = v;
    __syncthreads();
    for (int d = 1; d < 256; d <<= 1) {
        int x = (t >= d) ? s[t - d] : 0;
        __syncthreads();
        s[t] += x;
        __syncthreads();
    }
    if (i < n) rowptr[i] = s[t] - v + boff[blockIdx.x];
}

__global__ void offsets_k(int* __restrict__ hist, const int* __restrict__ rowptr, int N) {
    int i = blockIdx.x * 256 + threadIdx.x;
    if (i >= N) return;
    int r = i / NRG_SZ, li = i - r * NRG_SZ;
    int* hp = hist + ((size_t)r * CHK) * NRG_SZ + li;
    int run = rowptr[i];
#pragma unroll
    for (int c = 0; c < CHK; c++) {
        int v = hp[(size_t)c * NRG_SZ];
        hp[(size_t)c * NRG_SZ] = run;
        run += v;
    }
}

__global__ __launch_bounds__(256) void fill2_k(
    const unsigned long long* __restrict__ bucket, const int* __restrict__ bstart,
    const int* __restrict__ hist, int* __restrict__ col) {
    __shared__ int cur[NRG_SZ];
    int b = blockIdx.x, r = b & 7, c2 = b >> 3, t = threadIdx.x;
    const int* hp = hist + ((size_t)r * CHK + c2) * NRG_SZ;
    for (int i = t; i < NRG_SZ; i += 256) cur[i] = hp[i];
    int s0 = bstart[r], s1 = bstart[r + 1];
    int ec = (s1 - s0 + CHK - 1) / CHK;
    int e0 = s0 + c2 * ec, e1 = min(s1, e0 + ec);
    __syncthreads();
    for (int e = e0 + t; e < e1; e += 256) {
        unsigned long long v = __builtin_nontemporal_load(bucket + e);
        int slot = atomicAdd(&cur[(int)(v >> 32)], 1);   // LDS atomic
        col[slot] = (int)(unsigned int)(v & 0xffffffffULL);
    }
}

// ---------------- weight prep: fp32 W[K][OUT] -> bf16 W^T[OUT][K] ----------------

__global__ __launch_bounds__(256) void prep_w_k(
    const float* __restrict__ W1, const float* __restrict__ W2,
    const float* __restrict__ W3, const float* __restrict__ Wa1,
    const float* __restrict__ Wa2, const float* __restrict__ Wc1,
    const float* __restrict__ Wc2, unsigned short* __restrict__ wt) {
    int i = blockIdx.x * 256 + threadIdx.x;   // 0..73727
    const float* W; int off, K, OUT;
    if (i < 16384)      { W = W1;  off = 0;     K = 128; OUT = 128; }
    else if (i < 32768) { W = W2;  off = 16384; K = 128; OUT = 128; }
    else if (i < 40960) { W = W3;  off = 32768; K = 128; OUT = 64; }
    else if (i < 49152) { W = Wa1; off = 40960; K = 64;  OUT = 128; }
    else if (i < 57344) { W = Wa2; off = 49152; K = 128; OUT = 64; }
    else if (i < 65536) { W = Wc1; off = 57344; K = 64;  OUT = 128; }
    else                { W = Wc2; off = 65536; K = 128; OUT = 64; }
    int j = i - off, k = j / OUT, n = j - k * OUT;
    wt[off + n * K + k] = f2b(W[j]);
}

// ---------------- MFMA GEMM: Y = epi(X @ W) as bf16 ----------------
// BM=64 rows/block, 256 threads = 4 waves, wave w -> rows w*16..w*16+15.
// epi: BIAS_RELU ? relu(. + bias[col]) : . * dinv[row].

template <int K, int OUT, bool AF32, bool BIAS_RELU>
__global__ __launch_bounds__(256) void gemm_mfma_k(
    const void* __restrict__ Xv, const unsigned short* __restrict__ Wt,  // [OUT][K]
    const float* __restrict__ sb,   // dinv[N] or bias[OUT]
    unsigned short* __restrict__ Y, int N) {
    constexpr int LDK = K + 8;                    // shorts; rows stay 16B aligned
    __shared__ __align__(16) unsigned short As[64 * LDK];
    __shared__ __align__(16) unsigned short Bs[OUT * LDK];
    int t = threadIdx.x;
    int rowBase = blockIdx.x * 64;

    if constexpr (AF32) {
        const float* X = (const float*)Xv;
        for (int g = t; g < 64 * (K / 8); g += 256) {
            int r = g / (K / 8), q = g - r * (K / 8);
            int gr = rowBase + r;
            unsigned short us[8];
            if (gr < N) {
                float4 v0 = *(const float4*)(X + (size_t)gr * K + q * 8);
                float4 v1 = *(const float4*)(X + (size_t)gr * K + q * 8 + 4);
                us[0] = f2b(v0.x); us[1] = f2b(v0.y); us[2] = f2b(v0.z); us[3] = f2b(v0.w);
                us[4] = f2b(v1.x); us[5] = f2b(v1.y); us[6] = f2b(v1.z); us[7] = f2b(v1.w);
            } else {
#pragma unroll
                for (int j = 0; j < 8; j++) us[j] = 0;
            }
            *(uint4*)&As[r * LDK + q * 8] = *(uint4*)us;
        }
    } else {
        const unsigned short* X = (const unsigned short*)Xv;
        for (int g = t; g < 64 * (K / 8); g += 256) {
            int r = g / (K / 8), q = g - r * (K / 8);
            int gr = rowBase + r;
            uint4 v = make_uint4(0, 0, 0, 0);
            if (gr < N) v = *(const uint4*)(X + (size_t)gr * K + q * 8);
            *(uint4*)&As[r * LDK + q * 8] = v;
        }
    }
    for (int g = t; g < OUT * (K / 8); g += 256) {
        int r = g / (K / 8), q = g - r * (K / 8);
        *(uint4*)&Bs[r * LDK + q * 8] = *(const uint4*)(Wt + r * K + q * 8);
    }
    __syncthreads();

    int wv = t >> 6, lane = t & 63;
    int lm = lane & 15, lq = lane >> 4;
    constexpr int CT = OUT / 16;
    f32x4 acc[CT];
#pragma unroll
    for (int c = 0; c < CT; c++) acc[c] = (f32x4){0.f, 0.f, 0.f, 0.f};

    const unsigned short* arow = &As[(wv * 16 + lm) * LDK + lq * 8];
#pragma unroll
    for (int kt = 0; kt < K / 32; kt++) {
        bf16x8 a = *(const bf16x8*)(arow + kt * 32);
#pragma unroll
        for (int c = 0; c < CT; c++) {
            bf16x8 b = *(const bf16x8*)&Bs[(c * 16 + lm) * LDK + kt * 32 + lq * 8];
            acc[c] = __builtin_amdgcn_mfma_f32_16x16x32_bf16(a, b, acc[c], 0, 0, 0);
        }
    }

    // epilogue: C/D layout col=lane&15, row=(lane>>4)*4+reg  [m89/m91-verified]
    int r0 = rowBase + wv * 16 + lq * 4;
#pragma unroll
    for (int r = 0; r < 4; r++) {
        int gr = r0 + r;
        if (gr < N) {
            float scale = 1.f;
            if constexpr (!BIAS_RELU) scale = sb[gr];
#pragma unroll
            for (int c = 0; c < CT; c++) {
                int colg = c * 16 + lm;
                float v = acc[c][r];
                if constexpr (BIAS_RELU) v = fmaxf(v + sb[colg], 0.f);
                else v = v * scale;
                Y[(size_t)gr * OUT + colg] = f2b(v);
            }
        }
    }
}

// ---------------- aggregation: bf16 gather, fp32 accumulate, bf16 out ----------------

template <bool RELU>
__global__ __launch_bounds__(256) void agg128_k(
    const unsigned short* __restrict__ H,   // [N,128] bf16 hprime
    const int* __restrict__ rowptr, const int* __restrict__ col,
    const float* __restrict__ dinv, const float* __restrict__ bias,
    unsigned short* __restrict__ Y, int N) {
    int tid = threadIdx.x;
    int node = blockIdx.x * 4 + (tid >> 6);
    if (node >= N) return;
    int lane = tid & 63;
    int fo = lane * 2;

    float acc0, acc1;
    { ushort2 v = *(const ushort2*)(H + (size_t)node * 128 + fo);
      acc0 = b2f(v.x); acc1 = b2f(v.y); }

    int e = rowptr[node], end = rowptr[node + 1];
    for (; e + 4 <= end; e += 4) {
        int s0 = __builtin_nontemporal_load(col + e);
        int s1 = __builtin_nontemporal_load(col + e + 1);
        int s2 = __builtin_nontemporal_load(col + e + 2);
        int s3 = __builtin_nontemporal_load(col + e + 3);
        ushort2 a = *(const ushort2*)(H + (size_t)s0 * 128 + fo);
        ushort2 b = *(const ushort2*)(H + (size_t)s1 * 128 + fo);
        ushort2 c = *(const ushort2*)(H + (size_t)s2 * 128 + fo);
        ushort2 d = *(const ushort2*)(H + (size_t)s3 * 128 + fo);
        acc0 += (b2f(a.x) + b2f(b.x)) + (b2f(c.x) + b2f(d.x));
        acc1 += (b2f(a.y) + b2f(b.y)) + (b2f(c.y) + b2f(d.y));
    }
    for (; e < end; e++) {
        int s0 = __builtin_nontemporal_load(col + e);
        ushort2 a = *(const ushort2*)(H + (size_t)s0 * 128 + fo);
        acc0 += b2f(a.x); acc1 += b2f(a.y);
    }

    float dv = dinv[node];
    float2 bb = *(const float2*)(bias + fo);
    float o0 = acc0 * dv + bb.x;
    float o1 = acc1 * dv + bb.y;
    if (RELU) { o0 = fmaxf(o0, 0.f); o1 = fmaxf(o1, 0.f); }
    *(ushort2*)(Y + (size_t)node * 128 + fo) = make_ushort2(f2b(o0), f2b(o1));
}

// D=64, linear: half-wave (32 lanes) per node
__global__ __launch_bounds__(256) void agg64_k(
    const unsigned short* __restrict__ H,   // [N,64] bf16
    const int* __restrict__ rowptr, const int* __restrict__ col,
    const float* __restrict__ dinv, const float* __restrict__ bias,
    unsigned short* __restrict__ Y, int N) {
    int tid = threadIdx.x;
    int node = blockIdx.x * 8 + (tid >> 5);
    if (node >= N) return;
    int lane = tid & 31;
    int fo = lane * 2;

    float acc0, acc1;
    { ushort2 v = *(const ushort2*)(H + (size_t)node * 64 + fo);
      acc0 = b2f(v.x); acc1 = b2f(v.y); }

    int e = rowptr[node], end = rowptr[node + 1];
    for (; e + 4 <= end; e += 4) {
        int s0 = __builtin_nontemporal_load(col + e);
        int s1 = __builtin_nontemporal_load(col + e + 1);
        int s2 = __builtin_nontemporal_load(col + e + 2);
        int s3 = __builtin_nontemporal_load(col + e + 3);
        ushort2 a = *(const ushort2*)(H + (size_t)s0 * 64 + fo);
        ushort2 b = *(const ushort2*)(H + (size_t)s1 * 64 + fo);
        ushort2 c = *(const ushort2*)(H + (size_t)s2 * 64 + fo);
        ushort2 d = *(const ushort2*)(H + (size_t)s3 * 64 + fo);
        acc0 += (b2f(a.x) + b2f(b.x)) + (b2f(c.x) + b2f(d.x));
        acc1 += (b2f(a.y) + b2f(b.y)) + (b2f(c.y) + b2f(d.y));
    }
    for (; e < end; e++) {
        int s0 = __builtin_nontemporal_load(col + e);
        ushort2 a = *(const ushort2*)(H + (size_t)s0 * 64 + fo);
        acc0 += b2f(a.x); acc1 += b2f(a.y);
    }

    float dv = dinv[node];
    float2 bb = *(const float2*)(bias + fo);
    *(ushort2*)(Y + (size_t)node * 64 + fo) =
        make_ushort2(f2b(acc0 * dv + bb.x), f2b(acc1 * dv + bb.y));
}

// ---------------- final: logits + softmax + value ----------------
// thread = (node%32)*8 + action; 32 nodes / 256-thread block; N%32==0.

__global__ __launch_bounds__(256) void logits_k(
    const unsigned short* __restrict__ A2,   // [N,64] bf16
    const unsigned short* __restrict__ C2,   // [N,64] bf16
    const float* __restrict__ Wa3, const float* __restrict__ ba3,
    const float* __restrict__ Wc3, const float* __restrict__ bc3,
    float* __restrict__ out, int N) {
    int t = threadIdx.x;
    int node = blockIdx.x * 32 + (t >> 3);
    int a = t & 7;
    if (node >= N) return;

    const unsigned short* ar = A2 + (size_t)node * 64;
    float s = ba3[a];
#pragma unroll
    for (int q = 0; q < 8; q++) {
        uint4 pv = *(const uint4*)(ar + q * 8);
        const unsigned short* pu = (const unsigned short*)&pv;
#pragma unroll
        for (int j = 0; j < 8; j++)
            s = fmaf(b2f(pu[j]), Wa3[(q * 8 + j) * 8 + a], s);
    }
    float m = s;
#pragma unroll
    for (int w = 1; w < 8; w <<= 1) m = fmaxf(m, __shfl_xor(m, w, 64));
    float e = expf(s - m);
    float sum = e;
#pragma unroll
    for (int w = 1; w < 8; w <<= 1) sum += __shfl_xor(sum, w, 64);
    out[(size_t)node * 9 + a] = e / sum;

    if (a == 0) {
        const unsigned short* cr = C2 + (size_t)node * 64;
        float v = bc3[0];
#pragma unroll
        for (int q = 0; q < 8; q++) {
            uint4 pv = *(const uint4*)(cr + q * 8);
            const unsigned short* pu = (const unsigned short*)&pv;
#pragma unroll
            for (int j = 0; j < 8; j++)
                v = fmaf(b2f(pu[j]), Wc3[q * 8 + j], v);
        }
        out[(size_t)node * 9 + 8] = v;
    }
}

// ---------------- launch ----------------

extern "C" void kernel_launch(void* const* d_in, const int* in_sizes, int n_in,
                              void* d_out, int out_size, void* d_ws, size_t ws_size,
                              hipStream_t stream) {
    const float* x   = (const float*)d_in[0];
    const int*   ei  = (const int*)d_in[1];
    const float* W1  = (const float*)d_in[2];  const float* b1  = (const float*)d_in[3];
    const float* W2  = (const float*)d_in[4];  const float* b2  = (const float*)d_in[5];
    const float* W3  = (const float*)d_in[6];  const float* b3  = (const float*)d_in[7];
    const float* Wa1 = (const float*)d_in[8];  const float* ba1 = (const float*)d_in[9];
    const float* Wa2 = (const float*)d_in[10]; const float* ba2 = (const float*)d_in[11];
    const float* Wa3 = (const float*)d_in[12]; const float* ba3 = (const float*)d_in[13];
    const float* Wc1 = (const float*)d_in[14]; const float* bc1 = (const float*)d_in[15];
    const float* Wc2 = (const float*)d_in[16]; const float* bc2 = (const float*)d_in[17];
    const float* Wc3 = (const float*)d_in[18]; const float* bc3 = (const float*)d_in[19];
    float* out = (float*)d_out;

    const int N = in_sizes[0] / 128;     // 100000
    const int E = in_sizes[1] / 2;       // 3200000
    const int* src = ei;
    const int* dst = ei + E;

    // workspace layout (all big activations bf16)
    size_t off = 0;
    auto take = [&](size_t bytes) { size_t o = off; off = WS_ALIGN(off + bytes); return o; };
    char* ws = (char*)d_ws;
    unsigned short* h      = (unsigned short*)(ws + take((size_t)N * 128 * 2)); // 25.6MB
    unsigned short* hprime = (unsigned short*)(ws + take((size_t)N * 128 * 2)); // 25.6MB
    unsigned short* h3     = (unsigned short*)(ws + take((size_t)N * 64 * 2));  // 12.8MB
    int*            col    = (int*)(ws + take((size_t)E * 4));                  // 12.8MB
    unsigned short* A1C1   = (unsigned short*)(ws + take((size_t)N * 128 * 2)); // 25.6MB
    unsigned short* wt     = (unsigned short*)(ws + take(73728 * 2));           // 147KB
    float* dinv   = (float*)(ws + take((size_t)N * 4));
    int*   cnt    = (int*)  (ws + take((size_t)N * 4));
    int*   rowptr = (int*)  (ws + take((size_t)(N + 1) * 4));
    int*   bcnt   = (int*)  (ws + take(RNG * NB_A * 4));
    int*   base   = (int*)  (ws + take(RNG * NB_A * 4));
    int*   bstart = (int*)  (ws + take((RNG + 1) * 4));
    int*   bsum   = (int*)  (ws + take(512 * 4));
    int*   boff   = (int*)  (ws + take(512 * 4));
    // aliases (CSR phase, before h/A1C1 written): bucket 25.6MB on h,
    // hist 12.8MB on A1C1. Head intermediates alias hprime (dead after agg64).
    unsigned long long* bucket = (unsigned long long*)h;
    int* hist = (int*)A1C1;
    unsigned short* A2 = hprime;                       // [N,64] bf16 = 12.8MB
    unsigned short* C2 = hprime + (size_t)N * 64;      // [N,64] bf16 = 12.8MB
    (void)ws_size; (void)n_in; (void)out_size;

    const int nb  = (N + 255) / 256;     // 391 (<512)
    const int gN  = (N + 255) / 256;
    const int gT  = (N + 63) / 64;       // 1563

    // weight prep (independent of CSR, stream-ordered anyway)
    prep_w_k<<<288, 256, 0, stream>>>(W1, W2, W3, Wa1, Wa2, Wc1, Wc2, wt);
    const unsigned short* W1t  = wt;
    const unsigned short* W2t  = wt + 16384;
    const unsigned short* W3t  = wt + 32768;
    const unsigned short* Wa1t = wt + 40960;
    const unsigned short* Wa2t = wt + 49152;
    const unsigned short* Wc1t = wt + 57344;
    const unsigned short* Wc2t = wt + 65536;

    // CSR build: bucket sort
    bucket_count_k<<<NB_A, 256, 0, stream>>>(dst, bcnt, E);
    bucket_off_k<<<1, 1024, 0, stream>>>(bcnt, base, bstart, E);
    bucket_scatter_k<<<NB_A, 256, 0, stream>>>(src, dst, base, bucket, E);
    hist_bucket_k<<<RNG * CHK, 256, 0, stream>>>(bucket, bstart, hist);
    sum_hist_dinv_k<<<gN, 256, 0, stream>>>(hist, cnt, dinv, N);
    chunk_sum_k<<<nb, 256, 0, stream>>>(cnt, bsum, N);
    scan_mid_k<<<1, 512, 0, stream>>>(bsum, boff, nb, rowptr, N);
    scan_final_k<<<nb, 256, 0, stream>>>(cnt, boff, rowptr, N);
    offsets_k<<<gN, 256, 0, stream>>>(hist, rowptr, N);
    fill2_k<<<RNG * CHK, 256, 0, stream>>>(bucket, bstart, hist, col);

    // GCN layer 1: 128 -> 128, relu
    gemm_mfma_k<128, 128, true,  false><<<gT, 256, 0, stream>>>(x, W1t, dinv, hprime, N);
    agg128_k<true><<<(N + 3) / 4, 256, 0, stream>>>(hprime, rowptr, col, dinv, b1, h, N);
    // GCN layer 2: 128 -> 128, relu
    gemm_mfma_k<128, 128, false, false><<<gT, 256, 0, stream>>>(h, W2t, dinv, hprime, N);
    agg128_k<true><<<(N + 3) / 4, 256, 0, stream>>>(hprime, rowptr, col, dinv, b2, h, N);
    // GCN layer 3: 128 -> 64, linear
    gemm_mfma_k<128, 64,  false, false><<<gT, 256, 0, stream>>>(h, W3t, dinv, hprime, N);
    agg64_k<<<(N + 7) / 8, 256, 0, stream>>>(hprime, rowptr, col, dinv, b3, h3, N);

    // heads (hprime now dead; A2/C2 alias it)
    gemm_mfma_k<64,  128, false, true><<<gT, 256, 0, stream>>>(h3, Wa1t, ba1, A1C1, N);
    gemm_mfma_k<128, 64,  false, true><<<gT, 256, 0, stream>>>(A1C1, Wa2t, ba2, A2, N);
    gemm_mfma_k<64,  128, false, true><<<gT, 256, 0, stream>>>(h3, Wc1t, bc1, A1C1, N);
    gemm_mfma_k<128, 64,  false, true><<<gT, 256, 0, stream>>>(A1C1, Wc2t, bc2, C2, N);
    logits_k<<<(N + 31) / 32, 256, 0, stream>>>(A2, C2, Wa3, ba3, Wc3, bc3, out, N);
}

// Round 6
// 682.266 us; speedup vs baseline: 2.1840x; 1.1113x over previous
//
#include <hip/hip_runtime.h>
#include <hip/hip_bf16.h>
#include <math.h>

// ---------------------------------------------------------------------------
// FederatedPPOAgent: 3x GCNConv (N=100k, E=3.2M, D=128) + actor/critic MLPs.
//
// R6 change vs R5: hprime stored as fp8 e4m3 (scaled by S=64, folded into the
// GEMM epilogue; 1/S folded into agg's dinv multiply). R5's agg128_k was
// bytes-per-edge bound (FETCH 400MB, ~9 B/cyc/CU line throughput = fabric
// ceiling; random graph -> no locality to exploit). fp8 halves lines/edge
// (4->2 for D=128, ->1 for D=64). Agg loop unrolled to 8 edges. Heads chain
// stays bf16. Everything else unchanged from R5 (MFMA GEMMs, bucket-sort CSR).
// ---------------------------------------------------------------------------

#define WS_ALIGN(x) (((x) + 255) & ~(size_t)255)

constexpr int RNG    = 8;
constexpr int CHK    = 32;
constexpr int NRG_SZ = 12500;    // nodes per range (8*12500 = 100000 exactly)
constexpr int NB_A   = 256;      // bucket-phase blocks

constexpr float S_FP8     = 64.0f;       // hprime pre-quant scale
constexpr float S_FP8_INV = 1.0f / 64.0f;

using bf16x8 = __attribute__((ext_vector_type(8))) short;
using f32x4  = __attribute__((ext_vector_type(4))) float;
using f32x2  = __attribute__((ext_vector_type(2))) float;

__device__ __forceinline__ float b2f(unsigned short u) {
    return __uint_as_float(((unsigned int)u) << 16);
}
__device__ __forceinline__ unsigned short f2b(float f) {
    __hip_bfloat16 hb = __float2bfloat16(f);
    return *(unsigned short*)&hb;
}
__device__ __forceinline__ unsigned char f2fp8(float f) {
    return (unsigned char)(__builtin_amdgcn_cvt_pk_fp8_f32(f, f, 0, false) & 0xff);
}

// ---------------- CSR build (unchanged from R3) ----------------

__global__ __launch_bounds__(256) void bucket_count_k(
    const int* __restrict__ dst, int* __restrict__ bcnt, int E) {
    __shared__ int c8[RNG];
    int b = blockIdx.x, t = threadIdx.x;
    if (t < RNG) c8[t] = 0;
    __syncthreads();
    int ec = (E + NB_A - 1) / NB_A;
    int e0 = b * ec, e1 = min(E, e0 + ec);
    for (int e = e0 + t; e < e1; e += 256) {
        int d = __builtin_nontemporal_load(dst + e);
        atomicAdd(&c8[d / NRG_SZ], 1);
    }
    __syncthreads();
    if (t < RNG) bcnt[t * NB_A + b] = c8[t];
}

__global__ void bucket_off_k(const int* __restrict__ bcnt, int* __restrict__ base,
                             int* __restrict__ bstart, int E) {
    __shared__ int s[RNG * NB_A];
    int t = threadIdx.x;
    s[t] = bcnt[t];
    s[t + 1024] = bcnt[t + 1024];
    __syncthreads();
    if (t == 0) {
        int run = 0;
        for (int i = 0; i < RNG * NB_A; i++) { int v = s[i]; s[i] = run; run += v; }
    }
    __syncthreads();
    base[t] = s[t];
    base[t + 1024] = s[t + 1024];
    if (t < RNG) bstart[t] = s[t * NB_A];
    if (t == 0) bstart[RNG] = E;
}

__global__ __launch_bounds__(256) void bucket_scatter_k(
    const int* __restrict__ src, const int* __restrict__ dst,
    const int* __restrict__ base, unsigned long long* __restrict__ bucket, int E) {
    __shared__ int cur[RNG];
    int b = blockIdx.x, t = threadIdx.x;
    if (t < RNG) cur[t] = base[t * NB_A + b];
    __syncthreads();
    int ec = (E + NB_A - 1) / NB_A;
    int e0 = b * ec, e1 = min(E, e0 + ec);
    for (int e = e0 + t; e < e1; e += 256) {
        int d = __builtin_nontemporal_load(dst + e);
        int sv = __builtin_nontemporal_load(src + e);
        int r = d / NRG_SZ;
        int pos = atomicAdd(&cur[r], 1);
        bucket[pos] = ((unsigned long long)(d - r * NRG_SZ) << 32) | (unsigned int)sv;
    }
}

__global__ __launch_bounds__(256) void hist_bucket_k(
    const unsigned long long* __restrict__ bucket, const int* __restrict__ bstart,
    int* __restrict__ hist) {
    __shared__ int h[NRG_SZ];
    int b = blockIdx.x, r = b & 7, c2 = b >> 3, t = threadIdx.x;
    for (int i = t; i < NRG_SZ; i += 256) h[i] = 0;
    int s0 = bstart[r], s1 = bstart[r + 1];
    int ec = (s1 - s0 + CHK - 1) / CHK;
    int e0 = s0 + c2 * ec, e1 = min(s1, e0 + ec);
    __syncthreads();
    for (int e = e0 + t; e < e1; e += 256) {
        unsigned long long v = __builtin_nontemporal_load(bucket + e);
        atomicAdd(&h[(int)(v >> 32)], 1);
    }
    __syncthreads();
    int* out = hist + ((size_t)r * CHK + c2) * NRG_SZ;
    for (int i = t; i < NRG_SZ; i += 256) out[i] = h[i];
}

__global__ void sum_hist_dinv_k(const int* __restrict__ hist, int* __restrict__ cnt,
                                float* __restrict__ dinv, int N) {
    int i = blockIdx.x * 256 + threadIdx.x;
    if (i >= N) return;
    int r = i / NRG_SZ, li = i - r * NRG_SZ;
    const int* hp = hist + ((size_t)r * CHK) * NRG_SZ + li;
    int s = 0;
#pragma unroll
    for (int c = 0; c < CHK; c++) s += hp[(size_t)c * NRG_SZ];
    cnt[i] = s;
    dinv[i] = rsqrtf((float)s + 1.0f);   // +1: self loop
}

__global__ void chunk_sum_k(const int* __restrict__ cnt, int* __restrict__ bsum, int n) {
    __shared__ int sd[256];
    int t = threadIdx.x;
    int i = blockIdx.x * 256 + t;
    sd[t] = (i < n) ? cnt[i] : 0;
    __syncthreads();
    for (int d = 128; d > 0; d >>= 1) {
        if (t < d) sd[t] += sd[t + d];
        __syncthreads();
    }
    if (t == 0) bsum[blockIdx.x] = sd[0];
}

__global__ void scan_mid_k(const int* __restrict__ bsum, int* __restrict__ boff,
                           int nb, int* __restrict__ rowptr, int N) {
    __shared__ int s[512];
    int t = threadIdx.x;
    s[t] = (t < nb) ? bsum[t] : 0;
    __syncthreads();
    if (t == 0) {
        int run = 0;
        for (int i = 0; i < nb; i++) { int v = s[i]; s[i] = run; run += v; }
        rowptr[N] = run;
    }
    __syncthreads();
    if (t < nb) boff[t] = s[t];
}

__global__ void scan_final_k(const int* __restrict__ cnt, const int* __restrict__ boff,
                             int* __restrict__ rowptr, int n) {
    __shared__ int s[256];
    int t = threadIdx.x;
    int i = blockIdx.x * 256 + t;
    int v = (i < n) ? cnt[i] : 0;
    s[t] = v;
    __syncthreads();
    for (int d = 1; d < 256; d <<= 1) {
        int x = (t >= d) ? s[t - d] : 0;
        __syncthreads();
        s[t] += x;
        __syncthreads();
    }
    if (i < n) rowptr[i] = s[t] - v + boff[blockIdx.x];
}

__global__ void offsets_k(int* __restrict__ hist, const int* __restrict__ rowptr, int N) {
    int i = blockIdx.x * 256 + threadIdx.x;
    if (i >= N) return;
    int r = i / NRG_SZ, li = i - r * NRG_SZ;
    int* hp = hist + ((size_t)r * CHK) * NRG_SZ + li;
    int run = rowptr[i];
#pragma unroll
    for (int c = 0; c < CHK; c++) {
        int v = hp[(size_t)c * NRG_SZ];
        hp[(size_t)c * NRG_SZ] = run;
        run += v;
    }
}

__global__ __launch_bounds__(256) void fill2_k(
    const unsigned long long* __restrict__ bucket, const int* __restrict__ bstart,
    const int* __restrict__ hist, int* __restrict__ col) {
    __shared__ int cur[NRG_SZ];
    int b = blockIdx.x, r = b & 7, c2 = b >> 3, t = threadIdx.x;
    const int* hp = hist + ((size_t)r * CHK + c2) * NRG_SZ;
    for (int i = t; i < NRG_SZ; i += 256) cur[i] = hp[i];
    int s0 = bstart[r], s1 = bstart[r + 1];
    int ec = (s1 - s0 + CHK - 1) / CHK;
    int e0 = s0 + c2 * ec, e1 = min(s1, e0 + ec);
    __syncthreads();
    for (int e = e0 + t; e < e1; e += 256) {
        unsigned long long v = __builtin_nontemporal_load(bucket + e);
        int slot = atomicAdd(&cur[(int)(v >> 32)], 1);   // LDS atomic
        col[slot] = (int)(unsigned int)(v & 0xffffffffULL);
    }
}

// ---------------- weight prep: fp32 W[K][OUT] -> bf16 W^T[OUT][K] ----------------

__global__ __launch_bounds__(256) void prep_w_k(
    const float* __restrict__ W1, const float* __restrict__ W2,
    const float* __restrict__ W3, const float* __restrict__ Wa1,
    const float* __restrict__ Wa2, const float* __restrict__ Wc1,
    const float* __restrict__ Wc2, unsigned short* __restrict__ wt) {
    int i = blockIdx.x * 256 + threadIdx.x;   // 0..73727
    const float* W; int off, K, OUT;
    if (i < 16384)      { W = W1;  off = 0;     K = 128; OUT = 128; }
    else if (i < 32768) { W = W2;  off = 16384; K = 128; OUT = 128; }
    else if (i < 40960) { W = W3;  off = 32768; K = 128; OUT = 64; }
    else if (i < 49152) { W = Wa1; off = 40960; K = 64;  OUT = 128; }
    else if (i < 57344) { W = Wa2; off = 49152; K = 128; OUT = 64; }
    else if (i < 65536) { W = Wc1; off = 57344; K = 64;  OUT = 128; }
    else                { W = Wc2; off = 65536; K = 128; OUT = 64; }
    int j = i - off, k = j / OUT, n = j - k * OUT;
    wt[off + n * K + k] = f2b(W[j]);
}

// ---------------- MFMA GEMM: Y = epi(X @ W) ----------------
// BM=64 rows/block, 4 waves x 16-row strips, mfma_f32_16x16x32_bf16.
// epi: BIAS_RELU ? bf16(relu(.+bias[col])) : OFP8 ? fp8(. * dinv[row] * S)
//                                          : bf16(. * dinv[row])

template <int K, int OUT, bool AF32, bool BIAS_RELU, bool OFP8>
__global__ __launch_bounds__(256) void gemm_mfma_k(
    const void* __restrict__ Xv, const unsigned short* __restrict__ Wt,  // [OUT][K]
    const float* __restrict__ sb,   // dinv[N] or bias[OUT]
    void* __restrict__ Yv, int N) {
    constexpr int LDK = K + 8;
    __shared__ __align__(16) unsigned short As[64 * LDK];
    __shared__ __align__(16) unsigned short Bs[OUT * LDK];
    int t = threadIdx.x;
    int rowBase = blockIdx.x * 64;

    if constexpr (AF32) {
        const float* X = (const float*)Xv;
        for (int g = t; g < 64 * (K / 8); g += 256) {
            int r = g / (K / 8), q = g - r * (K / 8);
            int gr = rowBase + r;
            unsigned short us[8];
            if (gr < N) {
                float4 v0 = *(const float4*)(X + (size_t)gr * K + q * 8);
                float4 v1 = *(const float4*)(X + (size_t)gr * K + q * 8 + 4);
                us[0] = f2b(v0.x); us[1] = f2b(v0.y); us[2] = f2b(v0.z); us[3] = f2b(v0.w);
                us[4] = f2b(v1.x); us[5] = f2b(v1.y); us[6] = f2b(v1.z); us[7] = f2b(v1.w);
            } else {
#pragma unroll
                for (int j = 0; j < 8; j++) us[j] = 0;
            }
            *(uint4*)&As[r * LDK + q * 8] = *(uint4*)us;
        }
    } else {
        const unsigned short* X = (const unsigned short*)Xv;
        for (int g = t; g < 64 * (K / 8); g += 256) {
            int r = g / (K / 8), q = g - r * (K / 8);
            int gr = rowBase + r;
            uint4 v = make_uint4(0, 0, 0, 0);
            if (gr < N) v = *(const uint4*)(X + (size_t)gr * K + q * 8);
            *(uint4*)&As[r * LDK + q * 8] = v;
        }
    }
    for (int g = t; g < OUT * (K / 8); g += 256) {
        int r = g / (K / 8), q = g - r * (K / 8);
        *(uint4*)&Bs[r * LDK + q * 8] = *(const uint4*)(Wt + r * K + q * 8);
    }
    __syncthreads();

    int wv = t >> 6, lane = t & 63;
    int lm = lane & 15, lq = lane >> 4;
    constexpr int CT = OUT / 16;
    f32x4 acc[CT];
#pragma unroll
    for (int c = 0; c < CT; c++) acc[c] = (f32x4){0.f, 0.f, 0.f, 0.f};

    const unsigned short* arow = &As[(wv * 16 + lm) * LDK + lq * 8];
#pragma unroll
    for (int kt = 0; kt < K / 32; kt++) {
        bf16x8 a = *(const bf16x8*)(arow + kt * 32);
#pragma unroll
        for (int c = 0; c < CT; c++) {
            bf16x8 b = *(const bf16x8*)&Bs[(c * 16 + lm) * LDK + kt * 32 + lq * 8];
            acc[c] = __builtin_amdgcn_mfma_f32_16x16x32_bf16(a, b, acc[c], 0, 0, 0);
        }
    }

    // epilogue: C/D layout col=lane&15, row=(lane>>4)*4+reg  [m89/m91-verified]
    int r0 = rowBase + wv * 16 + lq * 4;
#pragma unroll
    for (int r = 0; r < 4; r++) {
        int gr = r0 + r;
        if (gr < N) {
            float scale = 1.f;
            if constexpr (!BIAS_RELU) scale = OFP8 ? sb[gr] * S_FP8 : sb[gr];
#pragma unroll
            for (int c = 0; c < CT; c++) {
                int colg = c * 16 + lm;
                float v = acc[c][r];
                if constexpr (BIAS_RELU) {
                    v = fmaxf(v + sb[colg], 0.f);
                    ((unsigned short*)Yv)[(size_t)gr * OUT + colg] = f2b(v);
                } else if constexpr (OFP8) {
                    ((unsigned char*)Yv)[(size_t)gr * OUT + colg] = f2fp8(v * scale);
                } else {
                    ((unsigned short*)Yv)[(size_t)gr * OUT + colg] = f2b(v * scale);
                }
            }
        }
    }
}

// ---------------- aggregation: fp8 gather, fp32 accumulate, bf16 out ----------------

template <bool RELU>
__global__ __launch_bounds__(256) void agg128_k(
    const unsigned char* __restrict__ H,   // [N,128] fp8 = S*hprime
    const int* __restrict__ rowptr, const int* __restrict__ col,
    const float* __restrict__ dinv, const float* __restrict__ bias,
    unsigned short* __restrict__ Y, int N) {
    int tid = threadIdx.x;
    int node = blockIdx.x * 4 + (tid >> 6);
    if (node >= N) return;
    int lane = tid & 63;
    int fo = lane * 2;   // 2 fp8 per lane

    float acc0, acc1;
    {   unsigned short u = *(const unsigned short*)(H + (size_t)node * 128 + fo);
        f32x2 v = __builtin_amdgcn_cvt_pk_f32_fp8((int)u, false);
        acc0 = v[0]; acc1 = v[1]; }

    int e = rowptr[node], end = rowptr[node + 1];
    for (; e + 8 <= end; e += 8) {
        int s0 = __builtin_nontemporal_load(col + e);
        int s1 = __builtin_nontemporal_load(col + e + 1);
        int s2 = __builtin_nontemporal_load(col + e + 2);
        int s3 = __builtin_nontemporal_load(col + e + 3);
        int s4 = __builtin_nontemporal_load(col + e + 4);
        int s5 = __builtin_nontemporal_load(col + e + 5);
        int s6 = __builtin_nontemporal_load(col + e + 6);
        int s7 = __builtin_nontemporal_load(col + e + 7);
        unsigned short u0 = *(const unsigned short*)(H + (size_t)s0 * 128 + fo);
        unsigned short u1 = *(const unsigned short*)(H + (size_t)s1 * 128 + fo);
        unsigned short u2 = *(const unsigned short*)(H + (size_t)s2 * 128 + fo);
        unsigned short u3 = *(const unsigned short*)(H + (size_t)s3 * 128 + fo);
        unsigned short u4 = *(const unsigned short*)(H + (size_t)s4 * 128 + fo);
        unsigned short u5 = *(const unsigned short*)(H + (size_t)s5 * 128 + fo);
        unsigned short u6 = *(const unsigned short*)(H + (size_t)s6 * 128 + fo);
        unsigned short u7 = *(const unsigned short*)(H + (size_t)s7 * 128 + fo);
        f32x2 v0 = __builtin_amdgcn_cvt_pk_f32_fp8((int)u0, false);
        f32x2 v1 = __builtin_amdgcn_cvt_pk_f32_fp8((int)u1, false);
        f32x2 v2 = __builtin_amdgcn_cvt_pk_f32_fp8((int)u2, false);
        f32x2 v3 = __builtin_amdgcn_cvt_pk_f32_fp8((int)u3, false);
        f32x2 v4 = __builtin_amdgcn_cvt_pk_f32_fp8((int)u4, false);
        f32x2 v5 = __builtin_amdgcn_cvt_pk_f32_fp8((int)u5, false);
        f32x2 v6 = __builtin_amdgcn_cvt_pk_f32_fp8((int)u6, false);
        f32x2 v7 = __builtin_amdgcn_cvt_pk_f32_fp8((int)u7, false);
        acc0 += ((v0[0] + v1[0]) + (v2[0] + v3[0])) + ((v4[0] + v5[0]) + (v6[0] + v7[0]));
        acc1 += ((v0[1] + v1[1]) + (v2[1] + v3[1])) + ((v4[1] + v5[1]) + (v6[1] + v7[1]));
    }
    for (; e < end; e++) {
        int s0 = __builtin_nontemporal_load(col + e);
        unsigned short u = *(const unsigned short*)(H + (size_t)s0 * 128 + fo);
        f32x2 v = __builtin_amdgcn_cvt_pk_f32_fp8((int)u, false);
        acc0 += v[0]; acc1 += v[1];
    }

    float dv = dinv[node] * S_FP8_INV;
    float2 bb = *(const float2*)(bias + fo);
    float o0 = acc0 * dv + bb.x;
    float o1 = acc1 * dv + bb.y;
    if (RELU) { o0 = fmaxf(o0, 0.f); o1 = fmaxf(o1, 0.f); }
    *(ushort2*)(Y + (size_t)node * 128 + fo) = make_ushort2(f2b(o0), f2b(o1));
}

// D=64, linear: half-wave (32 lanes x 2 fp8) per node
__global__ __launch_bounds__(256) void agg64_k(
    const unsigned char* __restrict__ H,   // [N,64] fp8
    const int* __restrict__ rowptr, const int* __restrict__ col,
    const float* __restrict__ dinv, const float* __restrict__ bias,
    unsigned short* __restrict__ Y, int N) {
    int tid = threadIdx.x;
    int node = blockIdx.x * 8 + (tid >> 5);
    if (node >= N) return;
    int lane = tid & 31;
    int fo = lane * 2;

    float acc0, acc1;
    {   unsigned short u = *(const unsigned short*)(H + (size_t)node * 64 + fo);
        f32x2 v = __builtin_amdgcn_cvt_pk_f32_fp8((int)u, false);
        acc0 = v[0]; acc1 = v[1]; }

    int e = rowptr[node], end = rowptr[node + 1];
    for (; e + 8 <= end; e += 8) {
        int s0 = __builtin_nontemporal_load(col + e);
        int s1 = __builtin_nontemporal_load(col + e + 1);
        int s2 = __builtin_nontemporal_load(col + e + 2);
        int s3 = __builtin_nontemporal_load(col + e + 3);
        int s4 = __builtin_nontemporal_load(col + e + 4);
        int s5 = __builtin_nontemporal_load(col + e + 5);
        int s6 = __builtin_nontemporal_load(col + e + 6);
        int s7 = __builtin_nontemporal_load(col + e + 7);
        unsigned short u0 = *(const unsigned short*)(H + (size_t)s0 * 64 + fo);
        unsigned short u1 = *(const unsigned short*)(H + (size_t)s1 * 64 + fo);
        unsigned short u2 = *(const unsigned short*)(H + (size_t)s2 * 64 + fo);
        unsigned short u3 = *(const unsigned short*)(H + (size_t)s3 * 64 + fo);
        unsigned short u4 = *(const unsigned short*)(H + (size_t)s4 * 64 + fo);
        unsigned short u5 = *(const unsigned short*)(H + (size_t)s5 * 64 + fo);
        unsigned short u6 = *(const unsigned short*)(H + (size_t)s6 * 64 + fo);
        unsigned short u7 = *(const unsigned short*)(H + (size_t)s7 * 64 + fo);
        f32x2 v0 = __builtin_amdgcn_cvt_pk_f32_fp8((int)u0, false);
        f32x2 v1 = __builtin_amdgcn_cvt_pk_f32_fp8((int)u1, false);
        f32x2 v2 = __builtin_amdgcn_cvt_pk_f32_fp8((int)u2, false);
        f32x2 v3 = __builtin_amdgcn_cvt_pk_f32_fp8((int)u3, false);
        f32x2 v4 = __builtin_amdgcn_cvt_pk_f32_fp8((int)u4, false);
        f32x2 v5 = __builtin_amdgcn_cvt_pk_f32_fp8((int)u5, false);
        f32x2 v6 = __builtin_amdgcn_cvt_pk_f32_fp8((int)u6, false);
        f32x2 v7 = __builtin_amdgcn_cvt_pk_f32_fp8((int)u7, false);
        acc0 += ((v0[0] + v1[0]) + (v2[0] + v3[0])) + ((v4[0] + v5[0]) + (v6[0] + v7[0]));
        acc1 += ((v0[1] + v1[1]) + (v2[1] + v3[1])) + ((v4[1] + v5[1]) + (v6[1] + v7[1]));
    }
    for (; e < end; e++) {
        int s0 = __builtin_nontemporal_load(col + e);
        unsigned short u = *(const unsigned short*)(H + (size_t)s0 * 64 + fo);
        f32x2 v = __builtin_amdgcn_cvt_pk_f32_fp8((int)u, false);
        acc0 += v[0]; acc1 += v[1];
    }

    float dv = dinv[node] * S_FP8_INV;
    float2 bb = *(const float2*)(bias + fo);
    *(ushort2*)(Y + (size_t)node * 64 + fo) =
        make_ushort2(f2b(acc0 * dv + bb.x), f2b(acc1 * dv + bb.y));
}

// ---------------- final: logits + softmax + value ----------------

__global__ __launch_bounds__(256) void logits_k(
    const unsigned short* __restrict__ A2,   // [N,64] bf16
    const unsigned short* __restrict__ C2,   // [N,64] bf16
    const float* __restrict__ Wa3, const float* __restrict__ ba3,
    const float* __restrict__ Wc3, const float* __restrict__ bc3,
    float* __restrict__ out, int N) {
    int t = threadIdx.x;
    int node = blockIdx.x * 32 + (t >> 3);
    int a = t & 7;
    if (node >= N) return;

    const unsigned short* ar = A2 + (size_t)node * 64;
    float s = ba3[a];
#pragma unroll
    for (int q = 0; q < 8; q++) {
        uint4 pv = *(const uint4*)(ar + q * 8);
        const unsigned short* pu = (const unsigned short*)&pv;
#pragma unroll
        for (int j = 0; j < 8; j++)
            s = fmaf(b2f(pu[j]), Wa3[(q * 8 + j) * 8 + a], s);
    }
    float m = s;
#pragma unroll
    for (int w = 1; w < 8; w <<= 1) m = fmaxf(m, __shfl_xor(m, w, 64));
    float e = expf(s - m);
    float sum = e;
#pragma unroll
    for (int w = 1; w < 8; w <<= 1) sum += __shfl_xor(sum, w, 64);
    out[(size_t)node * 9 + a] = e / sum;

    if (a == 0) {
        const unsigned short* cr = C2 + (size_t)node * 64;
        float v = bc3[0];
#pragma unroll
        for (int q = 0; q < 8; q++) {
            uint4 pv = *(const uint4*)(cr + q * 8);
            const unsigned short* pu = (const unsigned short*)&pv;
#pragma unroll
            for (int j = 0; j < 8; j++)
                v = fmaf(b2f(pu[j]), Wc3[q * 8 + j], v);
        }
        out[(size_t)node * 9 + 8] = v;
    }
}

// ---------------- launch ----------------

extern "C" void kernel_launch(void* const* d_in, const int* in_sizes, int n_in,
                              void* d_out, int out_size, void* d_ws, size_t ws_size,
                              hipStream_t stream) {
    const float* x   = (const float*)d_in[0];
    const int*   ei  = (const int*)d_in[1];
    const float* W1  = (const float*)d_in[2];  const float* b1  = (const float*)d_in[3];
    const float* W2  = (const float*)d_in[4];  const float* b2  = (const float*)d_in[5];
    const float* W3  = (const float*)d_in[6];  const float* b3  = (const float*)d_in[7];
    const float* Wa1 = (const float*)d_in[8];  const float* ba1 = (const float*)d_in[9];
    const float* Wa2 = (const float*)d_in[10]; const float* ba2 = (const float*)d_in[11];
    const float* Wa3 = (const float*)d_in[12]; const float* ba3 = (const float*)d_in[13];
    const float* Wc1 = (const float*)d_in[14]; const float* bc1 = (const float*)d_in[15];
    const float* Wc2 = (const float*)d_in[16]; const float* bc2 = (const float*)d_in[17];
    const float* Wc3 = (const float*)d_in[18]; const float* bc3 = (const float*)d_in[19];
    float* out = (float*)d_out;

    const int N = in_sizes[0] / 128;     // 100000
    const int E = in_sizes[1] / 2;       // 3200000
    const int* src = ei;
    const int* dst = ei + E;

    // workspace layout
    size_t off = 0;
    auto take = [&](size_t bytes) { size_t o = off; off = WS_ALIGN(off + bytes); return o; };
    char* ws = (char*)d_ws;
    unsigned short* h      = (unsigned short*)(ws + take((size_t)N * 128 * 2)); // 25.6MB
    unsigned char*  hpr8   = (unsigned char*) (ws + take((size_t)N * 128));     // 12.8MB
    unsigned short* h3     = (unsigned short*)(ws + take((size_t)N * 64 * 2));  // 12.8MB
    int*            col    = (int*)(ws + take((size_t)E * 4));                  // 12.8MB
    unsigned short* A1C1   = (unsigned short*)(ws + take((size_t)N * 128 * 2)); // 25.6MB
    unsigned short* wt     = (unsigned short*)(ws + take(73728 * 2));
    float* dinv   = (float*)(ws + take((size_t)N * 4));
    int*   cnt    = (int*)  (ws + take((size_t)N * 4));
    int*   rowptr = (int*)  (ws + take((size_t)(N + 1) * 4));
    int*   bcnt   = (int*)  (ws + take(RNG * NB_A * 4));
    int*   base   = (int*)  (ws + take(RNG * NB_A * 4));
    int*   bstart = (int*)  (ws + take((RNG + 1) * 4));
    int*   bsum   = (int*)  (ws + take(512 * 4));
    int*   boff   = (int*)  (ws + take(512 * 4));
    // aliases: bucket (E*8=25.6MB) on h [dead until agg L1];
    // hist (12.8MB) on A1C1 [dead until heads]; A2 on col [dead after agg64];
    // C2 on hpr8 [dead after agg64].
    unsigned long long* bucket = (unsigned long long*)h;
    int* hist = (int*)A1C1;
    unsigned short* A2 = (unsigned short*)col;   // [N,64] bf16 = 12.8MB
    unsigned short* C2 = (unsigned short*)hpr8;  // [N,64] bf16 = 12.8MB
    (void)ws_size; (void)n_in; (void)out_size;

    const int nb  = (N + 255) / 256;     // 391 (<512)
    const int gN  = (N + 255) / 256;
    const int gT  = (N + 63) / 64;       // 1563

    prep_w_k<<<288, 256, 0, stream>>>(W1, W2, W3, Wa1, Wa2, Wc1, Wc2, wt);
    const unsigned short* W1t  = wt;
    const unsigned short* W2t  = wt + 16384;
    const unsigned short* W3t  = wt + 32768;
    const unsigned short* Wa1t = wt + 40960;
    const unsigned short* Wa2t = wt + 49152;
    const unsigned short* Wc1t = wt + 57344;
    const unsigned short* Wc2t = wt + 65536;

    // CSR build: bucket sort
    bucket_count_k<<<NB_A, 256, 0, stream>>>(dst, bcnt, E);
    bucket_off_k<<<1, 1024, 0, stream>>>(bcnt, base, bstart, E);
    bucket_scatter_k<<<NB_A, 256, 0, stream>>>(src, dst, base, bucket, E);
    hist_bucket_k<<<RNG * CHK, 256, 0, stream>>>(bucket, bstart, hist);
    sum_hist_dinv_k<<<gN, 256, 0, stream>>>(hist, cnt, dinv, N);
    chunk_sum_k<<<nb, 256, 0, stream>>>(cnt, bsum, N);
    scan_mid_k<<<1, 512, 0, stream>>>(bsum, boff, nb, rowptr, N);
    scan_final_k<<<nb, 256, 0, stream>>>(cnt, boff, rowptr, N);
    offsets_k<<<gN, 256, 0, stream>>>(hist, rowptr, N);
    fill2_k<<<RNG * CHK, 256, 0, stream>>>(bucket, bstart, hist, col);

    // GCN layer 1: 128 -> 128, relu
    gemm_mfma_k<128, 128, true,  false, true><<<gT, 256, 0, stream>>>(x, W1t, dinv, hpr8, N);
    agg128_k<true><<<(N + 3) / 4, 256, 0, stream>>>(hpr8, rowptr, col, dinv, b1, h, N);
    // GCN layer 2: 128 -> 128, relu
    gemm_mfma_k<128, 128, false, false, true><<<gT, 256, 0, stream>>>(h, W2t, dinv, hpr8, N);
    agg128_k<true><<<(N + 3) / 4, 256, 0, stream>>>(hpr8, rowptr, col, dinv, b2, h, N);
    // GCN layer 3: 128 -> 64, linear
    gemm_mfma_k<128, 64,  false, false, true><<<gT, 256, 0, stream>>>(h, W3t, dinv, hpr8, N);
    agg64_k<<<(N + 7) / 8, 256, 0, stream>>>(hpr8, rowptr, col, dinv, b3, h3, N);

    // heads (col/hpr8 now dead; A2/C2 alias them)
    gemm_mfma_k<64,  128, false, true, false><<<gT, 256, 0, stream>>>(h3, Wa1t, ba1, A1C1, N);
    gemm_mfma_k<128, 64,  false, true, false><<<gT, 256, 0, stream>>>(A1C1, Wa2t, ba2, A2, N);
    gemm_mfma_k<64,  128, false, true, false><<<gT, 256, 0, stream>>>(h3, Wc1t, bc1, A1C1, N);
    gemm_mfma_k<128, 64,  false, true, false><<<gT, 256, 0, stream>>>(A1C1, Wc2t, bc2, C2, N);
    logits_k<<<(N + 31) / 32, 256, 0, stream>>>(A2, C2, Wa3, ba3, Wc3, bc3, out, N);
}

// Round 7
// 558.797 us; speedup vs baseline: 2.6665x; 1.2210x over previous
//
#include <hip/hip_runtime.h>
#include <hip/hip_bf16.h>
#include <math.h>

// ---------------------------------------------------------------------------
// FederatedPPOAgent: 3x GCNConv (N=100k, E=3.2M, D=128) + actor/critic MLPs.
//
// R7 change vs R6: agg VMEM-instruction dilution. R5/R6 fit t = a*inst + b*lines
// with a~42us, b~16us per (unit/edge): per-instruction TA cost now dominates.
// New agg: one gather instruction covers 2 edges (D=128: 32 lanes x 4B/row)
// or 4 edges (D=64: 16 lanes x 4B), col indices prefetched 64-at-a-time and
// broadcast via shfl -> VMEM inst/edge drops 2 -> ~0.58 (D=128). CSR ranges
// padded to multiples of 8 (pad slots -> zero row N; gemm fp8 path stores
// unguarded up to Npad so row N is auto-zeroed). Edge streams recombined with
// shfl_xor at the end.
// ---------------------------------------------------------------------------

#define WS_ALIGN(x) (((x) + 255) & ~(size_t)255)

constexpr int RNG    = 8;
constexpr int CHK    = 32;
constexpr int NRG_SZ = 12500;    // nodes per range (8*12500 = 100000 exactly)
constexpr int NB_A   = 256;      // bucket-phase blocks

constexpr float S_FP8     = 64.0f;       // hprime pre-quant scale
constexpr float S_FP8_INV = 1.0f / 64.0f;

using bf16x8 = __attribute__((ext_vector_type(8))) short;
using f32x4  = __attribute__((ext_vector_type(4))) float;
using f32x2  = __attribute__((ext_vector_type(2))) float;

__device__ __forceinline__ float b2f(unsigned short u) {
    return __uint_as_float(((unsigned int)u) << 16);
}
__device__ __forceinline__ unsigned short f2b(float f) {
    __hip_bfloat16 hb = __float2bfloat16(f);
    return *(unsigned short*)&hb;
}
__device__ __forceinline__ unsigned char f2fp8(float f) {
    return (unsigned char)(__builtin_amdgcn_cvt_pk_fp8_f32(f, f, 0, false) & 0xff);
}
__device__ __forceinline__ int pad8(int v) { return (v + 7) & ~7; }

// ---------------- CSR build ----------------

__global__ __launch_bounds__(256) void bucket_count_k(
    const int* __restrict__ dst, int* __restrict__ bcnt, int E) {
    __shared__ int c8[RNG];
    int b = blockIdx.x, t = threadIdx.x;
    if (t < RNG) c8[t] = 0;
    __syncthreads();
    int ec = (E + NB_A - 1) / NB_A;
    int e0 = b * ec, e1 = min(E, e0 + ec);
    for (int e = e0 + t; e < e1; e += 256) {
        int d = __builtin_nontemporal_load(dst + e);
        atomicAdd(&c8[d / NRG_SZ], 1);
    }
    __syncthreads();
    if (t < RNG) bcnt[t * NB_A + b] = c8[t];
}

__global__ void bucket_off_k(const int* __restrict__ bcnt, int* __restrict__ base,
                             int* __restrict__ bstart, int E) {
    __shared__ int s[RNG * NB_A];
    int t = threadIdx.x;
    s[t] = bcnt[t];
    s[t + 1024] = bcnt[t + 1024];
    __syncthreads();
    if (t == 0) {
        int run = 0;
        for (int i = 0; i < RNG * NB_A; i++) { int v = s[i]; s[i] = run; run += v; }
    }
    __syncthreads();
    base[t] = s[t];
    base[t + 1024] = s[t + 1024];
    if (t < RNG) bstart[t] = s[t * NB_A];
    if (t == 0) bstart[RNG] = E;
}

__global__ __launch_bounds__(256) void bucket_scatter_k(
    const int* __restrict__ src, const int* __restrict__ dst,
    const int* __restrict__ base, unsigned long long* __restrict__ bucket, int E) {
    __shared__ int cur[RNG];
    int b = blockIdx.x, t = threadIdx.x;
    if (t < RNG) cur[t] = base[t * NB_A + b];
    __syncthreads();
    int ec = (E + NB_A - 1) / NB_A;
    int e0 = b * ec, e1 = min(E, e0 + ec);
    for (int e = e0 + t; e < e1; e += 256) {
        int d = __builtin_nontemporal_load(dst + e);
        int sv = __builtin_nontemporal_load(src + e);
        int r = d / NRG_SZ;
        int pos = atomicAdd(&cur[r], 1);
        bucket[pos] = ((unsigned long long)(d - r * NRG_SZ) << 32) | (unsigned int)sv;
    }
}

__global__ __launch_bounds__(256) void hist_bucket_k(
    const unsigned long long* __restrict__ bucket, const int* __restrict__ bstart,
    int* __restrict__ hist) {
    __shared__ int h[NRG_SZ];
    int b = blockIdx.x, r = b & 7, c2 = b >> 3, t = threadIdx.x;
    for (int i = t; i < NRG_SZ; i += 256) h[i] = 0;
    int s0 = bstart[r], s1 = bstart[r + 1];
    int ec = (s1 - s0 + CHK - 1) / CHK;
    int e0 = s0 + c2 * ec, e1 = min(s1, e0 + ec);
    __syncthreads();
    for (int e = e0 + t; e < e1; e += 256) {
        unsigned long long v = __builtin_nontemporal_load(bucket + e);
        atomicAdd(&h[(int)(v >> 32)], 1);
    }
    __syncthreads();
    int* out = hist + ((size_t)r * CHK + c2) * NRG_SZ;
    for (int i = t; i < NRG_SZ; i += 256) out[i] = h[i];
}

__global__ void sum_hist_dinv_k(const int* __restrict__ hist, int* __restrict__ cnt,
                                float* __restrict__ dinv, int N) {
    int i = blockIdx.x * 256 + threadIdx.x;
    if (i >= N) return;
    int r = i / NRG_SZ, li = i - r * NRG_SZ;
    const int* hp = hist + ((size_t)r * CHK) * NRG_SZ + li;
    int s = 0;
#pragma unroll
    for (int c = 0; c < CHK; c++) s += hp[(size_t)c * NRG_SZ];
    cnt[i] = s;
    dinv[i] = rsqrtf((float)s + 1.0f);   // +1: self loop
}

// prefix sums run over PADDED counts (pad8) so every node range is 8-aligned
__global__ void chunk_sum_k(const int* __restrict__ cnt, int* __restrict__ bsum, int n) {
    __shared__ int sd[256];
    int t = threadIdx.x;
    int i = blockIdx.x * 256 + t;
    sd[t] = (i < n) ? pad8(cnt[i]) : 0;
    __syncthreads();
    for (int d = 128; d > 0; d >>= 1) {
        if (t < d) sd[t] += sd[t + d];
        __syncthreads();
    }
    if (t == 0) bsum[blockIdx.x] = sd[0];
}

__global__ void scan_mid_k(const int* __restrict__ bsum, int* __restrict__ boff,
                           int nb, int* __restrict__ rowptr, int N) {
    __shared__ int s[512];
    int t = threadIdx.x;
    s[t] = (t < nb) ? bsum[t] : 0;
    __syncthreads();
    if (t == 0) {
        int run = 0;
        for (int i = 0; i < nb; i++) { int v = s[i]; s[i] = run; run += v; }
        rowptr[N] = run;
    }
    __syncthreads();
    if (t < nb) boff[t] = s[t];
}

__global__ void scan_final_k(const int* __restrict__ cnt, const int* __restrict__ boff,
                             int* __restrict__ rowptr, int n) {
    __shared__ int s[256];
    int t = threadIdx.x;
    int i = blockIdx.x * 256 + t;
    int v = (i < n) ? pad8(cnt[i]) : 0;
    s[t] = v;
    __syncthreads();
    for (int d = 1; d < 256; d <<= 1) {
        int x = (t >= d) ? s[t - d] : 0;
        __syncthreads();
        s[t] += x;
        __syncthreads();
    }
    if (i < n) rowptr[i] = s[t] - v + boff[blockIdx.x];
}

// hist[r][c][li] -> running cursor = padded rowptr + prefix over chunks
__global__ void offsets_k(int* __restrict__ hist, const int* __restrict__ rowptr, int N) {
    int i = blockIdx.x * 256 + threadIdx.x;
    if (i >= N) return;
    int r = i / NRG_SZ, li = i - r * NRG_SZ;
    int* hp = hist + ((size_t)r * CHK) * NRG_SZ + li;
    int run = rowptr[i];
#pragma unroll
    for (int c = 0; c < CHK; c++) {
        int v = hp[(size_t)c * NRG_SZ];
        hp[(size_t)c * NRG_SZ] = run;
        run += v;
    }
}

__global__ __launch_bounds__(256) void fill2_k(
    const unsigned long long* __restrict__ bucket, const int* __restrict__ bstart,
    const int* __restrict__ hist, int* __restrict__ col) {
    __shared__ int cur[NRG_SZ];
    int b = blockIdx.x, r = b & 7, c2 = b >> 3, t = threadIdx.x;
    const int* hp = hist + ((size_t)r * CHK + c2) * NRG_SZ;
    for (int i = t; i < NRG_SZ; i += 256) cur[i] = hp[i];
    int s0 = bstart[r], s1 = bstart[r + 1];
    int ec = (s1 - s0 + CHK - 1) / CHK;
    int e0 = s0 + c2 * ec, e1 = min(s1, e0 + ec);
    __syncthreads();
    for (int e = e0 + t; e < e1; e += 256) {
        unsigned long long v = __builtin_nontemporal_load(bucket + e);
        int slot = atomicAdd(&cur[(int)(v >> 32)], 1);   // LDS atomic
        col[slot] = (int)(unsigned int)(v & 0xffffffffULL);
    }
}

// fill pad slots [rowptr[i]+cnt, rowptr[i+1]) with the zero-row index N
__global__ void pad_col_k(const int* __restrict__ cnt, const int* __restrict__ rowptr,
                          int* __restrict__ col, int N) {
    int i = blockIdx.x * 256 + threadIdx.x;
    if (i >= N) return;
    int e = rowptr[i] + cnt[i], end = rowptr[i + 1];
    for (; e < end; e++) col[e] = N;
}

// ---------------- weight prep: fp32 W[K][OUT] -> bf16 W^T[OUT][K] ----------------

__global__ __launch_bounds__(256) void prep_w_k(
    const float* __restrict__ W1, const float* __restrict__ W2,
    const float* __restrict__ W3, const float* __restrict__ Wa1,
    const float* __restrict__ Wa2, const float* __restrict__ Wc1,
    const float* __restrict__ Wc2, unsigned short* __restrict__ wt) {
    int i = blockIdx.x * 256 + threadIdx.x;   // 0..73727
    const float* W; int off, K, OUT;
    if (i < 16384)      { W = W1;  off = 0;     K = 128; OUT = 128; }
    else if (i < 32768) { W = W2;  off = 16384; K = 128; OUT = 128; }
    else if (i < 40960) { W = W3;  off = 32768; K = 128; OUT = 64; }
    else if (i < 49152) { W = Wa1; off = 40960; K = 64;  OUT = 128; }
    else if (i < 57344) { W = Wa2; off = 49152; K = 128; OUT = 64; }
    else if (i < 65536) { W = Wc1; off = 57344; K = 64;  OUT = 128; }
    else                { W = Wc2; off = 65536; K = 128; OUT = 64; }
    int j = i - off, k = j / OUT, n = j - k * OUT;
    wt[off + n * K + k] = f2b(W[j]);
}

// ---------------- MFMA GEMM: Y = epi(X @ W) ----------------
// BM=64 rows/block. OFP8 path stores UNGUARDED up to grid rows (rows >= N are
// all-zero since A rows >= N stage as 0) -> provides the zero pad-row at N.

template <int K, int OUT, bool AF32, bool BIAS_RELU, bool OFP8>
__global__ __launch_bounds__(256) void gemm_mfma_k(
    const void* __restrict__ Xv, const unsigned short* __restrict__ Wt,  // [OUT][K]
    const float* __restrict__ sb,   // dinv or bias
    void* __restrict__ Yv, int N) {
    constexpr int LDK = K + 8;
    __shared__ __align__(16) unsigned short As[64 * LDK];
    __shared__ __align__(16) unsigned short Bs[OUT * LDK];
    int t = threadIdx.x;
    int rowBase = blockIdx.x * 64;

    if constexpr (AF32) {
        const float* X = (const float*)Xv;
        for (int g = t; g < 64 * (K / 8); g += 256) {
            int r = g / (K / 8), q = g - r * (K / 8);
            int gr = rowBase + r;
            unsigned short us[8];
            if (gr < N) {
                float4 v0 = *(const float4*)(X + (size_t)gr * K + q * 8);
                float4 v1 = *(const float4*)(X + (size_t)gr * K + q * 8 + 4);
                us[0] = f2b(v0.x); us[1] = f2b(v0.y); us[2] = f2b(v0.z); us[3] = f2b(v0.w);
                us[4] = f2b(v1.x); us[5] = f2b(v1.y); us[6] = f2b(v1.z); us[7] = f2b(v1.w);
            } else {
#pragma unroll
                for (int j = 0; j < 8; j++) us[j] = 0;
            }
            *(uint4*)&As[r * LDK + q * 8] = *(uint4*)us;
        }
    } else {
        const unsigned short* X = (const unsigned short*)Xv;
        for (int g = t; g < 64 * (K / 8); g += 256) {
            int r = g / (K / 8), q = g - r * (K / 8);
            int gr = rowBase + r;
            uint4 v = make_uint4(0, 0, 0, 0);
            if (gr < N) v = *(const uint4*)(X + (size_t)gr * K + q * 8);
            *(uint4*)&As[r * LDK + q * 8] = v;
        }
    }
    for (int g = t; g < OUT * (K / 8); g += 256) {
        int r = g / (K / 8), q = g - r * (K / 8);
        *(uint4*)&Bs[r * LDK + q * 8] = *(const uint4*)(Wt + r * K + q * 8);
    }
    __syncthreads();

    int wv = t >> 6, lane = t & 63;
    int lm = lane & 15, lq = lane >> 4;
    constexpr int CT = OUT / 16;
    f32x4 acc[CT];
#pragma unroll
    for (int c = 0; c < CT; c++) acc[c] = (f32x4){0.f, 0.f, 0.f, 0.f};

    const unsigned short* arow = &As[(wv * 16 + lm) * LDK + lq * 8];
#pragma unroll
    for (int kt = 0; kt < K / 32; kt++) {
        bf16x8 a = *(const bf16x8*)(arow + kt * 32);
#pragma unroll
        for (int c = 0; c < CT; c++) {
            bf16x8 b = *(const bf16x8*)&Bs[(c * 16 + lm) * LDK + kt * 32 + lq * 8];
            acc[c] = __builtin_amdgcn_mfma_f32_16x16x32_bf16(a, b, acc[c], 0, 0, 0);
        }
    }

    // epilogue: C/D layout col=lane&15, row=(lane>>4)*4+reg  [m89/m91-verified]
    int r0 = rowBase + wv * 16 + lq * 4;
#pragma unroll
    for (int r = 0; r < 4; r++) {
        int gr = r0 + r;
        if constexpr (OFP8) {
            // unguarded store (rows >= N are zeros); caller sized Y for Npad
            float scale = (gr < N) ? sb[gr] * S_FP8 : 0.f;
#pragma unroll
            for (int c = 0; c < CT; c++) {
                int colg = c * 16 + lm;
                ((unsigned char*)Yv)[(size_t)gr * OUT + colg] = f2fp8(acc[c][r] * scale);
            }
        } else if (gr < N) {
#pragma unroll
            for (int c = 0; c < CT; c++) {
                int colg = c * 16 + lm;
                float v = acc[c][r];
                if constexpr (BIAS_RELU) v = fmaxf(v + sb[colg], 0.f);
                else v = v * sb[gr];
                ((unsigned short*)Yv)[(size_t)gr * OUT + colg] = f2b(v);
            }
        }
    }
}

// ---------------- aggregation (R7): multi-edge gather instructions ----------------
// Wave per node. D=128: lane covers 4 fp8 feats, halves -> 2 edges/inst.
// D=64: quarters -> 4 edges/inst. Col prefetched 64/window, shfl broadcast.

template <bool RELU>
__global__ __launch_bounds__(256) void agg128_k(
    const unsigned char* __restrict__ H,   // [(Npad+1),128] fp8 = S*hprime, row N = 0
    const int* __restrict__ rowptr, const int* __restrict__ col,
    const float* __restrict__ dinv, const float* __restrict__ bias,
    unsigned short* __restrict__ Y, int N, int Ecap) {
    int tid = threadIdx.x;
    int node = blockIdx.x * 4 + (tid >> 6);
    if (node >= N) return;
    int lane = tid & 63;
    int half = lane >> 5;          // which edge of the pair
    int li4 = (lane & 31) * 4;     // feature offset (4 fp8)

    float acc0 = 0.f, acc1 = 0.f, acc2 = 0.f, acc3 = 0.f;
    if (half == 0) {               // self loop (count once)
        unsigned u = *(const unsigned*)(H + (size_t)node * 128 + li4);
        f32x2 lo = __builtin_amdgcn_cvt_pk_f32_fp8((int)u, false);
        f32x2 hi = __builtin_amdgcn_cvt_pk_f32_fp8((int)u, true);
        acc0 = lo[0]; acc1 = lo[1]; acc2 = hi[0]; acc3 = hi[1];
    }

    int start = rowptr[node], end = rowptr[node + 1];   // padded to 8
    for (int e0 = start; e0 < end; e0 += 64) {
        int cidx = e0 + lane;
        int cv = col[min(cidx, Ecap - 1)];
        int pairs = min(64, end - e0) >> 1;             // multiple of 4
        for (int p = 0; p < pairs; p += 4) {
            int s0 = __shfl(cv, 2 * p + half, 64);
            int s1 = __shfl(cv, 2 * p + 2 + half, 64);
            int s2 = __shfl(cv, 2 * p + 4 + half, 64);
            int s3 = __shfl(cv, 2 * p + 6 + half, 64);
            unsigned u0 = *(const unsigned*)(H + (size_t)s0 * 128 + li4);
            unsigned u1 = *(const unsigned*)(H + (size_t)s1 * 128 + li4);
            unsigned u2 = *(const unsigned*)(H + (size_t)s2 * 128 + li4);
            unsigned u3 = *(const unsigned*)(H + (size_t)s3 * 128 + li4);
            f32x2 a0 = __builtin_amdgcn_cvt_pk_f32_fp8((int)u0, false);
            f32x2 b0 = __builtin_amdgcn_cvt_pk_f32_fp8((int)u0, true);
            f32x2 a1 = __builtin_amdgcn_cvt_pk_f32_fp8((int)u1, false);
            f32x2 b1 = __builtin_amdgcn_cvt_pk_f32_fp8((int)u1, true);
            f32x2 a2 = __builtin_amdgcn_cvt_pk_f32_fp8((int)u2, false);
            f32x2 b2 = __builtin_amdgcn_cvt_pk_f32_fp8((int)u2, true);
            f32x2 a3 = __builtin_amdgcn_cvt_pk_f32_fp8((int)u3, false);
            f32x2 b3 = __builtin_amdgcn_cvt_pk_f32_fp8((int)u3, true);
            acc0 += (a0[0] + a1[0]) + (a2[0] + a3[0]);
            acc1 += (a0[1] + a1[1]) + (a2[1] + a3[1]);
            acc2 += (b0[0] + b1[0]) + (b2[0] + b3[0]);
            acc3 += (b0[1] + b1[1]) + (b2[1] + b3[1]);
        }
    }

    // combine the two edge streams
    acc0 += __shfl_xor(acc0, 32, 64);
    acc1 += __shfl_xor(acc1, 32, 64);
    acc2 += __shfl_xor(acc2, 32, 64);
    acc3 += __shfl_xor(acc3, 32, 64);

    if (half == 0) {
        float dv = dinv[node] * S_FP8_INV;
        float4 bb = *(const float4*)(bias + li4);
        float o0 = acc0 * dv + bb.x, o1 = acc1 * dv + bb.y;
        float o2 = acc2 * dv + bb.z, o3 = acc3 * dv + bb.w;
        if (RELU) {
            o0 = fmaxf(o0, 0.f); o1 = fmaxf(o1, 0.f);
            o2 = fmaxf(o2, 0.f); o3 = fmaxf(o3, 0.f);
        }
        ushort4 st = make_ushort4(f2b(o0), f2b(o1), f2b(o2), f2b(o3));
        *(ushort4*)(Y + (size_t)node * 128 + li4) = st;
    }
}

__global__ __launch_bounds__(256) void agg64_k(
    const unsigned char* __restrict__ H,   // [(Npad+1),64] fp8, row N = 0
    const int* __restrict__ rowptr, const int* __restrict__ col,
    const float* __restrict__ dinv, const float* __restrict__ bias,
    unsigned short* __restrict__ Y, int N, int Ecap) {
    int tid = threadIdx.x;
    int node = blockIdx.x * 4 + (tid >> 6);
    if (node >= N) return;
    int lane = tid & 63;
    int quarter = lane >> 4;       // which edge of the quad
    int li4 = (lane & 15) * 4;

    float acc0 = 0.f, acc1 = 0.f, acc2 = 0.f, acc3 = 0.f;
    if (quarter == 0) {
        unsigned u = *(const unsigned*)(H + (size_t)node * 64 + li4);
        f32x2 lo = __builtin_amdgcn_cvt_pk_f32_fp8((int)u, false);
        f32x2 hi = __builtin_amdgcn_cvt_pk_f32_fp8((int)u, true);
        acc0 = lo[0]; acc1 = lo[1]; acc2 = hi[0]; acc3 = hi[1];
    }

    int start = rowptr[node], end = rowptr[node + 1];
    for (int e0 = start; e0 < end; e0 += 64) {
        int cidx = e0 + lane;
        int cv = col[min(cidx, Ecap - 1)];
        int quads = min(64, end - e0) >> 2;             // multiple of 2
        for (int q = 0; q < quads; q += 2) {
            int s0 = __shfl(cv, 4 * q + quarter, 64);
            int s1 = __shfl(cv, 4 * q + 4 + quarter, 64);
            unsigned u0 = *(const unsigned*)(H + (size_t)s0 * 64 + li4);
            unsigned u1 = *(const unsigned*)(H + (size_t)s1 * 64 + li4);
            f32x2 a0 = __builtin_amdgcn_cvt_pk_f32_fp8((int)u0, false);
            f32x2 b0 = __builtin_amdgcn_cvt_pk_f32_fp8((int)u0, true);
            f32x2 a1 = __builtin_amdgcn_cvt_pk_f32_fp8((int)u1, false);
            f32x2 b1 = __builtin_amdgcn_cvt_pk_f32_fp8((int)u1, true);
            acc0 += a0[0] + a1[0];
            acc1 += a0[1] + a1[1];
            acc2 += b0[0] + b1[0];
            acc3 += b0[1] + b1[1];
        }
    }

    acc0 += __shfl_xor(acc0, 16, 64); acc0 += __shfl_xor(acc0, 32, 64);
    acc1 += __shfl_xor(acc1, 16, 64); acc1 += __shfl_xor(acc1, 32, 64);
    acc2 += __shfl_xor(acc2, 16, 64); acc2 += __shfl_xor(acc2, 32, 64);
    acc3 += __shfl_xor(acc3, 16, 64); acc3 += __shfl_xor(acc3, 32, 64);

    if (quarter == 0 && (lane >> 5) == 0) {
        float dv = dinv[node] * S_FP8_INV;
        float4 bb = *(const float4*)(bias + li4);
        ushort4 st = make_ushort4(f2b(acc0 * dv + bb.x), f2b(acc1 * dv + bb.y),
                                  f2b(acc2 * dv + bb.z), f2b(acc3 * dv + bb.w));
        *(ushort4*)(Y + (size_t)node * 64 + li4) = st;
    }
}

// ---------------- final: logits + softmax + value ----------------

__global__ __launch_bounds__(256) void logits_k(
    const unsigned short* __restrict__ A2,   // [N,64] bf16
    const unsigned short* __restrict__ C2,   // [N,64] bf16
    const float* __restrict__ Wa3, const float* __restrict__ ba3,
    const float* __restrict__ Wc3, const float* __restrict__ bc3,
    float* __restrict__ out, int N) {
    int t = threadIdx.x;
    int node = blockIdx.x * 32 + (t >> 3);
    int a = t & 7;
    if (node >= N) return;

    const unsigned short* ar = A2 + (size_t)node * 64;
    float s = ba3[a];
#pragma unroll
    for (int q = 0; q < 8; q++) {
        uint4 pv = *(const uint4*)(ar + q * 8);
        const unsigned short* pu = (const unsigned short*)&pv;
#pragma unroll
        for (int j = 0; j < 8; j++)
            s = fmaf(b2f(pu[j]), Wa3[(q * 8 + j) * 8 + a], s);
    }
    float m = s;
#pragma unroll
    for (int w = 1; w < 8; w <<= 1) m = fmaxf(m, __shfl_xor(m, w, 64));
    float e = expf(s - m);
    float sum = e;
#pragma unroll
    for (int w = 1; w < 8; w <<= 1) sum += __shfl_xor(sum, w, 64);
    out[(size_t)node * 9 + a] = e / sum;

    if (a == 0) {
        const unsigned short* cr = C2 + (size_t)node * 64;
        float v = bc3[0];
#pragma unroll
        for (int q = 0; q < 8; q++) {
            uint4 pv = *(const uint4*)(cr + q * 8);
            const unsigned short* pu = (const unsigned short*)&pv;
#pragma unroll
            for (int j = 0; j < 8; j++)
                v = fmaf(b2f(pu[j]), Wc3[q * 8 + j], v);
        }
        out[(size_t)node * 9 + 8] = v;
    }
}

// ---------------- launch ----------------

extern "C" void kernel_launch(void* const* d_in, const int* in_sizes, int n_in,
                              void* d_out, int out_size, void* d_ws, size_t ws_size,
                              hipStream_t stream) {
    const float* x   = (const float*)d_in[0];
    const int*   ei  = (const int*)d_in[1];
    const float* W1  = (const float*)d_in[2];  const float* b1  = (const float*)d_in[3];
    const float* W2  = (const float*)d_in[4];  const float* b2  = (const float*)d_in[5];
    const float* W3  = (const float*)d_in[6];  const float* b3  = (const float*)d_in[7];
    const float* Wa1 = (const float*)d_in[8];  const float* ba1 = (const float*)d_in[9];
    const float* Wa2 = (const float*)d_in[10]; const float* ba2 = (const float*)d_in[11];
    const float* Wa3 = (const float*)d_in[12]; const float* ba3 = (const float*)d_in[13];
    const float* Wc1 = (const float*)d_in[14]; const float* bc1 = (const float*)d_in[15];
    const float* Wc2 = (const float*)d_in[16]; const float* bc2 = (const float*)d_in[17];
    const float* Wc3 = (const float*)d_in[18]; const float* bc3 = (const float*)d_in[19];
    float* out = (float*)d_out;

    const int N = in_sizes[0] / 128;     // 100000
    const int E = in_sizes[1] / 2;       // 3200000
    const int* src = ei;
    const int* dst = ei + E;
    const int Ecap = E + 8 * N;          // padded-CSR capacity
    const int Npad = ((N + 63) / 64) * 64;

    // workspace layout
    size_t off = 0;
    auto take = [&](size_t bytes) { size_t o = off; off = WS_ALIGN(off + bytes); return o; };
    char* ws = (char*)d_ws;
    unsigned short* h      = (unsigned short*)(ws + take((size_t)N * 128 * 2));      // 25.6MB
    unsigned char*  hpr8   = (unsigned char*) (ws + take((size_t)(Npad + 64) * 128));// 12.8MB
    unsigned short* h3     = (unsigned short*)(ws + take((size_t)N * 64 * 2));       // 12.8MB
    int*            col    = (int*)(ws + take((size_t)Ecap * 4));                    // 16MB
    unsigned short* A1C1   = (unsigned short*)(ws + take((size_t)N * 128 * 2));      // 25.6MB
    unsigned short* wt     = (unsigned short*)(ws + take(73728 * 2));
    float* dinv   = (float*)(ws + take((size_t)(N + 64) * 4));
    int*   cnt    = (int*)  (ws + take((size_t)N * 4));
    int*   rowptr = (int*)  (ws + take((size_t)(N + 1) * 4));
    int*   bcnt   = (int*)  (ws + take(RNG * NB_A * 4));
    int*   base   = (int*)  (ws + take(RNG * NB_A * 4));
    int*   bstart = (int*)  (ws + take((RNG + 1) * 4));
    int*   bsum   = (int*)  (ws + take(512 * 4));
    int*   boff   = (int*)  (ws + take(512 * 4));
    // aliases: bucket (E*8=25.6MB) on h [dead until agg L1];
    // hist (12.8MB) on A1C1 [dead until heads]; A2 on col [dead after agg64];
    // C2 on hpr8 [dead after agg64].
    unsigned long long* bucket = (unsigned long long*)h;
    int* hist = (int*)A1C1;
    unsigned short* A2 = (unsigned short*)col;   // [N,64] bf16 = 12.8MB <= 16MB
    unsigned short* C2 = (unsigned short*)hpr8;  // [N,64] bf16 = 12.8MB
    (void)ws_size; (void)n_in; (void)out_size;

    const int nb  = (N + 255) / 256;     // 391 (<512)
    const int gN  = (N + 255) / 256;
    const int gT  = (N + 63) / 64;       // 1563

    prep_w_k<<<288, 256, 0, stream>>>(W1, W2, W3, Wa1, Wa2, Wc1, Wc2, wt);
    const unsigned short* W1t  = wt;
    const unsigned short* W2t  = wt + 16384;
    const unsigned short* W3t  = wt + 32768;
    const unsigned short* Wa1t = wt + 40960;
    const unsigned short* Wa2t = wt + 49152;
    const unsigned short* Wc1t = wt + 57344;
    const unsigned short* Wc2t = wt + 65536;

    // CSR build: bucket sort, padded ranges (multiples of 8, pad -> row N)
    bucket_count_k<<<NB_A, 256, 0, stream>>>(dst, bcnt, E);
    bucket_off_k<<<1, 1024, 0, stream>>>(bcnt, base, bstart, E);
    bucket_scatter_k<<<NB_A, 256, 0, stream>>>(src, dst, base, bucket, E);
    hist_bucket_k<<<RNG * CHK, 256, 0, stream>>>(bucket, bstart, hist);
    sum_hist_dinv_k<<<gN, 256, 0, stream>>>(hist, cnt, dinv, N);
    chunk_sum_k<<<nb, 256, 0, stream>>>(cnt, bsum, N);
    scan_mid_k<<<1, 512, 0, stream>>>(bsum, boff, nb, rowptr, N);
    scan_final_k<<<nb, 256, 0, stream>>>(cnt, boff, rowptr, N);
    offsets_k<<<gN, 256, 0, stream>>>(hist, rowptr, N);
    fill2_k<<<RNG * CHK, 256, 0, stream>>>(bucket, bstart, hist, col);
    pad_col_k<<<gN, 256, 0, stream>>>(cnt, rowptr, col, N);

    // GCN layer 1: 128 -> 128, relu
    gemm_mfma_k<128, 128, true,  false, true><<<gT, 256, 0, stream>>>(x, W1t, dinv, hpr8, N);
    agg128_k<true><<<(N + 3) / 4, 256, 0, stream>>>(hpr8, rowptr, col, dinv, b1, h, N, Ecap);
    // GCN layer 2: 128 -> 128, relu
    gemm_mfma_k<128, 128, false, false, true><<<gT, 256, 0, stream>>>(h, W2t, dinv, hpr8, N);
    agg128_k<true><<<(N + 3) / 4, 256, 0, stream>>>(hpr8, rowptr, col, dinv, b2, h, N, Ecap);
    // GCN layer 3: 128 -> 64, linear
    gemm_mfma_k<128, 64,  false, false, true><<<gT, 256, 0, stream>>>(h, W3t, dinv, hpr8, N);
    agg64_k<<<(N + 3) / 4, 256, 0, stream>>>(hpr8, rowptr, col, dinv, b3, h3, N, Ecap);

    // heads (col/hpr8 now dead; A2/C2 alias them)
    gemm_mfma_k<64,  128, false, true, false><<<gT, 256, 0, stream>>>(h3, Wa1t, ba1, A1C1, N);
    gemm_mfma_k<128, 64,  false, true, false><<<gT, 256, 0, stream>>>(A1C1, Wa2t, ba2, A2, N);
    gemm_mfma_k<64,  128, false, true, false><<<gT, 256, 0, stream>>>(h3, Wc1t, bc1, A1C1, N);
    gemm_mfma_k<128, 64,  false, true, false><<<gT, 256, 0, stream>>>(A1C1, Wc2t, bc2, C2, N);
    logits_k<<<(N + 31) / 32, 256, 0, stream>>>(A2, C2, Wa3, ba3, Wc3, bc3, out, N);
}

// Round 8
// 507.021 us; speedup vs baseline: 2.9388x; 1.1021x over previous
//
#include <hip/hip_runtime.h>
#include <hip/hip_bf16.h>
#include <math.h>

// ---------------------------------------------------------------------------
// FederatedPPOAgent: 3x GCNConv (N=100k, E=3.2M, D=128) + actor/critic MLPs.
//
// R8 changes vs R7:
//  - agg: uint2 (8B/lane) gathers -> 4 edges/inst (D=128) / 8 edges/inst
//    (D=64); f32x2 accumulators (v_pk_add_f32); half the shfl broadcasts.
//    (R7 was VALU-limited: VALUBusy 59%.)
//  - CSR: u32 bucket entries (dl<<17|src), 64 node-ranges x 1024 scatter
//    blocks x 16 chunks; hist/fill LDS 50KB->6.3KB, grids 256->1024 blocks;
//    hist 12.8->6.4MB; hierarchical scan (rsum_k per range + rstart_k).
// ---------------------------------------------------------------------------

#define WS_ALIGN(x) (((x) + 255) & ~(size_t)255)

constexpr int RNG  = 64;        // node ranges
constexpr int NRG  = 1563;      // nodes per range (64*1563 = 100032 >= 100000)
constexpr int NB   = 1024;      // bucket-phase blocks
constexpr int CHK  = 16;        // per-range fill chunks

constexpr float S_FP8     = 64.0f;
constexpr float S_FP8_INV = 1.0f / 64.0f;

using bf16x8 = __attribute__((ext_vector_type(8))) short;
using f32x4  = __attribute__((ext_vector_type(4))) float;
using f32x2  = __attribute__((ext_vector_type(2))) float;

__device__ __forceinline__ float b2f(unsigned short u) {
    return __uint_as_float(((unsigned int)u) << 16);
}
__device__ __forceinline__ unsigned short f2b(float f) {
    __hip_bfloat16 hb = __float2bfloat16(f);
    return *(unsigned short*)&hb;
}
__device__ __forceinline__ unsigned char f2fp8(float f) {
    return (unsigned char)(__builtin_amdgcn_cvt_pk_fp8_f32(f, f, 0, false) & 0xff);
}
__device__ __forceinline__ int pad8(int v) { return (v + 7) & ~7; }

// 8 fp8 (uint2) -> 4 packed-f32 accumulators
__device__ __forceinline__ void acc8(uint2 u, f32x2& a01, f32x2& a23,
                                     f32x2& a45, f32x2& a67) {
    a01 += __builtin_amdgcn_cvt_pk_f32_fp8((int)u.x, false);
    a23 += __builtin_amdgcn_cvt_pk_f32_fp8((int)u.x, true);
    a45 += __builtin_amdgcn_cvt_pk_f32_fp8((int)u.y, false);
    a67 += __builtin_amdgcn_cvt_pk_f32_fp8((int)u.y, true);
}

// ---------------- CSR build ----------------

__global__ __launch_bounds__(256) void bucket_count_k(
    const int* __restrict__ dst, int* __restrict__ bcnt, int E) {
    __shared__ int c64[RNG];
    int b = blockIdx.x, t = threadIdx.x;
    if (t < RNG) c64[t] = 0;
    __syncthreads();
    int ec = (E + NB - 1) / NB;
    int e0 = b * ec, e1 = min(E, e0 + ec);
    for (int e = e0 + t; e < e1; e += 256) {
        int d = __builtin_nontemporal_load(dst + e);
        atomicAdd(&c64[d / NRG], 1);
    }
    __syncthreads();
    if (t < RNG) bcnt[t * NB + b] = c64[t];
}

// block r: exclusive scan of bcnt[r][0..NB) -> base, total -> rtot[r]
__global__ __launch_bounds__(256) void rsum_k(
    const int* __restrict__ bcnt, int* __restrict__ base, int* __restrict__ rtot) {
    __shared__ int s[256];
    int r = blockIdx.x, t = threadIdx.x;
    const int* row = bcnt + (size_t)r * NB;
    int v[4], loc = 0;
#pragma unroll
    for (int j = 0; j < 4; j++) { v[j] = row[t * 4 + j]; loc += v[j]; }
    s[t] = loc;
    __syncthreads();
    for (int d = 1; d < 256; d <<= 1) {
        int x = (t >= d) ? s[t - d] : 0;
        __syncthreads();
        s[t] += x;
        __syncthreads();
    }
    int run = s[t] - loc;   // exclusive
    int* bp = base + (size_t)r * NB + t * 4;
#pragma unroll
    for (int j = 0; j < 4; j++) { bp[j] = run; run += v[j]; }
    if (t == 255) rtot[r] = s[255];
}

__global__ void rstart_k(const int* __restrict__ rtot, int* __restrict__ bstart) {
    if (threadIdx.x == 0) {
        int run = 0;
        for (int r = 0; r < RNG; r++) { bstart[r] = run; run += rtot[r]; }
        bstart[RNG] = run;
    }
}

__global__ __launch_bounds__(256) void bucket_scatter_k(
    const int* __restrict__ src, const int* __restrict__ dst,
    const int* __restrict__ base, const int* __restrict__ bstart,
    unsigned* __restrict__ bucket, int E) {
    __shared__ int cur[RNG];
    int b = blockIdx.x, t = threadIdx.x;
    if (t < RNG) cur[t] = bstart[t] + base[(size_t)t * NB + b];
    __syncthreads();
    int ec = (E + NB - 1) / NB;
    int e0 = b * ec, e1 = min(E, e0 + ec);
    for (int e = e0 + t; e < e1; e += 256) {
        int d = __builtin_nontemporal_load(dst + e);
        int sv = __builtin_nontemporal_load(src + e);
        int r = d / NRG;
        int pos = atomicAdd(&cur[r], 1);
        bucket[pos] = ((unsigned)(d - r * NRG) << 17) | (unsigned)sv;
    }
}

__global__ __launch_bounds__(256) void hist_bucket_k(
    const unsigned* __restrict__ bucket, const int* __restrict__ bstart,
    int* __restrict__ hist) {
    __shared__ int h[NRG];
    int b = blockIdx.x, r = b & 63, c2 = b >> 6, t = threadIdx.x;
    for (int i = t; i < NRG; i += 256) h[i] = 0;
    int s0 = bstart[r], s1 = bstart[r + 1];
    int ec = (s1 - s0 + CHK - 1) / CHK;
    int e0 = s0 + c2 * ec, e1 = min(s1, e0 + ec);
    __syncthreads();
    for (int e = e0 + t; e < e1; e += 256) {
        unsigned v = __builtin_nontemporal_load(bucket + e);
        atomicAdd(&h[v >> 17], 1);
    }
    __syncthreads();
    int* out = hist + ((size_t)r * CHK + c2) * NRG;
    for (int i = t; i < NRG; i += 256) out[i] = h[i];
}

__global__ void sum_hist_dinv_k(const int* __restrict__ hist, int* __restrict__ cnt,
                                float* __restrict__ dinv, int N) {
    int i = blockIdx.x * 256 + threadIdx.x;
    if (i >= N) return;
    int r = i / NRG, li = i - r * NRG;
    const int* hp = hist + ((size_t)r * CHK) * NRG + li;
    int s = 0;
#pragma unroll
    for (int c = 0; c < CHK; c++) s += hp[(size_t)c * NRG];
    cnt[i] = s;
    dinv[i] = rsqrtf((float)s + 1.0f);   // +1: self loop
}

// prefix sums over PADDED counts (pad8) so every node range is 8-aligned
__global__ void chunk_sum_k(const int* __restrict__ cnt, int* __restrict__ bsum, int n) {
    __shared__ int sd[256];
    int t = threadIdx.x;
    int i = blockIdx.x * 256 + t;
    sd[t] = (i < n) ? pad8(cnt[i]) : 0;
    __syncthreads();
    for (int d = 128; d > 0; d >>= 1) {
        if (t < d) sd[t] += sd[t + d];
        __syncthreads();
    }
    if (t == 0) bsum[blockIdx.x] = sd[0];
}

__global__ void scan_mid_k(const int* __restrict__ bsum, int* __restrict__ boff,
                           int nb, int* __restrict__ rowptr, int N) {
    __shared__ int s[512];
    int t = threadIdx.x;
    s[t] = (t < nb) ? bsum[t] : 0;
    __syncthreads();
    if (t == 0) {
        int run = 0;
        for (int i = 0; i < nb; i++) { int v = s[i]; s[i] = run; run += v; }
        rowptr[N] = run;
    }
    __syncthreads();
    if (t < nb) boff[t] = s[t];
}

__global__ void scan_final_k(const int* __restrict__ cnt, const int* __restrict__ boff,
                             int* __restrict__ rowptr, int n) {
    __shared__ int s[256];
    int t = threadIdx.x;
    int i = blockIdx.x * 256 + t;
    int v = (i < n) ? pad8(cnt[i]) : 0;
    s[t] = v;
    __syncthreads();
    for (int d = 1; d < 256; d <<= 1) {
        int x = (t >= d) ? s[t - d] : 0;
        __syncthreads();
        s[t] += x;
        __syncthreads();
    }
    if (i < n) rowptr[i] = s[t] - v + boff[blockIdx.x];
}

__global__ void offsets_k(int* __restrict__ hist, const int* __restrict__ rowptr, int N) {
    int i = blockIdx.x * 256 + threadIdx.x;
    if (i >= N) return;
    int r = i / NRG, li = i - r * NRG;
    int* hp = hist + ((size_t)r * CHK) * NRG + li;
    int run = rowptr[i];
#pragma unroll
    for (int c = 0; c < CHK; c++) {
        int v = hp[(size_t)c * NRG];
        hp[(size_t)c * NRG] = run;
        run += v;
    }
}

__global__ __launch_bounds__(256) void fill2_k(
    const unsigned* __restrict__ bucket, const int* __restrict__ bstart,
    const int* __restrict__ hist, int* __restrict__ col) {
    __shared__ int cur[NRG];
    int b = blockIdx.x, r = b & 63, c2 = b >> 6, t = threadIdx.x;
    const int* hp = hist + ((size_t)r * CHK + c2) * NRG;
    for (int i = t; i < NRG; i += 256) cur[i] = hp[i];
    int s0 = bstart[r], s1 = bstart[r + 1];
    int ec = (s1 - s0 + CHK - 1) / CHK;
    int e0 = s0 + c2 * ec, e1 = min(s1, e0 + ec);
    __syncthreads();
    for (int e = e0 + t; e < e1; e += 256) {
        unsigned v = __builtin_nontemporal_load(bucket + e);
        int slot = atomicAdd(&cur[v >> 17], 1);   // LDS atomic
        col[slot] = (int)(v & 0x1FFFFu);
    }
}

// fill pad slots [rowptr[i]+cnt, rowptr[i+1]) with the zero-row index N
__global__ void pad_col_k(const int* __restrict__ cnt, const int* __restrict__ rowptr,
                          int* __restrict__ col, int N) {
    int i = blockIdx.x * 256 + threadIdx.x;
    if (i >= N) return;
    int e = rowptr[i] + cnt[i], end = rowptr[i + 1];
    for (; e < end; e++) col[e] = N;
}

// ---------------- weight prep: fp32 W[K][OUT] -> bf16 W^T[OUT][K] ----------------

__global__ __launch_bounds__(256) void prep_w_k(
    const float* __restrict__ W1, const float* __restrict__ W2,
    const float* __restrict__ W3, const float* __restrict__ Wa1,
    const float* __restrict__ Wa2, const float* __restrict__ Wc1,
    const float* __restrict__ Wc2, unsigned short* __restrict__ wt) {
    int i = blockIdx.x * 256 + threadIdx.x;   // 0..73727
    const float* W; int off, K, OUT;
    if (i < 16384)      { W = W1;  off = 0;     K = 128; OUT = 128; }
    else if (i < 32768) { W = W2;  off = 16384; K = 128; OUT = 128; }
    else if (i < 40960) { W = W3;  off = 32768; K = 128; OUT = 64; }
    else if (i < 49152) { W = Wa1; off = 40960; K = 64;  OUT = 128; }
    else if (i < 57344) { W = Wa2; off = 49152; K = 128; OUT = 64; }
    else if (i < 65536) { W = Wc1; off = 57344; K = 64;  OUT = 128; }
    else                { W = Wc2; off = 65536; K = 128; OUT = 64; }
    int j = i - off, k = j / OUT, n = j - k * OUT;
    wt[off + n * K + k] = f2b(W[j]);
}

// ---------------- MFMA GEMM: Y = epi(X @ W) ----------------

template <int K, int OUT, bool AF32, bool BIAS_RELU, bool OFP8>
__global__ __launch_bounds__(256) void gemm_mfma_k(
    const void* __restrict__ Xv, const unsigned short* __restrict__ Wt,  // [OUT][K]
    const float* __restrict__ sb,   // dinv or bias
    void* __restrict__ Yv, int N) {
    constexpr int LDK = K + 8;
    __shared__ __align__(16) unsigned short As[64 * LDK];
    __shared__ __align__(16) unsigned short Bs[OUT * LDK];
    int t = threadIdx.x;
    int rowBase = blockIdx.x * 64;

    if constexpr (AF32) {
        const float* X = (const float*)Xv;
        for (int g = t; g < 64 * (K / 8); g += 256) {
            int r = g / (K / 8), q = g - r * (K / 8);
            int gr = rowBase + r;
            unsigned short us[8];
            if (gr < N) {
                float4 v0 = *(const float4*)(X + (size_t)gr * K + q * 8);
                float4 v1 = *(const float4*)(X + (size_t)gr * K + q * 8 + 4);
                us[0] = f2b(v0.x); us[1] = f2b(v0.y); us[2] = f2b(v0.z); us[3] = f2b(v0.w);
                us[4] = f2b(v1.x); us[5] = f2b(v1.y); us[6] = f2b(v1.z); us[7] = f2b(v1.w);
            } else {
#pragma unroll
                for (int j = 0; j < 8; j++) us[j] = 0;
            }
            *(uint4*)&As[r * LDK + q * 8] = *(uint4*)us;
        }
    } else {
        const unsigned short* X = (const unsigned short*)Xv;
        for (int g = t; g < 64 * (K / 8); g += 256) {
            int r = g / (K / 8), q = g - r * (K / 8);
            int gr = rowBase + r;
            uint4 v = make_uint4(0, 0, 0, 0);
            if (gr < N) v = *(const uint4*)(X + (size_t)gr * K + q * 8);
            *(uint4*)&As[r * LDK + q * 8] = v;
        }
    }
    for (int g = t; g < OUT * (K / 8); g += 256) {
        int r = g / (K / 8), q = g - r * (K / 8);
        *(uint4*)&Bs[r * LDK + q * 8] = *(const uint4*)(Wt + r * K + q * 8);
    }
    __syncthreads();

    int wv = t >> 6, lane = t & 63;
    int lm = lane & 15, lq = lane >> 4;
    constexpr int CT = OUT / 16;
    f32x4 acc[CT];
#pragma unroll
    for (int c = 0; c < CT; c++) acc[c] = (f32x4){0.f, 0.f, 0.f, 0.f};

    const unsigned short* arow = &As[(wv * 16 + lm) * LDK + lq * 8];
#pragma unroll
    for (int kt = 0; kt < K / 32; kt++) {
        bf16x8 a = *(const bf16x8*)(arow + kt * 32);
#pragma unroll
        for (int c = 0; c < CT; c++) {
            bf16x8 b = *(const bf16x8*)&Bs[(c * 16 + lm) * LDK + kt * 32 + lq * 8];
            acc[c] = __builtin_amdgcn_mfma_f32_16x16x32_bf16(a, b, acc[c], 0, 0, 0);
        }
    }

    // epilogue: C/D layout col=lane&15, row=(lane>>4)*4+reg  [m89/m91-verified]
    int r0 = rowBase + wv * 16 + lq * 4;
#pragma unroll
    for (int r = 0; r < 4; r++) {
        int gr = r0 + r;
        if constexpr (OFP8) {
            // unguarded store (rows >= N are zeros); Y sized for Npad
            float scale = (gr < N) ? sb[gr] * S_FP8 : 0.f;
#pragma unroll
            for (int c = 0; c < CT; c++) {
                int colg = c * 16 + lm;
                ((unsigned char*)Yv)[(size_t)gr * OUT + colg] = f2fp8(acc[c][r] * scale);
            }
        } else if (gr < N) {
#pragma unroll
            for (int c = 0; c < CT; c++) {
                int colg = c * 16 + lm;
                float v = acc[c][r];
                if constexpr (BIAS_RELU) v = fmaxf(v + sb[colg], 0.f);
                else v = v * sb[gr];
                ((unsigned short*)Yv)[(size_t)gr * OUT + colg] = f2b(v);
            }
        }
    }
}

// ---------------- aggregation (R8): uint2 gathers, packed-f32 accumulate ----------------
// Wave per node. D=128: 16 lanes x 8B/row -> 4 edges/inst.
// D=64: 8 lanes x 8B/row -> 8 edges/inst.

template <bool RELU>
__global__ __launch_bounds__(256) void agg128_k(
    const unsigned char* __restrict__ H,   // [(Npad+1),128] fp8 = S*hprime, rows>=N zero
    const int* __restrict__ rowptr, const int* __restrict__ col,
    const float* __restrict__ dinv, const float* __restrict__ bias,
    unsigned short* __restrict__ Y, int N, int Ecap) {
    int tid = threadIdx.x;
    int node = blockIdx.x * 4 + (tid >> 6);
    if (node >= N) return;
    int lane = tid & 63;
    int grp = lane >> 4;            // which edge of the quad
    int li8 = (lane & 15) * 8;      // feature offset (8 fp8)

    f32x2 a01 = {0.f, 0.f}, a23 = {0.f, 0.f}, a45 = {0.f, 0.f}, a67 = {0.f, 0.f};
    if (grp == 0) {                 // self loop (count once)
        uint2 u = *(const uint2*)(H + (size_t)node * 128 + li8);
        acc8(u, a01, a23, a45, a67);
    }

    int start = rowptr[node], end = rowptr[node + 1];   // padded to 8
    for (int e0 = start; e0 < end; e0 += 64) {
        int cv = col[min(e0 + lane, Ecap - 1)];
        int quads = min(64, end - e0) >> 2;             // multiple of 2
        for (int q = 0; q < quads; q += 2) {
            int s0 = __shfl(cv, 4 * q + grp, 64);
            int s1 = __shfl(cv, 4 * q + 4 + grp, 64);
            uint2 u0 = *(const uint2*)(H + (size_t)s0 * 128 + li8);
            uint2 u1 = *(const uint2*)(H + (size_t)s1 * 128 + li8);
            acc8(u0, a01, a23, a45, a67);
            acc8(u1, a01, a23, a45, a67);
        }
    }

    // combine the 4 edge streams (lanes with same lane&15)
#pragma unroll
    for (int w = 16; w < 64; w <<= 1) {
        a01[0] += __shfl_xor(a01[0], w, 64); a01[1] += __shfl_xor(a01[1], w, 64);
        a23[0] += __shfl_xor(a23[0], w, 64); a23[1] += __shfl_xor(a23[1], w, 64);
        a45[0] += __shfl_xor(a45[0], w, 64); a45[1] += __shfl_xor(a45[1], w, 64);
        a67[0] += __shfl_xor(a67[0], w, 64); a67[1] += __shfl_xor(a67[1], w, 64);
    }

    if (grp == 0) {
        float dv = dinv[node] * S_FP8_INV;
        float4 b0 = *(const float4*)(bias + li8);
        float4 b1 = *(const float4*)(bias + li8 + 4);
        float o0 = a01[0] * dv + b0.x, o1 = a01[1] * dv + b0.y;
        float o2 = a23[0] * dv + b0.z, o3 = a23[1] * dv + b0.w;
        float o4 = a45[0] * dv + b1.x, o5 = a45[1] * dv + b1.y;
        float o6 = a67[0] * dv + b1.z, o7 = a67[1] * dv + b1.w;
        if (RELU) {
            o0 = fmaxf(o0, 0.f); o1 = fmaxf(o1, 0.f); o2 = fmaxf(o2, 0.f); o3 = fmaxf(o3, 0.f);
            o4 = fmaxf(o4, 0.f); o5 = fmaxf(o5, 0.f); o6 = fmaxf(o6, 0.f); o7 = fmaxf(o7, 0.f);
        }
        unsigned short us[8] = {f2b(o0), f2b(o1), f2b(o2), f2b(o3),
                                f2b(o4), f2b(o5), f2b(o6), f2b(o7)};
        *(uint4*)(Y + (size_t)node * 128 + li8) = *(uint4*)us;
    }
}

__global__ __launch_bounds__(256) void agg64_k(
    const unsigned char* __restrict__ H,   // [(Npad+1),64] fp8, rows>=N zero
    const int* __restrict__ rowptr, const int* __restrict__ col,
    const float* __restrict__ dinv, const float* __restrict__ bias,
    unsigned short* __restrict__ Y, int N, int Ecap) {
    int tid = threadIdx.x;
    int node = blockIdx.x * 4 + (tid >> 6);
    if (node >= N) return;
    int lane = tid & 63;
    int grp = lane >> 3;            // which edge of the oct
    int li8 = (lane & 7) * 8;

    f32x2 a01 = {0.f, 0.f}, a23 = {0.f, 0.f}, a45 = {0.f, 0.f}, a67 = {0.f, 0.f};
    if (grp == 0) {
        uint2 u = *(const uint2*)(H + (size_t)node * 64 + li8);
        acc8(u, a01, a23, a45, a67);
    }

    int start = rowptr[node], end = rowptr[node + 1];
    for (int e0 = start; e0 < end; e0 += 64) {
        int cv = col[min(e0 + lane, Ecap - 1)];
        int octs = min(64, end - e0) >> 3;              // >= 1
        int o = 0;
        for (; o + 2 <= octs; o += 2) {
            int s0 = __shfl(cv, 8 * o + grp, 64);
            int s1 = __shfl(cv, 8 * o + 8 + grp, 64);
            uint2 u0 = *(const uint2*)(H + (size_t)s0 * 64 + li8);
            uint2 u1 = *(const uint2*)(H + (size_t)s1 * 64 + li8);
            acc8(u0, a01, a23, a45, a67);
            acc8(u1, a01, a23, a45, a67);
        }
        if (o < octs) {
            int s0 = __shfl(cv, 8 * o + grp, 64);
            uint2 u0 = *(const uint2*)(H + (size_t)s0 * 64 + li8);
            acc8(u0, a01, a23, a45, a67);
        }
    }

#pragma unroll
    for (int w = 8; w < 64; w <<= 1) {
        a01[0] += __shfl_xor(a01[0], w, 64); a01[1] += __shfl_xor(a01[1], w, 64);
        a23[0] += __shfl_xor(a23[0], w, 64); a23[1] += __shfl_xor(a23[1], w, 64);
        a45[0] += __shfl_xor(a45[0], w, 64); a45[1] += __shfl_xor(a45[1], w, 64);
        a67[0] += __shfl_xor(a67[0], w, 64); a67[1] += __shfl_xor(a67[1], w, 64);
    }

    if (grp == 0) {
        float dv = dinv[node] * S_FP8_INV;
        float4 b0 = *(const float4*)(bias + li8);
        float4 b1 = *(const float4*)(bias + li8 + 4);
        unsigned short us[8] = {
            f2b(a01[0] * dv + b0.x), f2b(a01[1] * dv + b0.y),
            f2b(a23[0] * dv + b0.z), f2b(a23[1] * dv + b0.w),
            f2b(a45[0] * dv + b1.x), f2b(a45[1] * dv + b1.y),
            f2b(a67[0] * dv + b1.z), f2b(a67[1] * dv + b1.w)};
        *(uint4*)(Y + (size_t)node * 64 + li8) = *(uint4*)us;
    }
}

// ---------------- final: logits + softmax + value ----------------

__global__ __launch_bounds__(256) void logits_k(
    const unsigned short* __restrict__ A2,   // [N,64] bf16
    const unsigned short* __restrict__ C2,   // [N,64] bf16
    const float* __restrict__ Wa3, const float* __restrict__ ba3,
    const float* __restrict__ Wc3, const float* __restrict__ bc3,
    float* __restrict__ out, int N) {
    int t = threadIdx.x;
    int node = blockIdx.x * 32 + (t >> 3);
    int a = t & 7;
    if (node >= N) return;

    const unsigned short* ar = A2 + (size_t)node * 64;
    float s = ba3[a];
#pragma unroll
    for (int q = 0; q < 8; q++) {
        uint4 pv = *(const uint4*)(ar + q * 8);
        const unsigned short* pu = (const unsigned short*)&pv;
#pragma unroll
        for (int j = 0; j < 8; j++)
            s = fmaf(b2f(pu[j]), Wa3[(q * 8 + j) * 8 + a], s);
    }
    float m = s;
#pragma unroll
    for (int w = 1; w < 8; w <<= 1) m = fmaxf(m, __shfl_xor(m, w, 64));
    float e = expf(s - m);
    float sum = e;
#pragma unroll
    for (int w = 1; w < 8; w <<= 1) sum += __shfl_xor(sum, w, 64);
    out[(size_t)node * 9 + a] = e / sum;

    if (a == 0) {
        const unsigned short* cr = C2 + (size_t)node * 64;
        float v = bc3[0];
#pragma unroll
        for (int q = 0; q < 8; q++) {
            uint4 pv = *(const uint4*)(cr + q * 8);
            const unsigned short* pu = (const unsigned short*)&pv;
#pragma unroll
            for (int j = 0; j < 8; j++)
                v = fmaf(b2f(pu[j]), Wc3[q * 8 + j], v);
        }
        out[(size_t)node * 9 + 8] = v;
    }
}

// ---------------- launch ----------------

extern "C" void kernel_launch(void* const* d_in, const int* in_sizes, int n_in,
                              void* d_out, int out_size, void* d_ws, size_t ws_size,
                              hipStream_t stream) {
    const float* x   = (const float*)d_in[0];
    const int*   ei  = (const int*)d_in[1];
    const float* W1  = (const float*)d_in[2];  const float* b1  = (const float*)d_in[3];
    const float* W2  = (const float*)d_in[4];  const float* b2  = (const float*)d_in[5];
    const float* W3  = (const float*)d_in[6];  const float* b3  = (const float*)d_in[7];
    const float* Wa1 = (const float*)d_in[8];  const float* ba1 = (const float*)d_in[9];
    const float* Wa2 = (const float*)d_in[10]; const float* ba2 = (const float*)d_in[11];
    const float* Wa3 = (const float*)d_in[12]; const float* ba3 = (const float*)d_in[13];
    const float* Wc1 = (const float*)d_in[14]; const float* bc1 = (const float*)d_in[15];
    const float* Wc2 = (const float*)d_in[16]; const float* bc2 = (const float*)d_in[17];
    const float* Wc3 = (const float*)d_in[18]; const float* bc3 = (const float*)d_in[19];
    float* out = (float*)d_out;

    const int N = in_sizes[0] / 128;     // 100000
    const int E = in_sizes[1] / 2;       // 3200000
    const int* src = ei;
    const int* dst = ei + E;
    const int Ecap = E + 8 * N;          // padded-CSR capacity
    const int Npad = ((N + 63) / 64) * 64;

    // workspace layout
    size_t off = 0;
    auto take = [&](size_t bytes) { size_t o = off; off = WS_ALIGN(off + bytes); return o; };
    char* ws = (char*)d_ws;
    unsigned short* h      = (unsigned short*)(ws + take((size_t)N * 128 * 2));      // 25.6MB
    unsigned char*  hpr8   = (unsigned char*) (ws + take((size_t)(Npad + 64) * 128));// 12.8MB
    unsigned short* h3     = (unsigned short*)(ws + take((size_t)N * 64 * 2));       // 12.8MB
    int*            col    = (int*)(ws + take((size_t)Ecap * 4));                    // 16MB
    unsigned short* A1C1   = (unsigned short*)(ws + take((size_t)N * 128 * 2));      // 25.6MB
    unsigned short* wt     = (unsigned short*)(ws + take(73728 * 2));
    float* dinv   = (float*)(ws + take((size_t)(N + 64) * 4));
    int*   cnt    = (int*)  (ws + take((size_t)N * 4));
    int*   rowptr = (int*)  (ws + take((size_t)(N + 1) * 4));
    int*   bcnt   = (int*)  (ws + take((size_t)RNG * NB * 4));    // 256KB
    int*   base   = (int*)  (ws + take((size_t)RNG * NB * 4));    // 256KB
    int*   rtot   = (int*)  (ws + take(RNG * 4));
    int*   bstart = (int*)  (ws + take((RNG + 1) * 4));
    int*   bsum   = (int*)  (ws + take(512 * 4));
    int*   boff   = (int*)  (ws + take(512 * 4));
    // aliases: bucket (E*4=12.8MB) on h [dead until agg L1];
    // hist (RNG*CHK*NRG*4 = 6.4MB) on A1C1 [dead until heads];
    // A2 on col, C2 on hpr8 [dead after agg64].
    unsigned* bucket = (unsigned*)h;
    int* hist = (int*)A1C1;
    unsigned short* A2 = (unsigned short*)col;   // [N,64] bf16 = 12.8MB <= 16MB
    unsigned short* C2 = (unsigned short*)hpr8;  // [N,64] bf16 = 12.8MB
    (void)ws_size; (void)n_in; (void)out_size;

    const int nb  = (N + 255) / 256;     // 391 (<512)
    const int gN  = (N + 255) / 256;
    const int gT  = (N + 63) / 64;       // 1563

    prep_w_k<<<288, 256, 0, stream>>>(W1, W2, W3, Wa1, Wa2, Wc1, Wc2, wt);
    const unsigned short* W1t  = wt;
    const unsigned short* W2t  = wt + 16384;
    const unsigned short* W3t  = wt + 32768;
    const unsigned short* Wa1t = wt + 40960;
    const unsigned short* Wa2t = wt + 49152;
    const unsigned short* Wc1t = wt + 57344;
    const unsigned short* Wc2t = wt + 65536;

    // CSR build: u32 bucket sort, 64 ranges, padded rows (multiples of 8 -> row N)
    bucket_count_k<<<NB, 256, 0, stream>>>(dst, bcnt, E);
    rsum_k<<<RNG, 256, 0, stream>>>(bcnt, base, rtot);
    rstart_k<<<1, 64, 0, stream>>>(rtot, bstart);
    bucket_scatter_k<<<NB, 256, 0, stream>>>(src, dst, base, bstart, bucket, E);
    hist_bucket_k<<<RNG * CHK, 256, 0, stream>>>(bucket, bstart, hist);
    sum_hist_dinv_k<<<gN, 256, 0, stream>>>(hist, cnt, dinv, N);
    chunk_sum_k<<<nb, 256, 0, stream>>>(cnt, bsum, N);
    scan_mid_k<<<1, 512, 0, stream>>>(bsum, boff, nb, rowptr, N);
    scan_final_k<<<nb, 256, 0, stream>>>(cnt, boff, rowptr, N);
    offsets_k<<<gN, 256, 0, stream>>>(hist, rowptr, N);
    fill2_k<<<RNG * CHK, 256, 0, stream>>>(bucket, bstart, hist, col);
    pad_col_k<<<gN, 256, 0, stream>>>(cnt, rowptr, col, N);

    // GCN layer 1: 128 -> 128, relu
    gemm_mfma_k<128, 128, true,  false, true><<<gT, 256, 0, stream>>>(x, W1t, dinv, hpr8, N);
    agg128_k<true><<<(N + 3) / 4, 256, 0, stream>>>(hpr8, rowptr, col, dinv, b1, h, N, Ecap);
    // GCN layer 2: 128 -> 128, relu
    gemm_mfma_k<128, 128, false, false, true><<<gT, 256, 0, stream>>>(h, W2t, dinv, hpr8, N);
    agg128_k<true><<<(N + 3) / 4, 256, 0, stream>>>(hpr8, rowptr, col, dinv, b2, h, N, Ecap);
    // GCN layer 3: 128 -> 64, linear
    gemm_mfma_k<128, 64,  false, false, true><<<gT, 256, 0, stream>>>(h, W3t, dinv, hpr8, N);
    agg64_k<<<(N + 3) / 4, 256, 0, stream>>>(hpr8, rowptr, col, dinv, b3, h3, N, Ecap);

    // heads (col/hpr8 now dead; A2/C2 alias them)
    gemm_mfma_k<64,  128, false, true, false><<<gT, 256, 0, stream>>>(h3, Wa1t, ba1, A1C1, N);
    gemm_mfma_k<128, 64,  false, true, false><<<gT, 256, 0, stream>>>(A1C1, Wa2t, ba2, A2, N);
    gemm_mfma_k<64,  128, false, true, false><<<gT, 256, 0, stream>>>(h3, Wc1t, bc1, A1C1, N);
    gemm_mfma_k<128, 64,  false, true, false><<<gT, 256, 0, stream>>>(A1C1, Wc2t, bc2, C2, N);
    logits_k<<<(N + 31) / 32, 256, 0, stream>>>(A2, C2, Wa3, ba3, Wc3, bc3, out, N);
}

// Round 9
// 502.179 us; speedup vs baseline: 2.9672x; 1.0096x over previous
//
#include <hip/hip_runtime.h>
#include <hip/hip_bf16.h>
#include <math.h>

// ---------------------------------------------------------------------------
// FederatedPPOAgent: 3x GCNConv (N=100k, E=3.2M, D=128) + actor/critic MLPs.
//
// R9 changes vs R8:
//  - gemm2_k: weights-stationary grid-stride GEMM (grid 512, ~3 tiles/block,
//    B staged once/block). Replaces per-tile-block gemm_mfma_k (which
//    re-staged 32KB weights per 64-row tile).
//  - heads: layer-1 actor+critic as one concat GEMM (K=64,OUT=256 -> A1C1
//    [N,256] bf16, aliasing dead h/hpr8/col); layer-2 GEMMs carry fused
//    epilogues (EPI2: relu+logits+softmax -> out[0..8); EPI3: relu+value ->
//    out[8]) via in-register partial dots + 16-lane shfl reduce. logits_k,
//    A2, C2 gone.
//  - CSR: offsets+pad_col fused into scan_final (scan_off_pad_k).
//  - agg128/agg64 unchanged: R7 vs R8 showed identical 162MB FETCH at
//    identical 66us = ~2.5 TB/s L2-miss path saturation -> at HW ceiling.
// ---------------------------------------------------------------------------

#define WS_ALIGN(x) (((x) + 255) & ~(size_t)255)

constexpr int RNG  = 64;        // node ranges
constexpr int NRG  = 1563;      // nodes per range (64*1563 >= 100000)
constexpr int NB   = 1024;      // bucket-phase blocks
constexpr int CHK  = 16;        // per-range fill chunks

constexpr float S_FP8     = 64.0f;
constexpr float S_FP8_INV = 1.0f / 64.0f;

using bf16x8 = __attribute__((ext_vector_type(8))) short;
using f32x4  = __attribute__((ext_vector_type(4))) float;
using f32x2  = __attribute__((ext_vector_type(2))) float;

__device__ __forceinline__ float b2f(unsigned short u) {
    return __uint_as_float(((unsigned int)u) << 16);
}
__device__ __forceinline__ unsigned short f2b(float f) {
    __hip_bfloat16 hb = __float2bfloat16(f);
    return *(unsigned short*)&hb;
}
__device__ __forceinline__ unsigned char f2fp8(float f) {
    return (unsigned char)(__builtin_amdgcn_cvt_pk_fp8_f32(f, f, 0, false) & 0xff);
}
__device__ __forceinline__ int pad8(int v) { return (v + 7) & ~7; }

// 8 fp8 (uint2) -> 4 packed-f32 accumulators
__device__ __forceinline__ void acc8(uint2 u, f32x2& a01, f32x2& a23,
                                     f32x2& a45, f32x2& a67) {
    a01 += __builtin_amdgcn_cvt_pk_f32_fp8((int)u.x, false);
    a23 += __builtin_amdgcn_cvt_pk_f32_fp8((int)u.x, true);
    a45 += __builtin_amdgcn_cvt_pk_f32_fp8((int)u.y, false);
    a67 += __builtin_amdgcn_cvt_pk_f32_fp8((int)u.y, true);
}

// ---------------- CSR build ----------------

__global__ __launch_bounds__(256) void bucket_count_k(
    const int* __restrict__ dst, int* __restrict__ bcnt, int E) {
    __shared__ int c64[RNG];
    int b = blockIdx.x, t = threadIdx.x;
    if (t < RNG) c64[t] = 0;
    __syncthreads();
    int ec = (E + NB - 1) / NB;
    int e0 = b * ec, e1 = min(E, e0 + ec);
    for (int e = e0 + t; e < e1; e += 256) {
        int d = __builtin_nontemporal_load(dst + e);
        atomicAdd(&c64[d / NRG], 1);
    }
    __syncthreads();
    if (t < RNG) bcnt[t * NB + b] = c64[t];
}

// block r: exclusive scan of bcnt[r][0..NB) -> base, total -> rtot[r]
__global__ __launch_bounds__(256) void rsum_k(
    const int* __restrict__ bcnt, int* __restrict__ base, int* __restrict__ rtot) {
    __shared__ int s[256];
    int r = blockIdx.x, t = threadIdx.x;
    const int* row = bcnt + (size_t)r * NB;
    int v[4], loc = 0;
#pragma unroll
    for (int j = 0; j < 4; j++) { v[j] = row[t * 4 + j]; loc += v[j]; }
    s[t] = loc;
    __syncthreads();
    for (int d = 1; d < 256; d <<= 1) {
        int x = (t >= d) ? s[t - d] : 0;
        __syncthreads();
        s[t] += x;
        __syncthreads();
    }
    int run = s[t] - loc;   // exclusive
    int* bp = base + (size_t)r * NB + t * 4;
#pragma unroll
    for (int j = 0; j < 4; j++) { bp[j] = run; run += v[j]; }
    if (t == 255) rtot[r] = s[255];
}

__global__ void rstart_k(const int* __restrict__ rtot, int* __restrict__ bstart, int E) {
    if (threadIdx.x == 0) {
        int run = 0;
        for (int r = 0; r < RNG; r++) { bstart[r] = run; run += rtot[r]; }
        bstart[RNG] = run;
    }
}

__global__ __launch_bounds__(256) void bucket_scatter_k(
    const int* __restrict__ src, const int* __restrict__ dst,
    const int* __restrict__ base, const int* __restrict__ bstart,
    unsigned* __restrict__ bucket, int E) {
    __shared__ int cur[RNG];
    int b = blockIdx.x, t = threadIdx.x;
    if (t < RNG) cur[t] = bstart[t] + base[(size_t)t * NB + b];
    __syncthreads();
    int ec = (E + NB - 1) / NB;
    int e0 = b * ec, e1 = min(E, e0 + ec);
    for (int e = e0 + t; e < e1; e += 256) {
        int d = __builtin_nontemporal_load(dst + e);
        int sv = __builtin_nontemporal_load(src + e);
        int r = d / NRG;
        int pos = atomicAdd(&cur[r], 1);
        bucket[pos] = ((unsigned)(d - r * NRG) << 17) | (unsigned)sv;
    }
}

__global__ __launch_bounds__(256) void hist_bucket_k(
    const unsigned* __restrict__ bucket, const int* __restrict__ bstart,
    int* __restrict__ hist) {
    __shared__ int h[NRG];
    int b = blockIdx.x, r = b & 63, c2 = b >> 6, t = threadIdx.x;
    for (int i = t; i < NRG; i += 256) h[i] = 0;
    int s0 = bstart[r], s1 = bstart[r + 1];
    int ec = (s1 - s0 + CHK - 1) / CHK;
    int e0 = s0 + c2 * ec, e1 = min(s1, e0 + ec);
    __syncthreads();
    for (int e = e0 + t; e < e1; e += 256) {
        unsigned v = __builtin_nontemporal_load(bucket + e);
        atomicAdd(&h[v >> 17], 1);
    }
    __syncthreads();
    int* out = hist + ((size_t)r * CHK + c2) * NRG;
    for (int i = t; i < NRG; i += 256) out[i] = h[i];
}

__global__ void sum_hist_dinv_k(const int* __restrict__ hist, int* __restrict__ cnt,
                                float* __restrict__ dinv, int N) {
    int i = blockIdx.x * 256 + threadIdx.x;
    if (i >= N) return;
    int r = i / NRG, li = i - r * NRG;
    const int* hp = hist + ((size_t)r * CHK) * NRG + li;
    int s = 0;
#pragma unroll
    for (int c = 0; c < CHK; c++) s += hp[(size_t)c * NRG];
    cnt[i] = s;
    dinv[i] = rsqrtf((float)s + 1.0f);   // +1: self loop
}

// prefix sums over PADDED counts (pad8)
__global__ void chunk_sum_k(const int* __restrict__ cnt, int* __restrict__ bsum, int n) {
    __shared__ int sd[256];
    int t = threadIdx.x;
    int i = blockIdx.x * 256 + t;
    sd[t] = (i < n) ? pad8(cnt[i]) : 0;
    __syncthreads();
    for (int d = 128; d > 0; d >>= 1) {
        if (t < d) sd[t] += sd[t + d];
        __syncthreads();
    }
    if (t == 0) bsum[blockIdx.x] = sd[0];
}

__global__ void scan_mid_k(const int* __restrict__ bsum, int* __restrict__ boff,
                           int nb, int* __restrict__ rowptr, int N) {
    __shared__ int s[512];
    int t = threadIdx.x;
    s[t] = (t < nb) ? bsum[t] : 0;
    __syncthreads();
    if (t == 0) {
        int run = 0;
        for (int i = 0; i < nb; i++) { int v = s[i]; s[i] = run; run += v; }
        rowptr[N] = run;
    }
    __syncthreads();
    if (t < nb) boff[t] = s[t];
}

// scan_final + offsets + pad_col fused
__global__ void scan_off_pad_k(const int* __restrict__ cnt, const int* __restrict__ boff,
                               int* __restrict__ rowptr, int* __restrict__ hist,
                               int* __restrict__ col, int N) {
    __shared__ int s[256];
    int t = threadIdx.x;
    int i = blockIdx.x * 256 + t;
    int cv = (i < N) ? cnt[i] : 0;
    int v = pad8(cv);
    if (i >= N) v = 0;
    s[t] = v;
    __syncthreads();
    for (int d = 1; d < 256; d <<= 1) {
        int x = (t >= d) ? s[t - d] : 0;
        __syncthreads();
        s[t] += x;
        __syncthreads();
    }
    if (i < N) {
        int rp = s[t] - v + boff[blockIdx.x];
        rowptr[i] = rp;
        // offsets: hist[r][c][li] -> running cursor
        int r = i / NRG, li = i - r * NRG;
        int* hp = hist + ((size_t)r * CHK) * NRG + li;
        int run = rp;
#pragma unroll
        for (int c = 0; c < CHK; c++) {
            int hv = hp[(size_t)c * NRG];
            hp[(size_t)c * NRG] = run;
            run += hv;
        }
        // pad slots -> zero-row N
        for (int e = rp + cv; e < rp + v; e++) col[e] = N;
    }
}

__global__ __launch_bounds__(256) void fill2_k(
    const unsigned* __restrict__ bucket, const int* __restrict__ bstart,
    const int* __restrict__ hist, int* __restrict__ col) {
    __shared__ int cur[NRG];
    int b = blockIdx.x, r = b & 63, c2 = b >> 6, t = threadIdx.x;
    const int* hp = hist + ((size_t)r * CHK + c2) * NRG;
    for (int i = t; i < NRG; i += 256) cur[i] = hp[i];
    int s0 = bstart[r], s1 = bstart[r + 1];
    int ec = (s1 - s0 + CHK - 1) / CHK;
    int e0 = s0 + c2 * ec, e1 = min(s1, e0 + ec);
    __syncthreads();
    for (int e = e0 + t; e < e1; e += 256) {
        unsigned v = __builtin_nontemporal_load(bucket + e);
        int slot = atomicAdd(&cur[v >> 17], 1);   // LDS atomic
        col[slot] = (int)(v & 0x1FFFFu);
    }
}

// ---------------- weight prep: fp32 W[K][OUT] -> bf16 W^T[OUT][K] ----------------
// Layout: W1t(16384) W2t(16384) W3t(8192) Wh1t(16384: Wa1 rows 0..127,
// Wc1 rows 128..255, K=64) Wa2t(8192) Wc2t(8192)

__global__ __launch_bounds__(256) void prep_w_k(
    const float* __restrict__ W1, const float* __restrict__ W2,
    const float* __restrict__ W3, const float* __restrict__ Wa1,
    const float* __restrict__ Wc1, const float* __restrict__ Wa2,
    const float* __restrict__ Wc2, unsigned short* __restrict__ wt) {
    int i = blockIdx.x * 256 + threadIdx.x;   // 0..73727
    const float* W; int off, K, OUT;
    if (i < 16384)      { W = W1;  off = 0;     K = 128; OUT = 128; }
    else if (i < 32768) { W = W2;  off = 16384; K = 128; OUT = 128; }
    else if (i < 40960) { W = W3;  off = 32768; K = 128; OUT = 64; }
    else if (i < 49152) { W = Wa1; off = 40960; K = 64;  OUT = 128; }
    else if (i < 57344) { W = Wc1; off = 49152; K = 64;  OUT = 128; }
    else if (i < 65536) { W = Wa2; off = 57344; K = 128; OUT = 64; }
    else                { W = Wc2; off = 65536; K = 128; OUT = 64; }
    int j = i - off, k = j / OUT, n = j - k * OUT;
    wt[off + n * K + k] = f2b(W[j]);
}

// ---------------- gemm2: weights-stationary grid-stride MFMA GEMM ----------------
// EPI 0: fp8(acc * dinv[row] * S), unguarded rows (zero pad-row at N)
// EPI 1: bf16(relu(acc + concat-bias)), concat = sb(0..127)|w3b(128..255)
// EPI 2: actor head tail: v=relu(acc+sb[col]); logits=v@w3+b3; softmax -> out[0..8)
// EPI 3: critic head tail: v=relu(acc+sb[col]); value=v@w3+b3 -> out[8]

template <int K, int OUT, int EPI, bool AF32>
__global__ __launch_bounds__(256) void gemm2_k(
    const void* __restrict__ Xv, int ldx, const unsigned short* __restrict__ Wt,
    const float* __restrict__ sb, const float* __restrict__ w3b,
    const float* __restrict__ b3, void* __restrict__ Yv, int N, int NT) {
    constexpr int LDK = K + 8;
    __shared__ __align__(16) unsigned short Bs[OUT * LDK];
    __shared__ __align__(16) unsigned short As[64 * LDK];
    int t = threadIdx.x;

    // stage B once per block (visible after first in-loop barrier)
    for (int g = t; g < OUT * (K / 8); g += 256) {
        int r = g / (K / 8), q = g - r * (K / 8);
        *(uint4*)&Bs[r * LDK + q * 8] = *(const uint4*)(Wt + r * K + q * 8);
    }

    int wv = t >> 6, lane = t & 63;
    int lm = lane & 15, lq = lane >> 4;
    constexpr int CT = OUT / 16;

    for (int tile = blockIdx.x; tile < NT; tile += gridDim.x) {
        int rowBase = tile * 64;

        // stage A tile
        if constexpr (AF32) {
            const float* X = (const float*)Xv;
            for (int g = t; g < 64 * (K / 8); g += 256) {
                int r = g / (K / 8), q = g - r * (K / 8);
                int gr = rowBase + r;
                unsigned short us[8];
                if (gr < N) {
                    float4 v0 = *(const float4*)(X + (size_t)gr * ldx + q * 8);
                    float4 v1 = *(const float4*)(X + (size_t)gr * ldx + q * 8 + 4);
                    us[0] = f2b(v0.x); us[1] = f2b(v0.y); us[2] = f2b(v0.z); us[3] = f2b(v0.w);
                    us[4] = f2b(v1.x); us[5] = f2b(v1.y); us[6] = f2b(v1.z); us[7] = f2b(v1.w);
                } else {
#pragma unroll
                    for (int j = 0; j < 8; j++) us[j] = 0;
                }
                *(uint4*)&As[r * LDK + q * 8] = *(uint4*)us;
            }
        } else {
            const unsigned short* X = (const unsigned short*)Xv;
            for (int g = t; g < 64 * (K / 8); g += 256) {
                int r = g / (K / 8), q = g - r * (K / 8);
                int gr = rowBase + r;
                uint4 v = make_uint4(0, 0, 0, 0);
                if (gr < N) v = *(const uint4*)(X + (size_t)gr * ldx + q * 8);
                *(uint4*)&As[r * LDK + q * 8] = v;
            }
        }
        __syncthreads();

        f32x4 acc[CT];
#pragma unroll
        for (int c = 0; c < CT; c++) acc[c] = (f32x4){0.f, 0.f, 0.f, 0.f};

        const unsigned short* arow = &As[(wv * 16 + lm) * LDK + lq * 8];
#pragma unroll
        for (int kt = 0; kt < K / 32; kt++) {
            bf16x8 a = *(const bf16x8*)(arow + kt * 32);
#pragma unroll
            for (int c = 0; c < CT; c++) {
                bf16x8 b = *(const bf16x8*)&Bs[(c * 16 + lm) * LDK + kt * 32 + lq * 8];
                acc[c] = __builtin_amdgcn_mfma_f32_16x16x32_bf16(a, b, acc[c], 0, 0, 0);
            }
        }

        // epilogue: C/D layout col=lane&15, row=(lane>>4)*4+reg [m89/m91]
        int r0 = rowBase + wv * 16 + lq * 4;
        if constexpr (EPI == 0) {
#pragma unroll
            for (int r = 0; r < 4; r++) {
                int gr = r0 + r;
                float scale = (gr < N) ? sb[gr] * S_FP8 : 0.f;
#pragma unroll
                for (int c = 0; c < CT; c++) {
                    int colg = c * 16 + lm;
                    ((unsigned char*)Yv)[(size_t)gr * OUT + colg] = f2fp8(acc[c][r] * scale);
                }
            }
        } else if constexpr (EPI == 1) {
#pragma unroll
            for (int r = 0; r < 4; r++) {
                int gr = r0 + r;
                if (gr < N) {
#pragma unroll
                    for (int c = 0; c < CT; c++) {
                        int colg = c * 16 + lm;
                        float bb = (colg < 128) ? sb[colg] : w3b[colg - 128];
                        float v = fmaxf(acc[c][r] + bb, 0.f);
                        ((unsigned short*)Yv)[(size_t)gr * OUT + colg] = f2b(v);
                    }
                }
            }
        } else if constexpr (EPI == 2) {
            // actor: partial logits over owned cols, 16-lane reduce, softmax
            float l[4][8];
#pragma unroll
            for (int r = 0; r < 4; r++)
#pragma unroll
                for (int a = 0; a < 8; a++) l[r][a] = 0.f;
#pragma unroll
            for (int c = 0; c < CT; c++) {
                int colg = c * 16 + lm;
#pragma unroll
                for (int r = 0; r < 4; r++) {
                    float v = fmaxf(acc[c][r] + sb[colg], 0.f);
#pragma unroll
                    for (int a = 0; a < 8; a++)
                        l[r][a] = fmaf(v, w3b[colg * 8 + a], l[r][a]);
                }
            }
#pragma unroll
            for (int w = 1; w < 16; w <<= 1)
#pragma unroll
                for (int r = 0; r < 4; r++)
#pragma unroll
                    for (int a = 0; a < 8; a++)
                        l[r][a] += __shfl_xor(l[r][a], w, 64);
            if (lm < 8) {
#pragma unroll
                for (int r = 0; r < 4; r++) {
                    int gr = r0 + r;
                    if (gr < N) {
                        float lg[8], m = -1e30f;
#pragma unroll
                        for (int a = 0; a < 8; a++) { lg[a] = l[r][a] + b3[a]; m = fmaxf(m, lg[a]); }
                        float sum = 0.f;
#pragma unroll
                        for (int a = 0; a < 8; a++) { lg[a] = expf(lg[a] - m); sum += lg[a]; }
                        ((float*)Yv)[(size_t)gr * 9 + lm] = lg[lm] / sum;
                    }
                }
            }
        } else {   // EPI == 3: critic value
            float lv[4] = {0.f, 0.f, 0.f, 0.f};
#pragma unroll
            for (int c = 0; c < CT; c++) {
                int colg = c * 16 + lm;
#pragma unroll
                for (int r = 0; r < 4; r++) {
                    float v = fmaxf(acc[c][r] + sb[colg], 0.f);
                    lv[r] = fmaf(v, w3b[colg], lv[r]);
                }
            }
#pragma unroll
            for (int w = 1; w < 16; w <<= 1)
#pragma unroll
                for (int r = 0; r < 4; r++) lv[r] += __shfl_xor(lv[r], w, 64);
            if (lm == 0) {
#pragma unroll
                for (int r = 0; r < 4; r++) {
                    int gr = r0 + r;
                    if (gr < N) ((float*)Yv)[(size_t)gr * 9 + 8] = lv[r] + b3[0];
                }
            }
        }
        __syncthreads();   // protect As before next tile's staging
    }
}

// ---------------- aggregation (unchanged from R8) ----------------

template <bool RELU>
__global__ __launch_bounds__(256) void agg128_k(
    const unsigned char* __restrict__ H,   // [(Npad+64),128] fp8, rows>=N zero
    const int* __restrict__ rowptr, const int* __restrict__ col,
    const float* __restrict__ dinv, const float* __restrict__ bias,
    unsigned short* __restrict__ Y, int N, int Ecap) {
    int tid = threadIdx.x;
    int node = blockIdx.x * 4 + (tid >> 6);
    if (node >= N) return;
    int lane = tid & 63;
    int grp = lane >> 4;
    int li8 = (lane & 15) * 8;

    f32x2 a01 = {0.f, 0.f}, a23 = {0.f, 0.f}, a45 = {0.f, 0.f}, a67 = {0.f, 0.f};
    if (grp == 0) {
        uint2 u = *(const uint2*)(H + (size_t)node * 128 + li8);
        acc8(u, a01, a23, a45, a67);
    }

    int start = rowptr[node], end = rowptr[node + 1];
    for (int e0 = start; e0 < end; e0 += 64) {
        int cv = col[min(e0 + lane, Ecap - 1)];
        int quads = min(64, end - e0) >> 2;
        for (int q = 0; q < quads; q += 2) {
            int s0 = __shfl(cv, 4 * q + grp, 64);
            int s1 = __shfl(cv, 4 * q + 4 + grp, 64);
            uint2 u0 = *(const uint2*)(H + (size_t)s0 * 128 + li8);
            uint2 u1 = *(const uint2*)(H + (size_t)s1 * 128 + li8);
            acc8(u0, a01, a23, a45, a67);
            acc8(u1, a01, a23, a45, a67);
        }
    }

#pragma unroll
    for (int w = 16; w < 64; w <<= 1) {
        a01[0] += __shfl_xor(a01[0], w, 64); a01[1] += __shfl_xor(a01[1], w, 64);
        a23[0] += __shfl_xor(a23[0], w, 64); a23[1] += __shfl_xor(a23[1], w, 64);
        a45[0] += __shfl_xor(a45[0], w, 64); a45[1] += __shfl_xor(a45[1], w, 64);
        a67[0] += __shfl_xor(a67[0], w, 64); a67[1] += __shfl_xor(a67[1], w, 64);
    }

    if (grp == 0) {
        float dv = dinv[node] * S_FP8_INV;
        float4 b0 = *(const float4*)(bias + li8);
        float4 b1 = *(const float4*)(bias + li8 + 4);
        float o0 = a01[0] * dv + b0.x, o1 = a01[1] * dv + b0.y;
        float o2 = a23[0] * dv + b0.z, o3 = a23[1] * dv + b0.w;
        float o4 = a45[0] * dv + b1.x, o5 = a45[1] * dv + b1.y;
        float o6 = a67[0] * dv + b1.z, o7 = a67[1] * dv + b1.w;
        if (RELU) {
            o0 = fmaxf(o0, 0.f); o1 = fmaxf(o1, 0.f); o2 = fmaxf(o2, 0.f); o3 = fmaxf(o3, 0.f);
            o4 = fmaxf(o4, 0.f); o5 = fmaxf(o5, 0.f); o6 = fmaxf(o6, 0.f); o7 = fmaxf(o7, 0.f);
        }
        unsigned short us[8] = {f2b(o0), f2b(o1), f2b(o2), f2b(o3),
                                f2b(o4), f2b(o5), f2b(o6), f2b(o7)};
        *(uint4*)(Y + (size_t)node * 128 + li8) = *(uint4*)us;
    }
}

__global__ __launch_bounds__(256) void agg64_k(
    const unsigned char* __restrict__ H,   // [(Npad+64),64] fp8, rows>=N zero
    const int* __restrict__ rowptr, const int* __restrict__ col,
    const float* __restrict__ dinv, const float* __restrict__ bias,
    unsigned short* __restrict__ Y, int N, int Ecap) {
    int tid = threadIdx.x;
    int node = blockIdx.x * 4 + (tid >> 6);
    if (node >= N) return;
    int lane = tid & 63;
    int grp = lane >> 3;
    int li8 = (lane & 7) * 8;

    f32x2 a01 = {0.f, 0.f}, a23 = {0.f, 0.f}, a45 = {0.f, 0.f}, a67 = {0.f, 0.f};
    if (grp == 0) {
        uint2 u = *(const uint2*)(H + (size_t)node * 64 + li8);
        acc8(u, a01, a23, a45, a67);
    }

    int start = rowptr[node], end = rowptr[node + 1];
    for (int e0 = start; e0 < end; e0 += 64) {
        int cv = col[min(e0 + lane, Ecap - 1)];
        int octs = min(64, end - e0) >> 3;
        int o = 0;
        for (; o + 2 <= octs; o += 2) {
            int s0 = __shfl(cv, 8 * o + grp, 64);
            int s1 = __shfl(cv, 8 * o + 8 + grp, 64);
            uint2 u0 = *(const uint2*)(H + (size_t)s0 * 64 + li8);
            uint2 u1 = *(const uint2*)(H + (size_t)s1 * 64 + li8);
            acc8(u0, a01, a23, a45, a67);
            acc8(u1, a01, a23, a45, a67);
        }
        if (o < octs) {
            int s0 = __shfl(cv, 8 * o + grp, 64);
            uint2 u0 = *(const uint2*)(H + (size_t)s0 * 64 + li8);
            acc8(u0, a01, a23, a45, a67);
        }
    }

#pragma unroll
    for (int w = 8; w < 64; w <<= 1) {
        a01[0] += __shfl_xor(a01[0], w, 64); a01[1] += __shfl_xor(a01[1], w, 64);
        a23[0] += __shfl_xor(a23[0], w, 64); a23[1] += __shfl_xor(a23[1], w, 64);
        a45[0] += __shfl_xor(a45[0], w, 64); a45[1] += __shfl_xor(a45[1], w, 64);
        a67[0] += __shfl_xor(a67[0], w, 64); a67[1] += __shfl_xor(a67[1], w, 64);
    }

    if (grp == 0) {
        float dv = dinv[node] * S_FP8_INV;
        float4 b0 = *(const float4*)(bias + li8);
        float4 b1 = *(const float4*)(bias + li8 + 4);
        unsigned short us[8] = {
            f2b(a01[0] * dv + b0.x), f2b(a01[1] * dv + b0.y),
            f2b(a23[0] * dv + b0.z), f2b(a23[1] * dv + b0.w),
            f2b(a45[0] * dv + b1.x), f2b(a45[1] * dv + b1.y),
            f2b(a67[0] * dv + b1.z), f2b(a67[1] * dv + b1.w)};
        *(uint4*)(Y + (size_t)node * 64 + li8) = *(uint4*)us;
    }
}

// ---------------- launch ----------------

extern "C" void kernel_launch(void* const* d_in, const int* in_sizes, int n_in,
                              void* d_out, int out_size, void* d_ws, size_t ws_size,
                              hipStream_t stream) {
    const float* x   = (const float*)d_in[0];
    const int*   ei  = (const int*)d_in[1];
    const float* W1  = (const float*)d_in[2];  const float* b1  = (const float*)d_in[3];
    const float* W2  = (const float*)d_in[4];  const float* b2  = (const float*)d_in[5];
    const float* W3  = (const float*)d_in[6];  const float* b3  = (const float*)d_in[7];
    const float* Wa1 = (const float*)d_in[8];  const float* ba1 = (const float*)d_in[9];
    const float* Wa2 = (const float*)d_in[10]; const float* ba2 = (const float*)d_in[11];
    const float* Wa3 = (const float*)d_in[12]; const float* ba3 = (const float*)d_in[13];
    const float* Wc1 = (const float*)d_in[14]; const float* bc1 = (const float*)d_in[15];
    const float* Wc2 = (const float*)d_in[16]; const float* bc2 = (const float*)d_in[17];
    const float* Wc3 = (const float*)d_in[18]; const float* bc3 = (const float*)d_in[19];
    float* out = (float*)d_out;

    const int N = in_sizes[0] / 128;     // 100000
    const int E = in_sizes[1] / 2;       // 3200000
    const int* src = ei;
    const int* dst = ei + E;
    const int Ecap = E + 8 * N;          // padded-CSR capacity
    const int Npad = ((N + 63) / 64) * 64;
    const int NT   = (N + 63) / 64;      // 1563 row tiles

    // workspace layout (h3 first; h/hpr8/col contiguous so A1C1 can span them)
    size_t off = 0;
    auto take = [&](size_t bytes) { size_t o = off; off = WS_ALIGN(off + bytes); return o; };
    char* ws = (char*)d_ws;
    unsigned short* h3     = (unsigned short*)(ws + take((size_t)N * 64 * 2));       // 12.8MB
    unsigned short* h      = (unsigned short*)(ws + take((size_t)N * 128 * 2));      // 25.6MB
    unsigned char*  hpr8   = (unsigned char*) (ws + take((size_t)(Npad + 64) * 128));// 12.8MB
    int*            col    = (int*)(ws + take((size_t)Ecap * 4));                    // 16MB
    unsigned short* wt     = (unsigned short*)(ws + take(73728 * 2));
    float* dinv   = (float*)(ws + take((size_t)(N + 64) * 4));
    int*   cnt    = (int*)  (ws + take((size_t)N * 4));
    int*   rowptr = (int*)  (ws + take((size_t)(N + 1) * 4));
    int*   bcnt   = (int*)  (ws + take((size_t)RNG * NB * 4));
    int*   base   = (int*)  (ws + take((size_t)RNG * NB * 4));
    int*   rtot   = (int*)  (ws + take(RNG * 4));
    int*   bstart = (int*)  (ws + take((RNG + 1) * 4));
    int*   bsum   = (int*)  (ws + take(512 * 4));
    int*   boff   = (int*)  (ws + take(512 * 4));
    // aliases: bucket (12.8MB) on h [dead in CSR phase];
    // hist (6.4MB) on h3 [h3 written only by agg64, after fill2];
    // A1C1 [N,256] bf16 = 51.2MB spans h+hpr8+col (all dead after agg64).
    unsigned* bucket = (unsigned*)h;
    int* hist = (int*)h3;
    unsigned short* A1C1 = (unsigned short*)h;
    (void)ws_size; (void)n_in; (void)out_size;

    const int nb  = (N + 255) / 256;     // 391 (<512)
    const int gN  = (N + 255) / 256;
    const int GG  = 512;                 // gemm2 grid

    prep_w_k<<<288, 256, 0, stream>>>(W1, W2, W3, Wa1, Wc1, Wa2, Wc2, wt);
    const unsigned short* W1t  = wt;
    const unsigned short* W2t  = wt + 16384;
    const unsigned short* W3t  = wt + 32768;
    const unsigned short* Wh1t = wt + 40960;   // [256][64] concat actor|critic L1
    const unsigned short* Wa2t = wt + 57344;
    const unsigned short* Wc2t = wt + 65536;

    // CSR build
    bucket_count_k<<<NB, 256, 0, stream>>>(dst, bcnt, E);
    rsum_k<<<RNG, 256, 0, stream>>>(bcnt, base, rtot);
    rstart_k<<<1, 64, 0, stream>>>(rtot, bstart, E);
    bucket_scatter_k<<<NB, 256, 0, stream>>>(src, dst, base, bstart, bucket, E);
    hist_bucket_k<<<RNG * CHK, 256, 0, stream>>>(bucket, bstart, hist);
    sum_hist_dinv_k<<<gN, 256, 0, stream>>>(hist, cnt, dinv, N);
    chunk_sum_k<<<nb, 256, 0, stream>>>(cnt, bsum, N);
    scan_mid_k<<<1, 512, 0, stream>>>(bsum, boff, nb, rowptr, N);
    scan_off_pad_k<<<nb, 256, 0, stream>>>(cnt, boff, rowptr, hist, col, N);
    fill2_k<<<RNG * CHK, 256, 0, stream>>>(bucket, bstart, hist, col);

    // GCN layer 1..3
    gemm2_k<128, 128, 0, true><<<GG, 256, 0, stream>>>(
        x, 128, W1t, dinv, nullptr, nullptr, hpr8, N, NT);
    agg128_k<true><<<(N + 3) / 4, 256, 0, stream>>>(hpr8, rowptr, col, dinv, b1, h, N, Ecap);
    gemm2_k<128, 128, 0, false><<<GG, 256, 0, stream>>>(
        h, 128, W2t, dinv, nullptr, nullptr, hpr8, N, NT);
    agg128_k<true><<<(N + 3) / 4, 256, 0, stream>>>(hpr8, rowptr, col, dinv, b2, h, N, Ecap);
    gemm2_k<128, 64, 0, false><<<GG, 256, 0, stream>>>(
        h, 128, W3t, dinv, nullptr, nullptr, hpr8, N, NT);
    agg64_k<<<(N + 3) / 4, 256, 0, stream>>>(hpr8, rowptr, col, dinv, b3, h3, N, Ecap);

    // heads: concat L1, then fused-epilogue L2s (h/hpr8/col dead -> A1C1)
    gemm2_k<64, 256, 1, false><<<GG, 256, 0, stream>>>(
        h3, 64, Wh1t, ba1, bc1, nullptr, A1C1, N, NT);
    gemm2_k<128, 64, 2, false><<<GG, 256, 0, stream>>>(
        A1C1, 256, Wa2t, ba2, Wa3, ba3, out, N, NT);
    gemm2_k<128, 64, 3, false><<<GG, 256, 0, stream>>>(
        A1C1 + 128, 256, Wc2t, bc2, Wc3, bc3, out, N, NT);
}